// Round 5
// baseline (407.244 us; speedup 1.0000x reference)
//
#include <hip/hip_runtime.h>
#include <math.h>

constexpr int Nn = 50000;
constexpr int Mm = 4000;
constexpr int Ee = 320000;
constexpr int KPB = Ee / Mm;           // 80 entries per hyperedge (he_e = i % M)
constexpr float BINV = 1.0f / (float)KPB;
constexpr float EPSf = 1e-5f;
constexpr int NBKT = 16;               // stat buckets (fp32 atomics, no fence!)
constexpr int NBSCAN = 49;             // scan blocks (1024 nodes each)

typedef __attribute__((ext_vector_type(8))) short bfrag_t;   // 8 bf16 (4 VGPR)
typedef __attribute__((ext_vector_type(4))) float facc_t;    // 4 fp32 acc

__device__ __forceinline__ float lrelu_f(float x) { return x >= 0.f ? x : 0.2f * x; }

__device__ __forceinline__ unsigned short f2bf(float f) {   // RTN-even fp32->bf16
    unsigned int u = __float_as_uint(f);
    return (unsigned short)((u + 0x7FFFu + ((u >> 16) & 1u)) >> 16);
}

__device__ __forceinline__ float wave_sum(float v) {
#pragma unroll
    for (int o = 32; o >= 1; o >>= 1) v += __shfl_xor(v, o, 64);
    return v;
}

// Consumer-side BN finalize: stats buckets (prev kernel's fp32 atomics) -> AB in LDS.
__device__ __forceinline__ void finalize_to_lds(const float* __restrict__ st,
                                                const float* __restrict__ g,
                                                const float* __restrict__ b,
                                                float* ABsh, int t) {
    if (t < 128) {
        double ds = 0, dq = 0;
#pragma unroll
        for (int i = 0; i < NBKT; i++) {
            ds += (double)st[i * 256 + t];
            dq += (double)st[i * 256 + 128 + t];
        }
        double mean = ds / (double)Nn;
        double var = dq / (double)Nn - mean * mean;
        float rstd = (float)(1.0 / sqrt(var + (double)EPSf));
        float A = g[t] * rstd;
        ABsh[t] = A;
        ABsh[128 + t] = b[t] - (float)mean * A;
    }
    __syncthreads();
}

// exclusive scan of counts -> offs; block b handles nodes [b*1024, b*1024+1024)
__device__ void scan_body(const int* __restrict__ counts, int* __restrict__ offs,
                          int b, int t) {
    __shared__ int sdi[256];
    int pre = 0;
    for (int i = t; i < b * 1024; i += 256) pre += counts[i];
    sdi[t] = pre;
    __syncthreads();
    for (int st = 128; st >= 1; st >>= 1) {
        if (t < st) sdi[t] += sdi[t + st];
        __syncthreads();
    }
    int run0 = sdi[0];
    __syncthreads();
    int c4[4];
    int s = 0;
#pragma unroll
    for (int i = 0; i < 4; i++) {
        int n = b * 1024 + t * 4 + i;
        c4[i] = (n < Nn) ? counts[n] : 0;
        s += c4[i];
    }
    sdi[t] = s;
    __syncthreads();
    for (int off = 1; off < 256; off <<= 1) {
        int v = (t >= off) ? sdi[t - off] : 0;
        __syncthreads();
        sdi[t] += v;
        __syncthreads();
    }
    int run = sdi[t] - s + run0;
#pragma unroll
    for (int i = 0; i < 4; i++) {
        int n = b * 1024 + t * 4 + i;
        if (n < Nn) offs[n] = run;
        run += c4[i];
    }
    if (b == NBSCAN - 1 && t == 255) offs[Nn] = run0 + sdi[255];
}

// ---------------- gemmM v2: Nn x 128 @ 128x128 via bf16x3 MFMA ----------------------------
// R4 post-mortem: 782-block grid -> only ~12 waves/CU, latency-exposed (Occ 12.7%).
// v2: block = 32 rows; wave = 16 rows x 4 col-tiles (wv&1 selects col half) -> grid 1563,
// ~16 waves/CU resident, per-wave B-loads halved (32), 4 independent MFMA chains.
// B pre-split/packed in fragment order (BH/BL) by count_edges_watt block 1251 (unchanged).
// Fragment maps (gfx950): A[m][k]: m=lane&15, k=(lane>>4)*8+j ; B[k][n]: n=lane&15, same k;
// D[m][n]: n=lane&15, m=(lane>>4)*4+reg. K-slot consistency A<->Bpack by construction.
template <bool LRELU, bool PROBN, bool RESID, bool STATS, bool SCANX>
__global__ __launch_bounds__(256) void gemmM(const float* __restrict__ A,
                                             const unsigned short* __restrict__ BH,
                                             const unsigned short* __restrict__ BL,
                                             const float* __restrict__ bias,
                                             const float* __restrict__ stIn,
                                             const float* __restrict__ fing,
                                             const float* __restrict__ finb,
                                             const float* __restrict__ resid,
                                             float* __restrict__ stF,
                                             float* __restrict__ C, int R,
                                             int gemmBlocksX,
                                             const int* __restrict__ counts,
                                             int* __restrict__ offs) {
    const int t = threadIdx.x;
    if (SCANX && (int)blockIdx.x >= gemmBlocksX) {
        scan_body(counts, offs, blockIdx.x - gemmBlocksX, t);
        return;
    }
    __shared__ float ABsh[PROBN ? 256 : 1];
    __shared__ float SredS[STATS ? 4 : 1][STATS ? 128 : 1];
    __shared__ float SredQ[STATS ? 4 : 1][STATS ? 128 : 1];
    const int wv = t >> 6, l = t & 63, lm = l & 15, lg = l >> 4;
    const int row0 = blockIdx.x * 32 + (wv >> 1) * 16;
    const int cb0 = (wv & 1) * 4;              // col-tile base: 4 tiles = 64 cols per wave

    if (PROBN) finalize_to_lds(stIn, fing, finb, ABsh, t);

    int rA = row0 + lm;
    rA = rA < R ? rA : R - 1;
    const float* Ap = A + (size_t)rA * 128 + lg * 8;

    facc_t acc[4];
#pragma unroll
    for (int ct = 0; ct < 4; ct++) acc[ct] = (facc_t){0.f, 0.f, 0.f, 0.f};

#pragma unroll
    for (int ks = 0; ks < 4; ks++) {
        float4 a0 = *(const float4*)(Ap + ks * 32);
        float4 a1 = *(const float4*)(Ap + ks * 32 + 4);
        if (PROBN) {
            const int cbk = ks * 32 + lg * 8;
            float4 cA0 = *(const float4*)&ABsh[cbk];
            float4 cA1 = *(const float4*)&ABsh[cbk + 4];
            float4 cB0 = *(const float4*)&ABsh[128 + cbk];
            float4 cB1 = *(const float4*)&ABsh[128 + cbk + 4];
            a0.x = a0.x * cA0.x + cB0.x; a0.y = a0.y * cA0.y + cB0.y;
            a0.z = a0.z * cA0.z + cB0.z; a0.w = a0.w * cA0.w + cB0.w;
            a1.x = a1.x * cA1.x + cB1.x; a1.y = a1.y * cA1.y + cB1.y;
            a1.z = a1.z * cA1.z + cB1.z; a1.w = a1.w * cA1.w + cB1.w;
        }
        float av[8] = {a0.x, a0.y, a0.z, a0.w, a1.x, a1.y, a1.z, a1.w};
        bfrag_t ah, al;
#pragma unroll
        for (int j = 0; j < 8; j++) {
            unsigned short h = f2bf(av[j]);
            float hf = __uint_as_float(((unsigned int)h) << 16);
            ah[j] = (short)h;
            al[j] = (short)f2bf(av[j] - hf);
        }
#pragma unroll
        for (int ct = 0; ct < 4; ct++) {
            const size_t fo = (((size_t)(ks * 8 + cb0 + ct)) * 64 + l) * 8;
            bfrag_t bh = *(const bfrag_t*)(BH + fo);
            bfrag_t bl = *(const bfrag_t*)(BL + fo);
            acc[ct] = __builtin_amdgcn_mfma_f32_16x16x32_bf16(ah, bh, acc[ct], 0, 0, 0);
            acc[ct] = __builtin_amdgcn_mfma_f32_16x16x32_bf16(al, bh, acc[ct], 0, 0, 0);
            acc[ct] = __builtin_amdgcn_mfma_f32_16x16x32_bf16(ah, bl, acc[ct], 0, 0, 0);
        }
    }

    float cs[4], cq[4];
#pragma unroll
    for (int ct = 0; ct < 4; ct++) { cs[ct] = 0.f; cq[ct] = 0.f; }
#pragma unroll
    for (int ct = 0; ct < 4; ct++) {
        const int col = (cb0 + ct) * 16 + lm;
        const float bv = bias ? bias[col] : 0.f;
#pragma unroll
        for (int r = 0; r < 4; r++) {
            const int row = row0 + lg * 4 + r;
            if (row >= R) continue;
            float v = acc[ct][r] + bv;
            if (LRELU) v = lrelu_f(v);
            if (RESID) v += resid[(size_t)row * 128 + col];
            C[(size_t)row * 128 + col] = v;
            if (STATS) { cs[ct] += v; cq[ct] += v * v; }
        }
    }
    if (STATS) {
#pragma unroll
        for (int ct = 0; ct < 4; ct++) {
            cs[ct] += __shfl_xor(cs[ct], 16, 64);
            cs[ct] += __shfl_xor(cs[ct], 32, 64);
            cq[ct] += __shfl_xor(cq[ct], 16, 64);
            cq[ct] += __shfl_xor(cq[ct], 32, 64);
            const int col = (cb0 + ct) * 16 + lm;
            if (lg == 0) {
                SredS[wv][col] = cs[ct];
                SredQ[wv][col] = cq[ct];
            } else if (lg == 1) {       // zero the 64 cols this wave doesn't own
                SredS[wv][col ^ 64] = 0.f;
                SredQ[wv][col ^ 64] = 0.f;
            }
        }
        __syncthreads();
        if (t < 128) {
            float s = 0.f, q = 0.f;
#pragma unroll
            for (int ww = 0; ww < 4; ww++) { s += SredS[ww][t]; q += SredQ[ww][t]; }
            int bkt = blockIdx.x & (NBKT - 1);
            atomicAdd(&stF[bkt * 256 + t], s);
            atomicAdd(&stF[bkt * 256 + 128 + t], q);
        }
    }
}

// ---------------- GEMM (M-side eo): C[R, bcol:+128] = op(A[R,128] @ B[:, bcol:+128]) -------
// BK=16, A-tile transposed in LDS, ROWS=32. PACKH2: eo col-pair interleave (h=blockIdx.y).
template <int ROWS, bool PACKH2>
__global__ __launch_bounds__(256) void gemmT(const float* __restrict__ A, size_t aystride,
                                             const float* __restrict__ B, int ldb,
                                             float scale,
                                             float* __restrict__ C, int ldc, int R) {
    constexpr int RPT = ROWS / 16;
    const int t = threadIdx.x;
    __shared__ float As[16][ROWS + 4];
    __shared__ float Bs[16][128];
    const int ty = t >> 4, tx = t & 15;
    const int row0 = blockIdx.x * ROWS;
    const int bcol = blockIdx.y * 128;
    A += (size_t)blockIdx.y * aystride;

    float4 acc[RPT][2];
#pragma unroll
    for (int i = 0; i < RPT; i++)
#pragma unroll
        for (int q = 0; q < 2; q++) acc[i][q] = make_float4(0.f, 0.f, 0.f, 0.f);

    for (int k0 = 0; k0 < 128; k0 += 16) {
        {
            int r = t >> 3, kc = (t & 7) * 2;
            int rr = row0 + r;
            rr = rr < R ? rr : R - 1;
            float2 av = *(const float2*)(A + (size_t)rr * 128 + k0 + kc);
            As[kc + 0][r] = av.x;
            As[kc + 1][r] = av.y;
        }
        {
            int kk = t >> 5, c4 = (t & 31) * 4;
            float4 bv0 = *(const float4*)(B + (size_t)(k0 + kk) * ldb + bcol + c4);
            float4 bv1 = *(const float4*)(B + (size_t)(k0 + kk + 8) * ldb + bcol + c4);
            *(float4*)&Bs[kk][c4] = bv0;
            *(float4*)&Bs[kk + 8][c4] = bv1;
        }
        __syncthreads();
#pragma unroll
        for (int kk = 0; kk < 16; kk++) {
            float ar[RPT];
            {
                float2 a2 = *(const float2*)&As[kk][ty * 2];
                ar[0] = a2.x; ar[RPT - 1] = a2.y;
            }
            float4 b0 = *(const float4*)&Bs[kk][4 * tx];
            float4 b1 = *(const float4*)&Bs[kk][64 + 4 * tx];
#pragma unroll
            for (int i = 0; i < RPT; i++) {
                acc[i][0].x = fmaf(ar[i], b0.x, acc[i][0].x);
                acc[i][0].y = fmaf(ar[i], b0.y, acc[i][0].y);
                acc[i][0].z = fmaf(ar[i], b0.z, acc[i][0].z);
                acc[i][0].w = fmaf(ar[i], b0.w, acc[i][0].w);
                acc[i][1].x = fmaf(ar[i], b1.x, acc[i][1].x);
                acc[i][1].y = fmaf(ar[i], b1.y, acc[i][1].y);
                acc[i][1].z = fmaf(ar[i], b1.z, acc[i][1].z);
                acc[i][1].w = fmaf(ar[i], b1.w, acc[i][1].w);
            }
        }
        __syncthreads();
    }

#pragma unroll
    for (int i = 0; i < RPT; i++) {
        int row = row0 + ty * RPT + i;
        if (row >= R) continue;
        float4 v0, v1;
        v0.x = acc[i][0].x * scale; v0.y = acc[i][0].y * scale;
        v0.z = acc[i][0].z * scale; v0.w = acc[i][0].w * scale;
        v1.x = acc[i][1].x * scale; v1.y = acc[i][1].y * scale;
        v1.z = acc[i][1].z * scale; v1.w = acc[i][1].w * scale;
        if (PACKH2) {
            int h = blockIdx.y;
            float* c0 = C + (size_t)row * ldc + 8 * tx + 2 * h;
            *(float2*)(c0) = make_float2(v0.x, v0.y);
            *(float2*)(c0 + 4) = make_float2(v0.z, v0.w);
            float* c1 = C + (size_t)row * ldc + 128 + 8 * tx + 2 * h;
            *(float2*)(c1) = make_float2(v1.x, v1.y);
            *(float2*)(c1 + 4) = make_float2(v1.z, v1.w);
        } else {
            *(float4*)(C + (size_t)row * ldc + bcol + 4 * tx) = v0;
            *(float4*)(C + (size_t)row * ldc + bcol + 64 + 4 * tx) = v1;
        }
    }
}

// ---------------- CSR count + he_n transpose (+watt, +bf16 weight-pack extra blocks) --------
__global__ void count_edges_watt(const int* __restrict__ he_n, int* __restrict__ counts,
                                 const float* __restrict__ h1_w, const float* __restrict__ h1_att,
                                 const float* __restrict__ h2_w, const float* __restrict__ h2_att,
                                 float* __restrict__ wnA, float* __restrict__ weA,
                                 int* __restrict__ he_nT,
                                 const float* __restrict__ lin1_w,
                                 const float* __restrict__ lin2_w,
                                 unsigned short* __restrict__ bfH,
                                 unsigned short* __restrict__ bfL) {
    int t = threadIdx.x;
    if (blockIdx.x == 1250) {
        for (int j = 0; j < 3; j++) {
            int id = t + 256 * j;
            if (id >= 768) break;
            int which = id / 384;
            int rem = id % 384;
            int h3 = rem >> 7, k = rem & 127;
            float s = 0.f;
            if (h3 < 2) {
                const float* wrow = h1_w + (size_t)k * 256 + h3 * 128;
                const float* arow = h1_att + h3 * 256 + which * 128;
                for (int c = 0; c < 128; c++) s += wrow[c] * arow[c];
            } else {
                const float* wrow = h2_w + (size_t)k * 128;
                const float* arow = h2_att + which * 128;
                for (int c = 0; c < 128; c++) s += wrow[c] * arow[c];
            }
            (which ? weA : wnA)[h3 * 128 + k] = s;
        }
        return;
    }
    if (blockIdx.x == 1251) {
        // pack lin1_w/lin2_w -> bf16 hi/lo in MFMA-fragment order:
        // e = ((ks*8+ct)*64+lane)*8+j ; k = ks*32+(lane>>4)*8+j ; n = ct*16+(lane&15)
        for (int q = t; q < 32768; q += 256) {
            int mat = q >> 14;
            int e = q & 16383;
            int j = e & 7, lane = (e >> 3) & 63, ct = (e >> 9) & 7, ks = e >> 12;
            int k = ks * 32 + (lane >> 4) * 8 + j;
            int n = ct * 16 + (lane & 15);
            float f = (mat ? lin2_w : lin1_w)[(size_t)k * 128 + n];
            unsigned short h = f2bf(f);
            float hf = __uint_as_float(((unsigned int)h) << 16);
            bfH[mat * 16384 + e] = h;
            bfL[mat * 16384 + e] = f2bf(f - hf);
        }
        return;
    }
    int g = blockIdx.x * 256 + t;
    if (g < Ee) {
        int m = g / KPB;
        int k = g - m * KPB;
        int n = he_n[m + (size_t)k * Mm];
        he_nT[g] = n;
        atomicAdd(&counts[n], 1);
    }
}

// ---------------- BN dots (+in-kernel finalize; block 0 publishes AB; +fill_csr fold) ------
template <int H, bool FILL>
__global__ __launch_bounds__(256) void bn_dots(const float* __restrict__ X,
                                               const float* __restrict__ stIn,
                                               const float* __restrict__ fing,
                                               const float* __restrict__ finb,
                                               float* __restrict__ ABout,
                                               const float* __restrict__ wn,
                                               const float* __restrict__ we,
                                               float* __restrict__ an,
                                               float* __restrict__ pe,
                                               const int* __restrict__ he_n,
                                               const int* __restrict__ offs,
                                               int* __restrict__ cursor,
                                               int* __restrict__ eid, int mainBlocks) {
    int t = threadIdx.x;
    if (FILL && (int)blockIdx.x >= mainBlocks) {
        int e = (blockIdx.x - mainBlocks) * 256 + t;
        if (e < Ee) {
            int n = he_n[e];
            int p = atomicAdd(&cursor[n], 1);
            eid[offs[n] + p] = e;
        }
        return;
    }
    __shared__ float ABsh[256];
    finalize_to_lds(stIn, fing, finb, ABsh, t);
    if (blockIdx.x == 0) ABout[t] = ABsh[t];
    int w = t >> 6, lane = t & 63;
    float a0 = ABsh[lane], a1 = ABsh[lane + 64];
    float b0 = ABsh[128 + lane], b1 = ABsh[192 + lane];
    float wn0[H], wn1[H], we0[H], we1[H];
#pragma unroll
    for (int h = 0; h < H; h++) {
        wn0[h] = wn[h * 128 + lane]; wn1[h] = wn[h * 128 + 64 + lane];
        we0[h] = we[h * 128 + lane]; we1[h] = we[h * 128 + 64 + lane];
    }
#pragma unroll
    for (int nn = 0; nn < 4; nn++) {
        int row = blockIdx.x * 16 + w * 4 + nn;
        const float* xr = X + (size_t)row * 128;
        float v0 = xr[lane] * a0 + b0;
        float v1 = xr[lane + 64] * a1 + b1;
        float pv[H], qv[H];
#pragma unroll
        for (int h = 0; h < H; h++) {
            pv[h] = wave_sum(v0 * wn0[h] + v1 * wn1[h]);
            qv[h] = wave_sum(v0 * we0[h] + v1 * we1[h]);
        }
        if (lane == 0) {
            if (H == 2) {
                *(float2*)&an[row * 2] = make_float2(pv[0], pv[1]);
                *(float2*)&pe[row * 2] = make_float2(qv[0], qv[1]);
            } else {
                an[row] = pv[0];
                pe[row] = qv[0];
            }
        }
    }
}

// final elementwise BN apply with in-kernel finalize (16 rows/block)
__global__ __launch_bounds__(256) void bn_out(const float* __restrict__ X,
                                              const float* __restrict__ stIn,
                                              const float* __restrict__ fing,
                                              const float* __restrict__ finb,
                                              float* __restrict__ Y) {
    __shared__ float ABsh[256];
    int t = threadIdx.x;
    finalize_to_lds(stIn, fing, finb, ABsh, t);
    int w = t >> 6, lane = t & 63;
    float a0 = ABsh[lane], a1 = ABsh[lane + 64];
    float b0 = ABsh[128 + lane], b1 = ABsh[192 + lane];
#pragma unroll
    for (int nn = 0; nn < 4; nn++) {
        int row = blockIdx.x * 16 + w * 4 + nn;
        const float* xr = X + (size_t)row * 128;
        float* yr = Y + (size_t)row * 128;
        yr[lane] = xr[lane] * a0 + b0;
        yr[lane + 64] = xr[lane + 64] * a1 + b1;
    }
}

// ae[m,h] = sum over the 80 member nodes of pe[node,h]  (coalesced via he_nT)
template <int H>
__global__ __launch_bounds__(256) void ea_from_pe(const int* __restrict__ he_nT,
                                                  const float* __restrict__ pe,
                                                  float* __restrict__ ae) {
    int w = threadIdx.x >> 6, lane = threadIdx.x & 63;
    int m = blockIdx.x * 4 + w;
    if (m >= Mm) return;
    float s[H];
#pragma unroll
    for (int h = 0; h < H; h++) s[h] = 0.f;
    for (int k = lane; k < KPB; k += 64) {
        int idx = he_nT[m * KPB + k];
        if (H == 2) {
            float2 p2 = *(const float2*)(pe + (size_t)idx * 2);
            s[0] += p2.x;
            s[H - 1] += p2.y;
        } else {
            s[0] += pe[idx];
        }
    }
#pragma unroll
    for (int h = 0; h < H; h++) s[h] = wave_sum(s[h]);
    if (lane == 0)
#pragma unroll
        for (int h = 0; h < H; h++) ae[m * H + h] = s[h];
}

// per-node softmax STATS ONLY; consumers recompute p from nsp:
//   H=2: nsp[n*8..] = {an0,an1,mx0,mx1} {1/sm0,1/sm1,Dinv*0.5,0}
//   H=1: nsp[n*4..] = {an, mx, 1/sm, Dinv}
template <int H>
__global__ __launch_bounds__(256) void seg_softmax(const int* __restrict__ offs,
                                                   const int* __restrict__ eid,
                                                   const float* __restrict__ an,
                                                   const float* __restrict__ ae,
                                                   const float* __restrict__ he_w,
                                                   float* __restrict__ nsp) {
    int t = threadIdx.x;
    int wv = t >> 6, lane = t & 63;
    int q = lane >> 3, li = lane & 7;
    int n = blockIdx.x * 32 + wv * 8 + q;
    bool valid = n < Nn;
    int base = valid ? offs[n] : 0;
    int deg = valid ? offs[n + 1] - base : 0;
    float anv[H];
#pragma unroll
    for (int h = 0; h < H; h++) anv[h] = valid ? an[n * H + h] : 0.f;

    bool h0 = li < deg, h1 = li + 8 < deg;
    int m0 = 0, m1 = 0;
    float l0[H], l1[H];
    float mx[H];
#pragma unroll
    for (int h = 0; h < H; h++) { mx[h] = -INFINITY; l0[h] = 0.f; l1[h] = 0.f; }
    if (h0) {
        m0 = eid[base + li] % Mm;
#pragma unroll
        for (int h = 0; h < H; h++) {
            l0[h] = lrelu_f(anv[h] + ae[m0 * H + h]);
            mx[h] = fmaxf(mx[h], l0[h]);
        }
    }
    if (h1) {
        m1 = eid[base + li + 8] % Mm;
#pragma unroll
        for (int h = 0; h < H; h++) {
            l1[h] = lrelu_f(anv[h] + ae[m1 * H + h]);
            mx[h] = fmaxf(mx[h], l1[h]);
        }
    }
    for (int c = li + 16; c < deg; c += 8) {
        int m = eid[base + c] % Mm;
#pragma unroll
        for (int h = 0; h < H; h++) mx[h] = fmaxf(mx[h], lrelu_f(anv[h] + ae[m * H + h]));
    }
#pragma unroll
    for (int h = 0; h < H; h++) {
#pragma unroll
        for (int o = 1; o <= 4; o <<= 1) mx[h] = fmaxf(mx[h], __shfl_xor(mx[h], o, 64));
    }
    float sm[H];
#pragma unroll
    for (int h = 0; h < H; h++) sm[h] = 0.f;
    float dn = 0.f;
    if (h0) {
        dn += he_w[m0];
#pragma unroll
        for (int h = 0; h < H; h++) sm[h] += expf(l0[h] - mx[h]);
    }
    if (h1) {
        dn += he_w[m1];
#pragma unroll
        for (int h = 0; h < H; h++) sm[h] += expf(l1[h] - mx[h]);
    }
    for (int c = li + 16; c < deg; c += 8) {
        int m = eid[base + c] % Mm;
        dn += he_w[m];
#pragma unroll
        for (int h = 0; h < H; h++) sm[h] += expf(lrelu_f(anv[h] + ae[m * H + h]) - mx[h]);
    }
#pragma unroll
    for (int o = 1; o <= 4; o <<= 1) dn += __shfl_xor(dn, o, 64);
#pragma unroll
    for (int h = 0; h < H; h++) {
#pragma unroll
        for (int o = 1; o <= 4; o <<= 1) sm[h] += __shfl_xor(sm[h], o, 64);
    }
    if (valid && li == 0) {
        float Dv = dn > 0.f ? 1.0f / dn : 0.0f;
        if (H == 2) {
            *(float4*)(nsp + (size_t)n * 8) = make_float4(anv[0], anv[H - 1], mx[0], mx[H - 1]);
            *(float4*)(nsp + (size_t)n * 8 + 4) =
                make_float4(1.f / sm[0], 1.f / sm[H - 1], 0.5f * Dv, 0.f);
        } else {
            *(float4*)(nsp + (size_t)n * 4) = make_float4(anv[0], mx[0], 1.f / sm[0], Dv);
        }
    }
}

// S[h][m][:] = sum_k p[e,h] * BN(X[he_n[e], :])   (8 groups x 32 lanes x float4)
template <int H>
__global__ __launch_bounds__(256) void s_build(const float* __restrict__ X,
                                               const float* __restrict__ AB,
                                               const int* __restrict__ he_nT,
                                               const float* __restrict__ nsp,
                                               const float* __restrict__ ae,
                                               float* __restrict__ S) {
    __shared__ int idx[KPB];
    __shared__ float av[KPB][H];
    __shared__ float red[8][H][128];
    int m = blockIdx.x, t = threadIdx.x;
    int g = t >> 5, l = t & 31;
    if (t < KPB) {
        int nd = he_nT[m * KPB + t];
        idx[t] = nd;
        if (H == 2) {
            float4 pa = *(const float4*)(nsp + (size_t)nd * 8);
            float4 pb = *(const float4*)(nsp + (size_t)nd * 8 + 4);
            float2 a2 = *(const float2*)(ae + (size_t)m * 2);
            av[t][0] = expf(lrelu_f(pa.x + a2.x) - pa.z) * pb.x;
            av[t][H - 1] = expf(lrelu_f(pa.y + a2.y) - pa.w) * pb.y;
        } else {
            float4 pa = *(const float4*)(nsp + (size_t)nd * 4);
            float aem = ae[m];
            av[t][0] = expf(lrelu_f(pa.x + aem) - pa.y) * pa.z;
        }
    }
    __syncthreads();
    float4 A4 = ((const float4*)AB)[l];
    float4 B4 = ((const float4*)(AB + 128))[l];
    float4 acc[H];
#pragma unroll
    for (int h = 0; h < H; h++) acc[h] = make_float4(0.f, 0.f, 0.f, 0.f);
#pragma unroll
    for (int kk = 0; kk < KPB / 8; kk++) {
        int k = g + kk * 8;
        float4 v = ((const float4*)(X + (size_t)idx[k] * 128))[l];
        v.x = v.x * A4.x + B4.x;
        v.y = v.y * A4.y + B4.y;
        v.z = v.z * A4.z + B4.z;
        v.w = v.w * A4.w + B4.w;
#pragma unroll
        for (int h = 0; h < H; h++) {
            float a = av[k][h];
            acc[h].x = fmaf(a, v.x, acc[h].x);
            acc[h].y = fmaf(a, v.y, acc[h].y);
            acc[h].z = fmaf(a, v.z, acc[h].z);
            acc[h].w = fmaf(a, v.w, acc[h].w);
        }
    }
#pragma unroll
    for (int h = 0; h < H; h++) *(float4*)&red[g][h][l * 4] = acc[h];
    __syncthreads();
    if (t < 32 * H) {
        int h = t >> 5, l2 = t & 31;
        float4 s = make_float4(0.f, 0.f, 0.f, 0.f);
#pragma unroll
        for (int gg = 0; gg < 8; gg++) {
            float4 r = *(const float4*)&red[gg][h][l2 * 4];
            s.x += r.x; s.y += r.y; s.z += r.z; s.w += r.w;
        }
        ((float4*)(S + ((size_t)h * Mm + m) * 128))[l2] = s;
    }
}

// node_agg v5: wave = 4 consecutive nodes; staging recomputes per-slot {m, c0[,c1]} from
// eid+nsp+ae; main loop j-segmented with named accumulators. Fence-free stats. In-place T.
template <int H>
__global__ __launch_bounds__(256) void node_agg(const int* __restrict__ offs,
                                                const int* __restrict__ eid,
                                                const float* __restrict__ nsp,
                                                const float* __restrict__ ae,
                                                const float* __restrict__ eo,
                                                const float* __restrict__ bias,
                                                const float* __restrict__ AB,
                                                float* __restrict__ stF,
                                                float* __restrict__ T) {
    __shared__ float smem[4][256];
    __shared__ float redS[4][128], redQ[4][128];
    int t = threadIdx.x;
    int w = t >> 6, lane = t & 63;
    int n0 = blockIdx.x * 16 + w * 4;
    int o = offs[n0 + (lane < 4 ? lane : 4)];
    int b0 = __shfl(o, 0, 64);
    int b1 = __shfl(o, 1, 64);
    int b2 = __shfl(o, 2, 64);
    int b3 = __shfl(o, 3, 64);
    int b4 = __shfl(o, 4, 64);
    int cnt = b4 - b0;
    int cnt64 = cnt < 64 ? cnt : 64;

    if (lane < cnt64) {
        int slot = b0 + lane;
        int j = (slot >= b1) + (slot >= b2) + (slot >= b3);
        int e = eid[slot];
        int m = e % Mm;
        if (H == 2) {
            float4 pa = *(const float4*)(nsp + (size_t)(n0 + j) * 8);
            float4 pb = *(const float4*)(nsp + (size_t)(n0 + j) * 8 + 4);
            float2 a2 = *(const float2*)(ae + (size_t)m * 2);
            float c0 = expf(lrelu_f(pa.x + a2.x) - pa.z) * pb.x * pb.z;
            float c1 = expf(lrelu_f(pa.y + a2.y) - pa.w) * pb.y * pb.z;
            *(float4*)&smem[w][4 * lane] = make_float4(__int_as_float(m), c0, c1, 0.f);
        } else {
            float4 pa = *(const float4*)(nsp + (size_t)(n0 + j) * 4);
            float c = expf(lrelu_f(pa.x + ae[m]) - pa.y) * pa.z * pa.w;
            *(float2*)&smem[w][2 * lane] = make_float2(__int_as_float(m), c);
        }
    }
    __syncthreads();

    int s1 = min(b1 - b0, cnt64), s2 = min(b2 - b0, cnt64), s3 = min(b3 - b0, cnt64);
    float2 acc0 = make_float2(0.f, 0.f), acc1 = acc0, acc2 = acc0, acc3 = acc0;

#define NA_BODY(ACC, CBEG, CEND)                                                \
    {                                                                           \
        int c = (CBEG);                                                         \
        for (; c + 1 < (CEND); c += 2) {                                        \
            if (H == 2) {                                                       \
                float4 sa = *(const float4*)&smem[w][4 * c];                    \
                float4 sb = *(const float4*)&smem[w][4 * (c + 1)];              \
                float4 ea = *(const float4*)(eo + (size_t)__float_as_int(sa.x) * 256 + 4 * lane); \
                float4 eb = *(const float4*)(eo + (size_t)__float_as_int(sb.x) * 256 + 4 * lane); \
                ACC.x += sa.y * ea.x + sa.z * ea.z + sb.y * eb.x + sb.z * eb.z; \
                ACC.y += sa.y * ea.y + sa.z * ea.w + sb.y * eb.y + sb.z * eb.w; \
            } else {                                                            \
                float2 sa = *(const float2*)&smem[w][2 * c];                    \
                float2 sb = *(const float2*)&smem[w][2 * (c + 1)];              \
                float2 ea = *(const float2*)(eo + (size_t)__float_as_int(sa.x) * 128 + 2 * lane); \
                float2 eb = *(const float2*)(eo + (size_t)__float_as_int(sb.x) * 128 + 2 * lane); \
                ACC.x += sa.y * ea.x + sb.y * eb.x;                             \
                ACC.y += sa.y * ea.y + sb.y * eb.y;                             \
            }                                                                   \
        }                                                                       \
        if (c < (CEND)) {                                                       \
            if (H == 2) {                                                       \
                float4 sa = *(const float4*)&smem[w][4 * c];                    \
                float4 ea = *(const float4*)(eo + (size_t)__float_as_int(sa.x) * 256 + 4 * lane); \
                ACC.x += sa.y * ea.x + sa.z * ea.z;                             \
                ACC.y += sa.y * ea.y + sa.z * ea.w;                             \
            } else {                                                            \
                float2 sa = *(const float2*)&smem[w][2 * c];                    \
                float2 ea = *(const float2*)(eo + (size_t)__float_as_int(sa.x) * 128 + 2 * lane); \
                ACC.x += sa.y * ea.x;                                           \
                ACC.y += sa.y * ea.y;                                           \
            }                                                                   \
        }                                                                       \
    }
    NA_BODY(acc0, 0, s1)
    NA_BODY(acc1, s1, s2)
    NA_BODY(acc2, s2, s3)
    NA_BODY(acc3, s3, cnt64)
#undef NA_BODY

    for (int ss = 64; ss < cnt; ss++) {  // rare tail (cnt > 64): recompute coef inline
        int slot = b0 + ss;
        int j = (slot >= b1) + (slot >= b2) + (slot >= b3);
        int e = eid[slot];
        int m = e % Mm;
        float cx, cy;
        if (H == 2) {
            float4 pa = *(const float4*)(nsp + (size_t)(n0 + j) * 8);
            float4 pb = *(const float4*)(nsp + (size_t)(n0 + j) * 8 + 4);
            float2 a2 = *(const float2*)(ae + (size_t)m * 2);
            float c0 = expf(lrelu_f(pa.x + a2.x) - pa.z) * pb.x * pb.z;
            float c1 = expf(lrelu_f(pa.y + a2.y) - pa.w) * pb.y * pb.z;
            float4 ev = *(const float4*)(eo + (size_t)m * 256 + 4 * lane);
            cx = c0 * ev.x + c1 * ev.z;
            cy = c0 * ev.y + c1 * ev.w;
        } else {
            float4 pa = *(const float4*)(nsp + (size_t)(n0 + j) * 4);
            float c = expf(lrelu_f(pa.x + ae[m]) - pa.y) * pa.z * pa.w;
            float2 ev = *(const float2*)(eo + (size_t)m * 128 + 2 * lane);
            cx = c * ev.x;
            cy = c * ev.y;
        }
        if (j == 0) { acc0.x += cx; acc0.y += cy; }
        else if (j == 1) { acc1.x += cx; acc1.y += cy; }
        else if (j == 2) { acc2.x += cx; acc2.y += cy; }
        else { acc3.x += cx; acc3.y += cy; }
    }

    int col = 2 * lane;
    float2 A2 = *(const float2*)(AB + col);
    float2 B2 = *(const float2*)(AB + 128 + col);
    float2 bi = *(const float2*)(bias + col);
    float cs0 = 0.f, cs1 = 0.f, cq0 = 0.f, cq1 = 0.f;
    float2 accs[4] = {acc0, acc1, acc2, acc3};
#pragma unroll
    for (int j = 0; j < 4; j++) {
        int n = n0 + j;
        float2 xr = *(const float2*)(T + (size_t)n * 128 + col);
        float r0 = xr.x * A2.x + B2.x + bi.x + accs[j].x;
        float r1 = xr.y * A2.y + B2.y + bi.y + accs[j].y;
        *(float2*)(T + (size_t)n * 128 + col) = make_float2(r0, r1);
        cs0 += r0; cs1 += r1;
        cq0 += r0 * r0; cq1 += r1 * r1;
    }
    redS[w][col] = cs0; redS[w][col + 1] = cs1;
    redQ[w][col] = cq0; redQ[w][col + 1] = cq1;
    __syncthreads();
    if (t < 128) {
        float s = 0.f, qq = 0.f;
#pragma unroll
        for (int ww = 0; ww < 4; ww++) { s += redS[ww][t]; qq += redQ[ww][t]; }
        int bkt = blockIdx.x & (NBKT - 1);
        atomicAdd(&stF[bkt * 256 + t], s);
        atomicAdd(&stF[bkt * 256 + 128 + t], qq);
    }
}

extern "C" void kernel_launch(void* const* d_in, const int* in_sizes, int n_in,
                              void* d_out, int out_size, void* d_ws, size_t ws_size,
                              hipStream_t stream) {
    const float* x = (const float*)d_in[0];
    const int* he_n = (const int*)d_in[1];
    const float* he_w = (const float*)d_in[3];
    const float* lin1_w = (const float*)d_in[4];
    const float* lin1_b = (const float*)d_in[5];
    const float* bn1_g = (const float*)d_in[6];
    const float* bn1_b = (const float*)d_in[7];
    const float* h1_w = (const float*)d_in[8];
    const float* h1_att = (const float*)d_in[9];
    const float* h1_b = (const float*)d_in[10];
    const float* bn2_g = (const float*)d_in[11];
    const float* bn2_b = (const float*)d_in[12];
    const float* h2_w = (const float*)d_in[13];
    const float* h2_att = (const float*)d_in[14];
    const float* h2_b = (const float*)d_in[15];
    const float* bn3_g = (const float*)d_in[16];
    const float* bn3_b = (const float*)d_in[17];
    const float* lin2_w = (const float*)d_in[18];
    const float* lin2_b = (const float*)d_in[19];
    const float* bn4_g = (const float*)d_in[20];
    const float* bn4_b = (const float*)d_in[21];
    float* out = (float*)d_out;

    char* ws = (char*)d_ws;
    size_t off = 0;
    auto alloc = [&](size_t bytes) -> char* {
        char* p = ws + off;
        off = (off + bytes + 255) & ~(size_t)255;
        return p;
    };
    // --- zeroed region (one memset) ---
    int* counts = (int*)alloc((size_t)Nn * 4);
    int* cursor = (int*)alloc((size_t)Nn * 4);
    float* stats = (float*)alloc((size_t)4 * NBKT * 256 * 4);
    size_t zbytes = off;
    // --- rest ---
    int* offs = (int*)alloc((size_t)(Nn + 1) * 4);
    int* eid = (int*)alloc((size_t)Ee * 4);
    int* he_nT = (int*)alloc((size_t)Ee * 4);
    float* an = (float*)alloc((size_t)Nn * 2 * 4);
    float* pe = (float*)alloc((size_t)Nn * 2 * 4);
    float* ae = (float*)alloc((size_t)Mm * 2 * 4);
    float* nsp = (float*)alloc((size_t)Nn * 8 * 4);
    float* S = (float*)alloc((size_t)2 * Mm * 128 * 4);
    float* eo = (float*)alloc((size_t)2 * Mm * 128 * 4);
    float* wnA = (float*)alloc(384 * 4);
    float* weA = (float*)alloc(384 * 4);
    float* AB = (float*)alloc(2 * 256 * 4);
    unsigned short* bfH = (unsigned short*)alloc((size_t)2 * 16384 * 2);
    unsigned short* bfL = (unsigned short*)alloc((size_t)2 * 16384 * 2);
    float* buf = (float*)alloc((size_t)Nn * 128 * 4);

    float* st0 = stats;
    float* st1 = stats + NBKT * 256;
    float* st2 = stats + 2 * NBKT * 256;
    float* st3 = stats + 3 * NBKT * 256;
    float *AB1 = AB, *AB2 = AB + 256;

    hipMemsetAsync(d_ws, 0, zbytes, stream);

    constexpr int GB32M = (Nn + 31) / 32;   // 1563
    // CSR count + he_n transpose (+watt block 1250, +bf16 weight-pack block 1251)
    count_edges_watt<<<1252, 256, 0, stream>>>(he_n, counts, h1_w, h1_att, h2_w, h2_att,
                                               wnA, weA, he_nT, lin1_w, lin2_w, bfH, bfL);

    // stage 1: buf = lrelu(x@lin1_w + b) via bf16x3 MFMA; bn1 stats; +49 scan blocks
    gemmM<true, false, false, true, true><<<GB32M + NBSCAN, 256, 0, stream>>>(
        x, bfH, bfL, lin1_b, nullptr, nullptr, nullptr, nullptr, st0, buf, Nn,
        GB32M, counts, offs);
    // bn1 dots (finalizes st0 in-kernel; block 0 publishes AB1); +1250 blocks run fill_csr
    bn_dots<2, true><<<3125 + 1250, 256, 0, stream>>>(buf, st0, bn1_g, bn1_b, AB1, wnA, weA,
                                                      an, pe, he_n, offs, cursor, eid, 3125);

    // hgconv1 (H=2); BN1 applied inline from AB1
    ea_from_pe<2><<<Mm / 4, 256, 0, stream>>>(he_nT, pe, ae);
    seg_softmax<2><<<(Nn + 31) / 32, 256, 0, stream>>>(offs, eid, an, ae, he_w, nsp);
    s_build<2><<<Mm, 256, 0, stream>>>(buf, AB1, he_nT, nsp, ae, S);
    gemmT<32, true><<<dim3(125, 2), 256, 0, stream>>>(
        S, (size_t)Mm * 128, h1_w, 256, BINV, eo, 256, Mm);
    node_agg<2><<<3125, 256, 0, stream>>>(offs, eid, nsp, ae, eo, h1_b, AB1, st1, buf);

    // stage 2 dots (finalizes st1 -> AB2)
    bn_dots<1, false><<<3125, 256, 0, stream>>>(buf, st1, bn2_g, bn2_b, AB2, wnA + 256,
                                                weA + 256, an, pe, nullptr, nullptr, nullptr,
                                                nullptr, 3125);

    // hgconv2 (H=1); BN2 applied inline from AB2
    ea_from_pe<1><<<Mm / 4, 256, 0, stream>>>(he_nT, pe, ae);
    seg_softmax<1><<<(Nn + 31) / 32, 256, 0, stream>>>(offs, eid, an, ae, he_w, nsp);
    s_build<1><<<Mm, 256, 0, stream>>>(buf, AB2, he_nT, nsp, ae, S);
    gemmT<32, false><<<dim3(125, 1), 256, 0, stream>>>(
        S, 0, h2_w, 128, BINV, eo, 128, Mm);
    node_agg<1><<<3125, 256, 0, stream>>>(offs, eid, nsp, ae, eo, h2_b, AB2, st2, buf);

    // lin2 via bf16x3 MFMA: in-kernel BN3 finalize+apply prologue, lrelu+resid+bn4 stats
    gemmM<true, true, true, true, false><<<GB32M, 256, 0, stream>>>(
        buf, bfH + 16384, bfL + 16384, lin2_b, st2, bn3_g, bn3_b, x, st3, buf, Nn,
        GB32M, nullptr, nullptr);
    // final BN4: in-kernel finalize (st3) + apply
    bn_out<<<3125, 256, 0, stream>>>(buf, st3, bn4_g, bn4_b, out);
}

// Round 6
// 378.152 us; speedup vs baseline: 1.0769x; 1.0769x over previous
//
#include <hip/hip_runtime.h>
#include <hip/hip_fp16.h>
#include <math.h>

constexpr int Nn = 50000;
constexpr int Mm = 4000;
constexpr int Ee = 320000;
constexpr int KPB = Ee / Mm;           // 80 entries per hyperedge (he_e = i % M)
constexpr float BINV = 1.0f / (float)KPB;
constexpr float EPSf = 1e-5f;
constexpr int NBKT = 16;               // stat buckets (fp32 atomics, no fence!)
constexpr int NBSCAN = 49;             // scan blocks (1024 nodes each)

__device__ __forceinline__ float lrelu_f(float x) { return x >= 0.f ? x : 0.2f * x; }

__device__ __forceinline__ unsigned short f2h(float f) {
    __half h = __float2half_rn(f);
    return *reinterpret_cast<unsigned short*>(&h);
}
__device__ __forceinline__ float h2f(unsigned short s) {
    __half_raw r; r.x = s;
    return __half2float(__half(r));
}

__device__ __forceinline__ float wave_sum(float v) {
#pragma unroll
    for (int o = 32; o >= 1; o >>= 1) v += __shfl_xor(v, o, 64);
    return v;
}

// Consumer-side BN finalize: stats buckets (prev kernel's fp32 atomics) -> AB in LDS.
__device__ __forceinline__ void finalize_to_lds(const float* __restrict__ st,
                                                const float* __restrict__ g,
                                                const float* __restrict__ b,
                                                float* ABsh, int t) {
    if (t < 128) {
        double ds = 0, dq = 0;
#pragma unroll
        for (int i = 0; i < NBKT; i++) {
            ds += (double)st[i * 256 + t];
            dq += (double)st[i * 256 + 128 + t];
        }
        double mean = ds / (double)Nn;
        double var = dq / (double)Nn - mean * mean;
        float rstd = (float)(1.0 / sqrt(var + (double)EPSf));
        float A = g[t] * rstd;
        ABsh[t] = A;
        ABsh[128 + t] = b[t] - (float)mean * A;
    }
    __syncthreads();
}

// exclusive scan of counts -> offs; block b handles nodes [b*1024, b*1024+1024)
__device__ void scan_body(const int* __restrict__ counts, int* __restrict__ offs,
                          int b, int t) {
    __shared__ int sdi[256];
    int pre = 0;
    for (int i = t; i < b * 1024; i += 256) pre += counts[i];
    sdi[t] = pre;
    __syncthreads();
    for (int st = 128; st >= 1; st >>= 1) {
        if (t < st) sdi[t] += sdi[t + st];
        __syncthreads();
    }
    int run0 = sdi[0];
    __syncthreads();
    int c4[4];
    int s = 0;
#pragma unroll
    for (int i = 0; i < 4; i++) {
        int n = b * 1024 + t * 4 + i;
        c4[i] = (n < Nn) ? counts[n] : 0;
        s += c4[i];
    }
    sdi[t] = s;
    __syncthreads();
    for (int off = 1; off < 256; off <<= 1) {
        int v = (t >= off) ? sdi[t - off] : 0;
        __syncthreads();
        sdi[t] += v;
        __syncthreads();
    }
    int run = sdi[t] - s + run0;
#pragma unroll
    for (int i = 0; i < 4; i++) {
        int n = b * 1024 + t * 4 + i;
        if (n < Nn) offs[n] = run;
        run += c4[i];
    }
    if (b == NBSCAN - 1 && t == 255) offs[Nn] = run0 + sdi[255];
}

// ---------------- GEMM: C[R, bcol:+128] = op(op_bn(A[R,128]) @ B[:, bcol:+128]) -------------
// BK=16, A-tile transposed in LDS. ROWS=32 for the Nn gemms (R1 best config).
// PROBN: in-kernel BN finalize + apply on A load. PACKH2: eo col-pair interleave (h=blockIdx.y).
// STATS: bucketed fp32 atomics (fence-free). SCANX: extra x-blocks run the CSR offset scan.
template <int ROWS, bool LRELU, bool PROBN, bool RESID, bool STATS, bool PACKH2, bool SCANX>
__global__ __launch_bounds__(256) void gemmT(const float* __restrict__ A, size_t aystride,
                                             const float* __restrict__ B, int ldb,
                                             const float* __restrict__ bias, float scale,
                                             const float* __restrict__ stIn,
                                             const float* __restrict__ fing,
                                             const float* __restrict__ finb,
                                             const float* __restrict__ resid,
                                             float* __restrict__ stF,
                                             float* __restrict__ C, int ldc, int R,
                                             int gemmBlocksX,
                                             const int* __restrict__ counts,
                                             int* __restrict__ offs) {
    constexpr int RPT = ROWS / 16;
    const int t = threadIdx.x;
    if (SCANX && (int)blockIdx.x >= gemmBlocksX) {
        if (blockIdx.y == 0) scan_body(counts, offs, blockIdx.x - gemmBlocksX, t);
        return;
    }
    __shared__ float As[16][ROWS + 4];
    __shared__ float Bs[16][128];
    __shared__ float Sred[STATS ? 16 : 1][STATS ? 128 : 1];
    __shared__ float ABsh[PROBN ? 256 : 1];
    const int ty = t >> 4, tx = t & 15;
    const int row0 = blockIdx.x * ROWS;
    const int bcol = blockIdx.y * 128;
    A += (size_t)blockIdx.y * aystride;

    if (PROBN) finalize_to_lds(stIn, fing, finb, ABsh, t);

    float4 acc[RPT][2];
#pragma unroll
    for (int i = 0; i < RPT; i++)
#pragma unroll
        for (int q = 0; q < 2; q++) acc[i][q] = make_float4(0.f, 0.f, 0.f, 0.f);

    for (int k0 = 0; k0 < 128; k0 += 16) {
        if (ROWS == 64) {
            int r = t >> 2, kc = (t & 3) * 4;
            int rr = row0 + r;
            rr = rr < R ? rr : R - 1;
            float4 av = *(const float4*)(A + (size_t)rr * 128 + k0 + kc);
            if (PROBN) {
                float4 sA = *(const float4*)&ABsh[k0 + kc];
                float4 sB = *(const float4*)&ABsh[128 + k0 + kc];
                av.x = av.x * sA.x + sB.x; av.y = av.y * sA.y + sB.y;
                av.z = av.z * sA.z + sB.z; av.w = av.w * sA.w + sB.w;
            }
            As[kc + 0][r] = av.x; As[kc + 1][r] = av.y;
            As[kc + 2][r] = av.z; As[kc + 3][r] = av.w;
        } else {  // ROWS == 32
            int r = t >> 3, kc = (t & 7) * 2;
            int rr = row0 + r;
            rr = rr < R ? rr : R - 1;
            float2 av = *(const float2*)(A + (size_t)rr * 128 + k0 + kc);
            if (PROBN) {
                av.x = av.x * ABsh[k0 + kc] + ABsh[128 + k0 + kc];
                av.y = av.y * ABsh[k0 + kc + 1] + ABsh[128 + k0 + kc + 1];
            }
            As[kc + 0][r] = av.x;
            As[kc + 1][r] = av.y;
        }
        {
            int kk = t >> 5, c4 = (t & 31) * 4;
            float4 bv0 = *(const float4*)(B + (size_t)(k0 + kk) * ldb + bcol + c4);
            float4 bv1 = *(const float4*)(B + (size_t)(k0 + kk + 8) * ldb + bcol + c4);
            *(float4*)&Bs[kk][c4] = bv0;
            *(float4*)&Bs[kk + 8][c4] = bv1;
        }
        __syncthreads();
#pragma unroll
        for (int kk = 0; kk < 16; kk++) {
            float ar[RPT];
            if (RPT == 4) {
                float4 a4 = *(const float4*)&As[kk][ty * 4];
                ar[0] = a4.x; ar[1] = a4.y; ar[2] = a4.z; ar[3] = a4.w;
            } else {
                float2 a2 = *(const float2*)&As[kk][ty * 2];
                ar[0] = a2.x; ar[RPT - 1] = a2.y;
            }
            float4 b0 = *(const float4*)&Bs[kk][4 * tx];
            float4 b1 = *(const float4*)&Bs[kk][64 + 4 * tx];
#pragma unroll
            for (int i = 0; i < RPT; i++) {
                acc[i][0].x = fmaf(ar[i], b0.x, acc[i][0].x);
                acc[i][0].y = fmaf(ar[i], b0.y, acc[i][0].y);
                acc[i][0].z = fmaf(ar[i], b0.z, acc[i][0].z);
                acc[i][0].w = fmaf(ar[i], b0.w, acc[i][0].w);
                acc[i][1].x = fmaf(ar[i], b1.x, acc[i][1].x);
                acc[i][1].y = fmaf(ar[i], b1.y, acc[i][1].y);
                acc[i][1].z = fmaf(ar[i], b1.z, acc[i][1].z);
                acc[i][1].w = fmaf(ar[i], b1.w, acc[i][1].w);
            }
        }
        __syncthreads();
    }

    float4 bv0 = make_float4(0.f, 0.f, 0.f, 0.f), bv1 = bv0;
    if (bias) {
        bv0 = *(const float4*)(bias + bcol + 4 * tx);
        bv1 = *(const float4*)(bias + bcol + 64 + 4 * tx);
    }
    float4 cs0 = make_float4(0.f, 0.f, 0.f, 0.f), cs1 = cs0, cq0 = cs0, cq1 = cs0;
#pragma unroll
    for (int i = 0; i < RPT; i++) {
        int row = row0 + ty * RPT + i;
        if (row >= R) continue;
        float4 v0, v1;
        v0.x = acc[i][0].x * scale + bv0.x; v0.y = acc[i][0].y * scale + bv0.y;
        v0.z = acc[i][0].z * scale + bv0.z; v0.w = acc[i][0].w * scale + bv0.w;
        v1.x = acc[i][1].x * scale + bv1.x; v1.y = acc[i][1].y * scale + bv1.y;
        v1.z = acc[i][1].z * scale + bv1.z; v1.w = acc[i][1].w * scale + bv1.w;
        if (LRELU) {
            v0.x = lrelu_f(v0.x); v0.y = lrelu_f(v0.y); v0.z = lrelu_f(v0.z); v0.w = lrelu_f(v0.w);
            v1.x = lrelu_f(v1.x); v1.y = lrelu_f(v1.y); v1.z = lrelu_f(v1.z); v1.w = lrelu_f(v1.w);
        }
        if (RESID) {
            float4 r0 = *(const float4*)(resid + (size_t)row * 128 + bcol + 4 * tx);
            float4 r1 = *(const float4*)(resid + (size_t)row * 128 + bcol + 64 + 4 * tx);
            v0.x += r0.x; v0.y += r0.y; v0.z += r0.z; v0.w += r0.w;
            v1.x += r1.x; v1.y += r1.y; v1.z += r1.z; v1.w += r1.w;
        }
        if (PACKH2) {
            int h = blockIdx.y;
            float* c0 = C + (size_t)row * ldc + 8 * tx + 2 * h;
            *(float2*)(c0) = make_float2(v0.x, v0.y);
            *(float2*)(c0 + 4) = make_float2(v0.z, v0.w);
            float* c1 = C + (size_t)row * ldc + 128 + 8 * tx + 2 * h;
            *(float2*)(c1) = make_float2(v1.x, v1.y);
            *(float2*)(c1 + 4) = make_float2(v1.z, v1.w);
        } else {
            *(float4*)(C + (size_t)row * ldc + bcol + 4 * tx) = v0;
            *(float4*)(C + (size_t)row * ldc + bcol + 64 + 4 * tx) = v1;
        }
        if (STATS) {
            cs0.x += v0.x; cs0.y += v0.y; cs0.z += v0.z; cs0.w += v0.w;
            cs1.x += v1.x; cs1.y += v1.y; cs1.z += v1.z; cs1.w += v1.w;
            cq0.x += v0.x * v0.x; cq0.y += v0.y * v0.y; cq0.z += v0.z * v0.z; cq0.w += v0.w * v0.w;
            cq1.x += v1.x * v1.x; cq1.y += v1.y * v1.y; cq1.z += v1.z * v1.z; cq1.w += v1.w * v1.w;
        }
    }
    if (STATS) {
        int bkt = blockIdx.x & (NBKT - 1);
#pragma unroll
        for (int pass = 0; pass < 2; pass++) {
            *(float4*)&Sred[ty][4 * tx] = pass ? cq0 : cs0;
            *(float4*)&Sred[ty][64 + 4 * tx] = pass ? cq1 : cs1;
            __syncthreads();
            if (t < 128) {
                float tot = 0.f;
#pragma unroll
                for (int r = 0; r < 16; r++) tot += Sred[r][t];
                atomicAdd(&stF[bkt * 256 + pass * 128 + t], tot);
            }
            __syncthreads();
        }
    }
}

// ---------------- CSR count + he_n transpose (+watt folded into extra block) ----------------
__global__ void count_edges_watt(const int* __restrict__ he_n, int* __restrict__ counts,
                                 const float* __restrict__ h1_w, const float* __restrict__ h1_att,
                                 const float* __restrict__ h2_w, const float* __restrict__ h2_att,
                                 float* __restrict__ wnA, float* __restrict__ weA,
                                 int* __restrict__ he_nT) {
    int t = threadIdx.x;
    if (blockIdx.x == 1250) {
        for (int j = 0; j < 3; j++) {
            int id = t + 256 * j;
            if (id >= 768) break;
            int which = id / 384;
            int rem = id % 384;
            int h3 = rem >> 7, k = rem & 127;
            float s = 0.f;
            if (h3 < 2) {
                const float* wrow = h1_w + (size_t)k * 256 + h3 * 128;
                const float* arow = h1_att + h3 * 256 + which * 128;
                for (int c = 0; c < 128; c++) s += wrow[c] * arow[c];
            } else {
                const float* wrow = h2_w + (size_t)k * 128;
                const float* arow = h2_att + which * 128;
                for (int c = 0; c < 128; c++) s += wrow[c] * arow[c];
            }
            (which ? weA : wnA)[h3 * 128 + k] = s;
        }
        return;
    }
    int g = blockIdx.x * 256 + t;
    if (g < Ee) {
        int m = g / KPB;
        int k = g - m * KPB;
        int n = he_n[m + (size_t)k * Mm];
        he_nT[g] = n;
        atomicAdd(&counts[n], 1);
    }
}

// ---------------- BN dots (+in-kernel finalize; block 0 publishes AB; +fill_csr fold) ------
// NEW (R6): also emits bufh = fp16(BN(X)) -- the half-width gather source for s_build.
template <int H, bool FILL>
__global__ __launch_bounds__(256) void bn_dots(const float* __restrict__ X,
                                               const float* __restrict__ stIn,
                                               const float* __restrict__ fing,
                                               const float* __restrict__ finb,
                                               float* __restrict__ ABout,
                                               const float* __restrict__ wn,
                                               const float* __restrict__ we,
                                               float* __restrict__ an,
                                               float* __restrict__ pe,
                                               unsigned short* __restrict__ bufh,
                                               const int* __restrict__ he_n,
                                               const int* __restrict__ offs,
                                               int* __restrict__ cursor,
                                               int* __restrict__ eid, int mainBlocks) {
    int t = threadIdx.x;
    if (FILL && (int)blockIdx.x >= mainBlocks) {
        int e = (blockIdx.x - mainBlocks) * 256 + t;
        if (e < Ee) {
            int n = he_n[e];
            int p = atomicAdd(&cursor[n], 1);
            eid[offs[n] + p] = e;
        }
        return;
    }
    __shared__ float ABsh[256];
    finalize_to_lds(stIn, fing, finb, ABsh, t);
    if (blockIdx.x == 0) ABout[t] = ABsh[t];
    int w = t >> 6, lane = t & 63;
    float a0 = ABsh[lane], a1 = ABsh[lane + 64];
    float b0 = ABsh[128 + lane], b1 = ABsh[192 + lane];
    float wn0[H], wn1[H], we0[H], we1[H];
#pragma unroll
    for (int h = 0; h < H; h++) {
        wn0[h] = wn[h * 128 + lane]; wn1[h] = wn[h * 128 + 64 + lane];
        we0[h] = we[h * 128 + lane]; we1[h] = we[h * 128 + 64 + lane];
    }
#pragma unroll
    for (int nn = 0; nn < 4; nn++) {
        int row = blockIdx.x * 16 + w * 4 + nn;
        const float* xr = X + (size_t)row * 128;
        float v0 = xr[lane] * a0 + b0;
        float v1 = xr[lane + 64] * a1 + b1;
        bufh[(size_t)row * 128 + lane] = f2h(v0);
        bufh[(size_t)row * 128 + 64 + lane] = f2h(v1);
        float pv[H], qv[H];
#pragma unroll
        for (int h = 0; h < H; h++) {
            pv[h] = wave_sum(v0 * wn0[h] + v1 * wn1[h]);
            qv[h] = wave_sum(v0 * we0[h] + v1 * we1[h]);
        }
        if (lane == 0) {
            if (H == 2) {
                *(float2*)&an[row * 2] = make_float2(pv[0], pv[1]);
                *(float2*)&pe[row * 2] = make_float2(qv[0], qv[1]);
            } else {
                an[row] = pv[0];
                pe[row] = qv[0];
            }
        }
    }
}

// final elementwise BN apply with in-kernel finalize (16 rows/block)
__global__ __launch_bounds__(256) void bn_out(const float* __restrict__ X,
                                              const float* __restrict__ stIn,
                                              const float* __restrict__ fing,
                                              const float* __restrict__ finb,
                                              float* __restrict__ Y) {
    __shared__ float ABsh[256];
    int t = threadIdx.x;
    finalize_to_lds(stIn, fing, finb, ABsh, t);
    int w = t >> 6, lane = t & 63;
    float a0 = ABsh[lane], a1 = ABsh[lane + 64];
    float b0 = ABsh[128 + lane], b1 = ABsh[192 + lane];
#pragma unroll
    for (int nn = 0; nn < 4; nn++) {
        int row = blockIdx.x * 16 + w * 4 + nn;
        const float* xr = X + (size_t)row * 128;
        float* yr = Y + (size_t)row * 128;
        yr[lane] = xr[lane] * a0 + b0;
        yr[lane + 64] = xr[lane + 64] * a1 + b1;
    }
}

// ae[m,h] = sum over the 80 member nodes of pe[node,h]  (coalesced via he_nT)
template <int H>
__global__ __launch_bounds__(256) void ea_from_pe(const int* __restrict__ he_nT,
                                                  const float* __restrict__ pe,
                                                  float* __restrict__ ae) {
    int w = threadIdx.x >> 6, lane = threadIdx.x & 63;
    int m = blockIdx.x * 4 + w;
    if (m >= Mm) return;
    float s[H];
#pragma unroll
    for (int h = 0; h < H; h++) s[h] = 0.f;
    for (int k = lane; k < KPB; k += 64) {
        int idx = he_nT[m * KPB + k];
        if (H == 2) {
            float2 p2 = *(const float2*)(pe + (size_t)idx * 2);
            s[0] += p2.x;
            s[H - 1] += p2.y;
        } else {
            s[0] += pe[idx];
        }
    }
#pragma unroll
    for (int h = 0; h < H; h++) s[h] = wave_sum(s[h]);
    if (lane == 0)
#pragma unroll
        for (int h = 0; h < H; h++) ae[m * H + h] = s[h];
}

// per-node softmax STATS ONLY; consumers recompute p from nsp:
//   H=2: nsp[n*8..] = {an0,an1,mx0,mx1} {1/sm0,1/sm1,Dinv*0.5,0}
//   H=1: nsp[n*4..] = {an, mx, 1/sm, Dinv}
template <int H>
__global__ __launch_bounds__(256) void seg_softmax(const int* __restrict__ offs,
                                                   const int* __restrict__ eid,
                                                   const float* __restrict__ an,
                                                   const float* __restrict__ ae,
                                                   const float* __restrict__ he_w,
                                                   float* __restrict__ nsp) {
    int t = threadIdx.x;
    int wv = t >> 6, lane = t & 63;
    int q = lane >> 3, li = lane & 7;
    int n = blockIdx.x * 32 + wv * 8 + q;
    bool valid = n < Nn;
    int base = valid ? offs[n] : 0;
    int deg = valid ? offs[n + 1] - base : 0;
    float anv[H];
#pragma unroll
    for (int h = 0; h < H; h++) anv[h] = valid ? an[n * H + h] : 0.f;

    bool h0 = li < deg, h1 = li + 8 < deg;
    int m0 = 0, m1 = 0;
    float l0[H], l1[H];
    float mx[H];
#pragma unroll
    for (int h = 0; h < H; h++) { mx[h] = -INFINITY; l0[h] = 0.f; l1[h] = 0.f; }
    if (h0) {
        m0 = eid[base + li] % Mm;
#pragma unroll
        for (int h = 0; h < H; h++) {
            l0[h] = lrelu_f(anv[h] + ae[m0 * H + h]);
            mx[h] = fmaxf(mx[h], l0[h]);
        }
    }
    if (h1) {
        m1 = eid[base + li + 8] % Mm;
#pragma unroll
        for (int h = 0; h < H; h++) {
            l1[h] = lrelu_f(anv[h] + ae[m1 * H + h]);
            mx[h] = fmaxf(mx[h], l1[h]);
        }
    }
    for (int c = li + 16; c < deg; c += 8) {
        int m = eid[base + c] % Mm;
#pragma unroll
        for (int h = 0; h < H; h++) mx[h] = fmaxf(mx[h], lrelu_f(anv[h] + ae[m * H + h]));
    }
#pragma unroll
    for (int h = 0; h < H; h++) {
#pragma unroll
        for (int o = 1; o <= 4; o <<= 1) mx[h] = fmaxf(mx[h], __shfl_xor(mx[h], o, 64));
    }
    float sm[H];
#pragma unroll
    for (int h = 0; h < H; h++) sm[h] = 0.f;
    float dn = 0.f;
    if (h0) {
        dn += he_w[m0];
#pragma unroll
        for (int h = 0; h < H; h++) sm[h] += expf(l0[h] - mx[h]);
    }
    if (h1) {
        dn += he_w[m1];
#pragma unroll
        for (int h = 0; h < H; h++) sm[h] += expf(l1[h] - mx[h]);
    }
    for (int c = li + 16; c < deg; c += 8) {
        int m = eid[base + c] % Mm;
        dn += he_w[m];
#pragma unroll
        for (int h = 0; h < H; h++) sm[h] += expf(lrelu_f(anv[h] + ae[m * H + h]) - mx[h]);
    }
#pragma unroll
    for (int o = 1; o <= 4; o <<= 1) dn += __shfl_xor(dn, o, 64);
#pragma unroll
    for (int h = 0; h < H; h++) {
#pragma unroll
        for (int o = 1; o <= 4; o <<= 1) sm[h] += __shfl_xor(sm[h], o, 64);
    }
    if (valid && li == 0) {
        float Dv = dn > 0.f ? 1.0f / dn : 0.0f;
        if (H == 2) {
            *(float4*)(nsp + (size_t)n * 8) = make_float4(anv[0], anv[H - 1], mx[0], mx[H - 1]);
            *(float4*)(nsp + (size_t)n * 8 + 4) =
                make_float4(1.f / sm[0], 1.f / sm[H - 1], 0.5f * Dv, 0.f);
        } else {
            *(float4*)(nsp + (size_t)n * 4) = make_float4(anv[0], mx[0], 1.f / sm[0], Dv);
        }
    }
}

// S[h][m][:] = sum_k p[e,h] * BNX_h[he_n[e], :]   (8 groups x 32 lanes)
// R6: gathers the fp16 BN-applied copy (bufh) -- 256B/row instead of 512B, no A/B fma.
template <int H>
__global__ __launch_bounds__(256) void s_build(const unsigned short* __restrict__ Xh,
                                               const int* __restrict__ he_nT,
                                               const float* __restrict__ nsp,
                                               const float* __restrict__ ae,
                                               float* __restrict__ S) {
    __shared__ int idx[KPB];
    __shared__ float av[KPB][H];
    __shared__ float red[8][H][128];
    int m = blockIdx.x, t = threadIdx.x;
    int g = t >> 5, l = t & 31;
    if (t < KPB) {
        int nd = he_nT[m * KPB + t];
        idx[t] = nd;
        if (H == 2) {
            float4 pa = *(const float4*)(nsp + (size_t)nd * 8);
            float4 pb = *(const float4*)(nsp + (size_t)nd * 8 + 4);
            float2 a2 = *(const float2*)(ae + (size_t)m * 2);
            av[t][0] = expf(lrelu_f(pa.x + a2.x) - pa.z) * pb.x;
            av[t][H - 1] = expf(lrelu_f(pa.y + a2.y) - pa.w) * pb.y;
        } else {
            float4 pa = *(const float4*)(nsp + (size_t)nd * 4);
            float aem = ae[m];
            av[t][0] = expf(lrelu_f(pa.x + aem) - pa.y) * pa.z;
        }
    }
    __syncthreads();
    float4 acc[H];
#pragma unroll
    for (int h = 0; h < H; h++) acc[h] = make_float4(0.f, 0.f, 0.f, 0.f);
#pragma unroll
    for (int kk = 0; kk < KPB / 8; kk++) {
        int k = g + kk * 8;
        ushort4 u = *(const ushort4*)(Xh + (size_t)idx[k] * 128 + l * 4);
        float vx = h2f(u.x), vy = h2f(u.y), vz = h2f(u.z), vw = h2f(u.w);
#pragma unroll
        for (int h = 0; h < H; h++) {
            float a = av[k][h];
            acc[h].x = fmaf(a, vx, acc[h].x);
            acc[h].y = fmaf(a, vy, acc[h].y);
            acc[h].z = fmaf(a, vz, acc[h].z);
            acc[h].w = fmaf(a, vw, acc[h].w);
        }
    }
#pragma unroll
    for (int h = 0; h < H; h++) *(float4*)&red[g][h][l * 4] = acc[h];
    __syncthreads();
    if (t < 32 * H) {
        int h = t >> 5, l2 = t & 31;
        float4 s = make_float4(0.f, 0.f, 0.f, 0.f);
#pragma unroll
        for (int gg = 0; gg < 8; gg++) {
            float4 r = *(const float4*)&red[gg][h][l2 * 4];
            s.x += r.x; s.y += r.y; s.z += r.z; s.w += r.w;
        }
        ((float4*)(S + ((size_t)h * Mm + m) * 128))[l2] = s;
    }
}

// node_agg v5: wave = 4 consecutive nodes; staging recomputes per-slot {m, c0[,c1]} from
// eid+nsp+ae; main loop j-segmented with named accumulators. Fence-free stats. In-place T.
template <int H>
__global__ __launch_bounds__(256) void node_agg(const int* __restrict__ offs,
                                                const int* __restrict__ eid,
                                                const float* __restrict__ nsp,
                                                const float* __restrict__ ae,
                                                const float* __restrict__ eo,
                                                const float* __restrict__ bias,
                                                const float* __restrict__ AB,
                                                float* __restrict__ stF,
                                                float* __restrict__ T) {
    __shared__ float smem[4][256];
    __shared__ float redS[4][128], redQ[4][128];
    int t = threadIdx.x;
    int w = t >> 6, lane = t & 63;
    int n0 = blockIdx.x * 16 + w * 4;
    int o = offs[n0 + (lane < 4 ? lane : 4)];
    int b0 = __shfl(o, 0, 64);
    int b1 = __shfl(o, 1, 64);
    int b2 = __shfl(o, 2, 64);
    int b3 = __shfl(o, 3, 64);
    int b4 = __shfl(o, 4, 64);
    int cnt = b4 - b0;
    int cnt64 = cnt < 64 ? cnt : 64;

    if (lane < cnt64) {
        int slot = b0 + lane;
        int j = (slot >= b1) + (slot >= b2) + (slot >= b3);
        int e = eid[slot];
        int m = e % Mm;
        if (H == 2) {
            float4 pa = *(const float4*)(nsp + (size_t)(n0 + j) * 8);
            float4 pb = *(const float4*)(nsp + (size_t)(n0 + j) * 8 + 4);
            float2 a2 = *(const float2*)(ae + (size_t)m * 2);
            float c0 = expf(lrelu_f(pa.x + a2.x) - pa.z) * pb.x * pb.z;
            float c1 = expf(lrelu_f(pa.y + a2.y) - pa.w) * pb.y * pb.z;
            *(float4*)&smem[w][4 * lane] = make_float4(__int_as_float(m), c0, c1, 0.f);
        } else {
            float4 pa = *(const float4*)(nsp + (size_t)(n0 + j) * 4);
            float c = expf(lrelu_f(pa.x + ae[m]) - pa.y) * pa.z * pa.w;
            *(float2*)&smem[w][2 * lane] = make_float2(__int_as_float(m), c);
        }
    }
    __syncthreads();

    int s1 = min(b1 - b0, cnt64), s2 = min(b2 - b0, cnt64), s3 = min(b3 - b0, cnt64);
    float2 acc0 = make_float2(0.f, 0.f), acc1 = acc0, acc2 = acc0, acc3 = acc0;

#define NA_BODY(ACC, CBEG, CEND)                                                \
    {                                                                           \
        int c = (CBEG);                                                         \
        for (; c + 1 < (CEND); c += 2) {                                        \
            if (H == 2) {                                                       \
                float4 sa = *(const float4*)&smem[w][4 * c];                    \
                float4 sb = *(const float4*)&smem[w][4 * (c + 1)];              \
                float4 ea = *(const float4*)(eo + (size_t)__float_as_int(sa.x) * 256 + 4 * lane); \
                float4 eb = *(const float4*)(eo + (size_t)__float_as_int(sb.x) * 256 + 4 * lane); \
                ACC.x += sa.y * ea.x + sa.z * ea.z + sb.y * eb.x + sb.z * eb.z; \
                ACC.y += sa.y * ea.y + sa.z * ea.w + sb.y * eb.y + sb.z * eb.w; \
            } else {                                                            \
                float2 sa = *(const float2*)&smem[w][2 * c];                    \
                float2 sb = *(const float2*)&smem[w][2 * (c + 1)];              \
                float2 ea = *(const float2*)(eo + (size_t)__float_as_int(sa.x) * 128 + 2 * lane); \
                float2 eb = *(const float2*)(eo + (size_t)__float_as_int(sb.x) * 128 + 2 * lane); \
                ACC.x += sa.y * ea.x + sb.y * eb.x;                             \
                ACC.y += sa.y * ea.y + sb.y * eb.y;                             \
            }                                                                   \
        }                                                                       \
        if (c < (CEND)) {                                                       \
            if (H == 2) {                                                       \
                float4 sa = *(const float4*)&smem[w][4 * c];                    \
                float4 ea = *(const float4*)(eo + (size_t)__float_as_int(sa.x) * 256 + 4 * lane); \
                ACC.x += sa.y * ea.x + sa.z * ea.z;                             \
                ACC.y += sa.y * ea.y + sa.z * ea.w;                             \
            } else {                                                            \
                float2 sa = *(const float2*)&smem[w][2 * c];                    \
                float2 ea = *(const float2*)(eo + (size_t)__float_as_int(sa.x) * 128 + 2 * lane); \
                ACC.x += sa.y * ea.x;                                           \
                ACC.y += sa.y * ea.y;                                           \
            }                                                                   \
        }                                                                       \
    }
    NA_BODY(acc0, 0, s1)
    NA_BODY(acc1, s1, s2)
    NA_BODY(acc2, s2, s3)
    NA_BODY(acc3, s3, cnt64)
#undef NA_BODY

    for (int ss = 64; ss < cnt; ss++) {  // rare tail (cnt > 64): recompute coef inline
        int slot = b0 + ss;
        int j = (slot >= b1) + (slot >= b2) + (slot >= b3);
        int e = eid[slot];
        int m = e % Mm;
        float cx, cy;
        if (H == 2) {
            float4 pa = *(const float4*)(nsp + (size_t)(n0 + j) * 8);
            float4 pb = *(const float4*)(nsp + (size_t)(n0 + j) * 8 + 4);
            float2 a2 = *(const float2*)(ae + (size_t)m * 2);
            float c0 = expf(lrelu_f(pa.x + a2.x) - pa.z) * pb.x * pb.z;
            float c1 = expf(lrelu_f(pa.y + a2.y) - pa.w) * pb.y * pb.z;
            float4 ev = *(const float4*)(eo + (size_t)m * 256 + 4 * lane);
            cx = c0 * ev.x + c1 * ev.z;
            cy = c0 * ev.y + c1 * ev.w;
        } else {
            float4 pa = *(const float4*)(nsp + (size_t)(n0 + j) * 4);
            float c = expf(lrelu_f(pa.x + ae[m]) - pa.y) * pa.z * pa.w;
            float2 ev = *(const float2*)(eo + (size_t)m * 128 + 2 * lane);
            cx = c * ev.x;
            cy = c * ev.y;
        }
        if (j == 0) { acc0.x += cx; acc0.y += cy; }
        else if (j == 1) { acc1.x += cx; acc1.y += cy; }
        else if (j == 2) { acc2.x += cx; acc2.y += cy; }
        else { acc3.x += cx; acc3.y += cy; }
    }

    int col = 2 * lane;
    float2 A2 = *(const float2*)(AB + col);
    float2 B2 = *(const float2*)(AB + 128 + col);
    float2 bi = *(const float2*)(bias + col);
    float cs0 = 0.f, cs1 = 0.f, cq0 = 0.f, cq1 = 0.f;
    float2 accs[4] = {acc0, acc1, acc2, acc3};
#pragma unroll
    for (int j = 0; j < 4; j++) {
        int n = n0 + j;
        float2 xr = *(const float2*)(T + (size_t)n * 128 + col);
        float r0 = xr.x * A2.x + B2.x + bi.x + accs[j].x;
        float r1 = xr.y * A2.y + B2.y + bi.y + accs[j].y;
        *(float2*)(T + (size_t)n * 128 + col) = make_float2(r0, r1);
        cs0 += r0; cs1 += r1;
        cq0 += r0 * r0; cq1 += r1 * r1;
    }
    redS[w][col] = cs0; redS[w][col + 1] = cs1;
    redQ[w][col] = cq0; redQ[w][col + 1] = cq1;
    __syncthreads();
    if (t < 128) {
        float s = 0.f, qq = 0.f;
#pragma unroll
        for (int ww = 0; ww < 4; ww++) { s += redS[ww][t]; qq += redQ[ww][t]; }
        int bkt = blockIdx.x & (NBKT - 1);
        atomicAdd(&stF[bkt * 256 + t], s);
        atomicAdd(&stF[bkt * 256 + 128 + t], qq);
    }
}

extern "C" void kernel_launch(void* const* d_in, const int* in_sizes, int n_in,
                              void* d_out, int out_size, void* d_ws, size_t ws_size,
                              hipStream_t stream) {
    const float* x = (const float*)d_in[0];
    const int* he_n = (const int*)d_in[1];
    const float* he_w = (const float*)d_in[3];
    const float* lin1_w = (const float*)d_in[4];
    const float* lin1_b = (const float*)d_in[5];
    const float* bn1_g = (const float*)d_in[6];
    const float* bn1_b = (const float*)d_in[7];
    const float* h1_w = (const float*)d_in[8];
    const float* h1_att = (const float*)d_in[9];
    const float* h1_b = (const float*)d_in[10];
    const float* bn2_g = (const float*)d_in[11];
    const float* bn2_b = (const float*)d_in[12];
    const float* h2_w = (const float*)d_in[13];
    const float* h2_att = (const float*)d_in[14];
    const float* h2_b = (const float*)d_in[15];
    const float* bn3_g = (const float*)d_in[16];
    const float* bn3_b = (const float*)d_in[17];
    const float* lin2_w = (const float*)d_in[18];
    const float* lin2_b = (const float*)d_in[19];
    const float* bn4_g = (const float*)d_in[20];
    const float* bn4_b = (const float*)d_in[21];
    float* out = (float*)d_out;

    char* ws = (char*)d_ws;
    size_t off = 0;
    auto alloc = [&](size_t bytes) -> char* {
        char* p = ws + off;
        off = (off + bytes + 255) & ~(size_t)255;
        return p;
    };
    // --- zeroed region (one memset) ---
    int* counts = (int*)alloc((size_t)Nn * 4);
    int* cursor = (int*)alloc((size_t)Nn * 4);
    float* stats = (float*)alloc((size_t)4 * NBKT * 256 * 4);
    size_t zbytes = off;
    // --- rest ---
    int* offs = (int*)alloc((size_t)(Nn + 1) * 4);
    int* eid = (int*)alloc((size_t)Ee * 4);
    int* he_nT = (int*)alloc((size_t)Ee * 4);
    float* an = (float*)alloc((size_t)Nn * 2 * 4);
    float* pe = (float*)alloc((size_t)Nn * 2 * 4);
    float* ae = (float*)alloc((size_t)Mm * 2 * 4);
    float* nsp = (float*)alloc((size_t)Nn * 8 * 4);
    float* S = (float*)alloc((size_t)2 * Mm * 128 * 4);
    float* eo = (float*)alloc((size_t)2 * Mm * 128 * 4);
    float* wnA = (float*)alloc(384 * 4);
    float* weA = (float*)alloc(384 * 4);
    float* AB = (float*)alloc(2 * 256 * 4);
    unsigned short* bufh = (unsigned short*)alloc((size_t)Nn * 128 * 2);
    float* buf = (float*)alloc((size_t)Nn * 128 * 4);

    float* st0 = stats;
    float* st1 = stats + NBKT * 256;
    float* st2 = stats + 2 * NBKT * 256;
    float* st3 = stats + 3 * NBKT * 256;
    float *AB1 = AB, *AB2 = AB + 256;

    hipMemsetAsync(d_ws, 0, zbytes, stream);

    constexpr int GB32 = (Nn + 31) / 32;    // 1563
    // CSR count + he_n transpose (+watt in extra block)
    count_edges_watt<<<1251, 256, 0, stream>>>(he_n, counts, h1_w, h1_att, h2_w, h2_att,
                                               wnA, weA, he_nT);

    // stage 1: buf = lrelu(x@lin1_w + b); fused bn1 stats; +49 blocks run the CSR scan
    gemmT<32, true, false, false, true, false, true><<<dim3(GB32 + NBSCAN, 1), 256, 0, stream>>>(
        x, 0, lin1_w, 128, lin1_b, 1.f, nullptr, nullptr, nullptr, nullptr, st0, buf, 128, Nn,
        GB32, counts, offs);
    // bn1 dots (finalizes st0 in-kernel; publishes AB1 + fp16 bufh); +1250 blocks fill_csr
    bn_dots<2, true><<<3125 + 1250, 256, 0, stream>>>(buf, st0, bn1_g, bn1_b, AB1, wnA, weA,
                                                      an, pe, bufh, he_n, offs, cursor, eid,
                                                      3125);

    // hgconv1 (H=2); BN1 pre-applied in bufh (fp16) for s_build; AB1 for node_agg epilogue
    ea_from_pe<2><<<Mm / 4, 256, 0, stream>>>(he_nT, pe, ae);
    seg_softmax<2><<<(Nn + 31) / 32, 256, 0, stream>>>(offs, eid, an, ae, he_w, nsp);
    s_build<2><<<Mm, 256, 0, stream>>>(bufh, he_nT, nsp, ae, S);
    gemmT<32, false, false, false, false, true, false><<<dim3(125, 2), 256, 0, stream>>>(
        S, (size_t)Mm * 128, h1_w, 256, nullptr, BINV, nullptr, nullptr, nullptr, nullptr,
        nullptr, eo, 256, Mm, 125, nullptr, nullptr);
    node_agg<2><<<3125, 256, 0, stream>>>(offs, eid, nsp, ae, eo, h1_b, AB1, st1, buf);

    // stage 2 dots (finalizes st1 -> AB2; emits BN2-applied fp16 bufh)
    bn_dots<1, false><<<3125, 256, 0, stream>>>(buf, st1, bn2_g, bn2_b, AB2, wnA + 256,
                                                weA + 256, an, pe, bufh, nullptr, nullptr,
                                                nullptr, nullptr, 3125);

    // hgconv2 (H=1); BN2 pre-applied in bufh
    ea_from_pe<1><<<Mm / 4, 256, 0, stream>>>(he_nT, pe, ae);
    seg_softmax<1><<<(Nn + 31) / 32, 256, 0, stream>>>(offs, eid, an, ae, he_w, nsp);
    s_build<1><<<Mm, 256, 0, stream>>>(bufh, he_nT, nsp, ae, S);
    gemmT<32, false, false, false, false, false, false><<<dim3(125, 1), 256, 0, stream>>>(
        S, 0, h2_w, 128, nullptr, BINV, nullptr, nullptr, nullptr, nullptr, nullptr,
        eo, 128, Mm, 125, nullptr, nullptr);
    node_agg<1><<<3125, 256, 0, stream>>>(offs, eid, nsp, ae, eo, h2_b, AB2, st2, buf);

    // lin2: in-kernel BN3 finalize (st2) + prologue, lrelu + residual + bn4 stats epilogue
    gemmT<32, true, true, true, true, false, false><<<dim3(GB32, 1), 256, 0, stream>>>(
        buf, 0, lin2_w, 128, lin2_b, 1.f, st2, bn3_g, bn3_b, x, st3, buf, 128, Nn,
        GB32, nullptr, nullptr);
    // final BN4: in-kernel finalize (st3) + apply
    bn_out<<<3125, 256, 0, stream>>>(buf, st3, bn4_g, bn4_b, out);
}

// Round 7
// 358.614 us; speedup vs baseline: 1.1356x; 1.0545x over previous
//
#include <hip/hip_runtime.h>
#include <hip/hip_fp16.h>
#include <math.h>

constexpr int Nn = 50000;
constexpr int Mm = 4000;
constexpr int Ee = 320000;
constexpr int KPB = Ee / Mm;           // 80 entries per hyperedge (he_e = i % M)
constexpr float BINV = 1.0f / (float)KPB;
constexpr float EPSf = 1e-5f;
constexpr int NBKT = 16;               // stat buckets (fp32 atomics, no fence!)
constexpr int NBSCAN = 49;             // scan blocks (1024 nodes each)

__device__ __forceinline__ float lrelu_f(float x) { return x >= 0.f ? x : 0.2f * x; }

__device__ __forceinline__ unsigned short f2h(float f) {
    __half h = __float2half_rn(f);
    return *reinterpret_cast<unsigned short*>(&h);
}
__device__ __forceinline__ float h2f(unsigned short s) {
    __half_raw r; r.x = s;
    return __half2float(__half(r));
}
__device__ __forceinline__ unsigned int packh2(float a, float b) {
    return (unsigned int)f2h(a) | ((unsigned int)f2h(b) << 16);
}
__device__ __forceinline__ float4 ldh4(const unsigned short* p) {
    ushort4 u = *(const ushort4*)p;
    return make_float4(h2f(u.x), h2f(u.y), h2f(u.z), h2f(u.w));
}
__device__ __forceinline__ float2 ldh2(const unsigned short* p) {
    ushort2 u = *(const ushort2*)p;
    return make_float2(h2f(u.x), h2f(u.y));
}

__device__ __forceinline__ float wave_sum(float v) {
#pragma unroll
    for (int o = 32; o >= 1; o >>= 1) v += __shfl_xor(v, o, 64);
    return v;
}

// Consumer-side BN finalize: stats buckets (prev kernel's fp32 atomics) -> AB in LDS.
__device__ __forceinline__ void finalize_to_lds(const float* __restrict__ st,
                                                const float* __restrict__ g,
                                                const float* __restrict__ b,
                                                float* ABsh, int t) {
    if (t < 128) {
        double ds = 0, dq = 0;
#pragma unroll
        for (int i = 0; i < NBKT; i++) {
            ds += (double)st[i * 256 + t];
            dq += (double)st[i * 256 + 128 + t];
        }
        double mean = ds / (double)Nn;
        double var = dq / (double)Nn - mean * mean;
        float rstd = (float)(1.0 / sqrt(var + (double)EPSf));
        float A = g[t] * rstd;
        ABsh[t] = A;
        ABsh[128 + t] = b[t] - (float)mean * A;
    }
    __syncthreads();
}

// exclusive scan of counts -> offs; block b handles nodes [b*1024, b*1024+1024)
__device__ void scan_body(const int* __restrict__ counts, int* __restrict__ offs,
                          int b, int t) {
    __shared__ int sdi[256];
    int pre = 0;
    for (int i = t; i < b * 1024; i += 256) pre += counts[i];
    sdi[t] = pre;
    __syncthreads();
    for (int st = 128; st >= 1; st >>= 1) {
        if (t < st) sdi[t] += sdi[t + st];
        __syncthreads();
    }
    int run0 = sdi[0];
    __syncthreads();
    int c4[4];
    int s = 0;
#pragma unroll
    for (int i = 0; i < 4; i++) {
        int n = b * 1024 + t * 4 + i;
        c4[i] = (n < Nn) ? counts[n] : 0;
        s += c4[i];
    }
    sdi[t] = s;
    __syncthreads();
    for (int off = 1; off < 256; off <<= 1) {
        int v = (t >= off) ? sdi[t - off] : 0;
        __syncthreads();
        sdi[t] += v;
        __syncthreads();
    }
    int run = sdi[t] - s + run0;
#pragma unroll
    for (int i = 0; i < 4; i++) {
        int n = b * 1024 + t * 4 + i;
        if (n < Nn) offs[n] = run;
        run += c4[i];
    }
    if (b == NBSCAN - 1 && t == 255) offs[Nn] = run0 + sdi[255];
}

// ---------------- GEMM: C[R, bcol:+128] = op(op_bn(A[R,128]) @ B[:, bcol:+128]) -------------
// BK=16, A-tile transposed in LDS. ROWS=32 for the Nn gemms (R1 best config).
// PROBN: in-kernel BN finalize + apply on A load. PACKH2: eo col-pair interleave (h=blockIdx.y).
// STATS: bucketed fp32 atomics (fence-free). SCANX: extra x-blocks run the CSR offset scan.
// HALFOUT (R7): C is fp16 (same element indices) -- halves node_agg's eo gather bytes.
template <int ROWS, bool LRELU, bool PROBN, bool RESID, bool STATS, bool PACKH2, bool SCANX,
          bool HALFOUT>
__global__ __launch_bounds__(256) void gemmT(const float* __restrict__ A, size_t aystride,
                                             const float* __restrict__ B, int ldb,
                                             const float* __restrict__ bias, float scale,
                                             const float* __restrict__ stIn,
                                             const float* __restrict__ fing,
                                             const float* __restrict__ finb,
                                             const float* __restrict__ resid,
                                             float* __restrict__ stF,
                                             float* __restrict__ C, int ldc, int R,
                                             int gemmBlocksX,
                                             const int* __restrict__ counts,
                                             int* __restrict__ offs) {
    constexpr int RPT = ROWS / 16;
    const int t = threadIdx.x;
    if (SCANX && (int)blockIdx.x >= gemmBlocksX) {
        if (blockIdx.y == 0) scan_body(counts, offs, blockIdx.x - gemmBlocksX, t);
        return;
    }
    __shared__ float As[16][ROWS + 4];
    __shared__ float Bs[16][128];
    __shared__ float Sred[STATS ? 16 : 1][STATS ? 128 : 1];
    __shared__ float ABsh[PROBN ? 256 : 1];
    const int ty = t >> 4, tx = t & 15;
    const int row0 = blockIdx.x * ROWS;
    const int bcol = blockIdx.y * 128;
    A += (size_t)blockIdx.y * aystride;

    if (PROBN) finalize_to_lds(stIn, fing, finb, ABsh, t);

    float4 acc[RPT][2];
#pragma unroll
    for (int i = 0; i < RPT; i++)
#pragma unroll
        for (int q = 0; q < 2; q++) acc[i][q] = make_float4(0.f, 0.f, 0.f, 0.f);

    for (int k0 = 0; k0 < 128; k0 += 16) {
        if (ROWS == 64) {
            int r = t >> 2, kc = (t & 3) * 4;
            int rr = row0 + r;
            rr = rr < R ? rr : R - 1;
            float4 av = *(const float4*)(A + (size_t)rr * 128 + k0 + kc);
            if (PROBN) {
                float4 sA = *(const float4*)&ABsh[k0 + kc];
                float4 sB = *(const float4*)&ABsh[128 + k0 + kc];
                av.x = av.x * sA.x + sB.x; av.y = av.y * sA.y + sB.y;
                av.z = av.z * sA.z + sB.z; av.w = av.w * sA.w + sB.w;
            }
            As[kc + 0][r] = av.x; As[kc + 1][r] = av.y;
            As[kc + 2][r] = av.z; As[kc + 3][r] = av.w;
        } else {  // ROWS == 32
            int r = t >> 3, kc = (t & 7) * 2;
            int rr = row0 + r;
            rr = rr < R ? rr : R - 1;
            float2 av = *(const float2*)(A + (size_t)rr * 128 + k0 + kc);
            if (PROBN) {
                av.x = av.x * ABsh[k0 + kc] + ABsh[128 + k0 + kc];
                av.y = av.y * ABsh[k0 + kc + 1] + ABsh[128 + k0 + kc + 1];
            }
            As[kc + 0][r] = av.x;
            As[kc + 1][r] = av.y;
        }
        {
            int kk = t >> 5, c4 = (t & 31) * 4;
            float4 bv0 = *(const float4*)(B + (size_t)(k0 + kk) * ldb + bcol + c4);
            float4 bv1 = *(const float4*)(B + (size_t)(k0 + kk + 8) * ldb + bcol + c4);
            *(float4*)&Bs[kk][c4] = bv0;
            *(float4*)&Bs[kk + 8][c4] = bv1;
        }
        __syncthreads();
#pragma unroll
        for (int kk = 0; kk < 16; kk++) {
            float ar[RPT];
            if (RPT == 4) {
                float4 a4 = *(const float4*)&As[kk][ty * 4];
                ar[0] = a4.x; ar[1] = a4.y; ar[2] = a4.z; ar[3] = a4.w;
            } else {
                float2 a2 = *(const float2*)&As[kk][ty * 2];
                ar[0] = a2.x; ar[RPT - 1] = a2.y;
            }
            float4 b0 = *(const float4*)&Bs[kk][4 * tx];
            float4 b1 = *(const float4*)&Bs[kk][64 + 4 * tx];
#pragma unroll
            for (int i = 0; i < RPT; i++) {
                acc[i][0].x = fmaf(ar[i], b0.x, acc[i][0].x);
                acc[i][0].y = fmaf(ar[i], b0.y, acc[i][0].y);
                acc[i][0].z = fmaf(ar[i], b0.z, acc[i][0].z);
                acc[i][0].w = fmaf(ar[i], b0.w, acc[i][0].w);
                acc[i][1].x = fmaf(ar[i], b1.x, acc[i][1].x);
                acc[i][1].y = fmaf(ar[i], b1.y, acc[i][1].y);
                acc[i][1].z = fmaf(ar[i], b1.z, acc[i][1].z);
                acc[i][1].w = fmaf(ar[i], b1.w, acc[i][1].w);
            }
        }
        __syncthreads();
    }

    float4 bv0 = make_float4(0.f, 0.f, 0.f, 0.f), bv1 = bv0;
    if (bias) {
        bv0 = *(const float4*)(bias + bcol + 4 * tx);
        bv1 = *(const float4*)(bias + bcol + 64 + 4 * tx);
    }
    float4 cs0 = make_float4(0.f, 0.f, 0.f, 0.f), cs1 = cs0, cq0 = cs0, cq1 = cs0;
#pragma unroll
    for (int i = 0; i < RPT; i++) {
        int row = row0 + ty * RPT + i;
        if (row >= R) continue;
        float4 v0, v1;
        v0.x = acc[i][0].x * scale + bv0.x; v0.y = acc[i][0].y * scale + bv0.y;
        v0.z = acc[i][0].z * scale + bv0.z; v0.w = acc[i][0].w * scale + bv0.w;
        v1.x = acc[i][1].x * scale + bv1.x; v1.y = acc[i][1].y * scale + bv1.y;
        v1.z = acc[i][1].z * scale + bv1.z; v1.w = acc[i][1].w * scale + bv1.w;
        if (LRELU) {
            v0.x = lrelu_f(v0.x); v0.y = lrelu_f(v0.y); v0.z = lrelu_f(v0.z); v0.w = lrelu_f(v0.w);
            v1.x = lrelu_f(v1.x); v1.y = lrelu_f(v1.y); v1.z = lrelu_f(v1.z); v1.w = lrelu_f(v1.w);
        }
        if (RESID) {
            float4 r0 = *(const float4*)(resid + (size_t)row * 128 + bcol + 4 * tx);
            float4 r1 = *(const float4*)(resid + (size_t)row * 128 + bcol + 64 + 4 * tx);
            v0.x += r0.x; v0.y += r0.y; v0.z += r0.z; v0.w += r0.w;
            v1.x += r1.x; v1.y += r1.y; v1.z += r1.z; v1.w += r1.w;
        }
        if (HALFOUT) {
            unsigned short* Ch = (unsigned short*)C;
            if (PACKH2) {
                int h = blockIdx.y;
                unsigned short* c0 = Ch + (size_t)row * ldc + 8 * tx + 2 * h;
                *(unsigned int*)(c0) = packh2(v0.x, v0.y);
                *(unsigned int*)(c0 + 4) = packh2(v0.z, v0.w);
                unsigned short* c1 = Ch + (size_t)row * ldc + 128 + 8 * tx + 2 * h;
                *(unsigned int*)(c1) = packh2(v1.x, v1.y);
                *(unsigned int*)(c1 + 4) = packh2(v1.z, v1.w);
            } else {
                unsigned short* c0 = Ch + (size_t)row * ldc + bcol + 4 * tx;
                *(unsigned int*)(c0) = packh2(v0.x, v0.y);
                *(unsigned int*)(c0 + 2) = packh2(v0.z, v0.w);
                unsigned short* c1 = Ch + (size_t)row * ldc + bcol + 64 + 4 * tx;
                *(unsigned int*)(c1) = packh2(v1.x, v1.y);
                *(unsigned int*)(c1 + 2) = packh2(v1.z, v1.w);
            }
        } else if (PACKH2) {
            int h = blockIdx.y;
            float* c0 = C + (size_t)row * ldc + 8 * tx + 2 * h;
            *(float2*)(c0) = make_float2(v0.x, v0.y);
            *(float2*)(c0 + 4) = make_float2(v0.z, v0.w);
            float* c1 = C + (size_t)row * ldc + 128 + 8 * tx + 2 * h;
            *(float2*)(c1) = make_float2(v1.x, v1.y);
            *(float2*)(c1 + 4) = make_float2(v1.z, v1.w);
        } else {
            *(float4*)(C + (size_t)row * ldc + bcol + 4 * tx) = v0;
            *(float4*)(C + (size_t)row * ldc + bcol + 64 + 4 * tx) = v1;
        }
        if (STATS) {
            cs0.x += v0.x; cs0.y += v0.y; cs0.z += v0.z; cs0.w += v0.w;
            cs1.x += v1.x; cs1.y += v1.y; cs1.z += v1.z; cs1.w += v1.w;
            cq0.x += v0.x * v0.x; cq0.y += v0.y * v0.y; cq0.z += v0.z * v0.z; cq0.w += v0.w * v0.w;
            cq1.x += v1.x * v1.x; cq1.y += v1.y * v1.y; cq1.z += v1.z * v1.z; cq1.w += v1.w * v1.w;
        }
    }
    if (STATS) {
        int bkt = blockIdx.x & (NBKT - 1);
#pragma unroll
        for (int pass = 0; pass < 2; pass++) {
            *(float4*)&Sred[ty][4 * tx] = pass ? cq0 : cs0;
            *(float4*)&Sred[ty][64 + 4 * tx] = pass ? cq1 : cs1;
            __syncthreads();
            if (t < 128) {
                float tot = 0.f;
#pragma unroll
                for (int r = 0; r < 16; r++) tot += Sred[r][t];
                atomicAdd(&stF[bkt * 256 + pass * 128 + t], tot);
            }
            __syncthreads();
        }
    }
}

// ---------------- CSR count + he_n transpose (+watt folded into extra block) ----------------
__global__ void count_edges_watt(const int* __restrict__ he_n, int* __restrict__ counts,
                                 const float* __restrict__ h1_w, const float* __restrict__ h1_att,
                                 const float* __restrict__ h2_w, const float* __restrict__ h2_att,
                                 float* __restrict__ wnA, float* __restrict__ weA,
                                 int* __restrict__ he_nT) {
    int t = threadIdx.x;
    if (blockIdx.x == 1250) {
        for (int j = 0; j < 3; j++) {
            int id = t + 256 * j;
            if (id >= 768) break;
            int which = id / 384;
            int rem = id % 384;
            int h3 = rem >> 7, k = rem & 127;
            float s = 0.f;
            if (h3 < 2) {
                const float* wrow = h1_w + (size_t)k * 256 + h3 * 128;
                const float* arow = h1_att + h3 * 256 + which * 128;
                for (int c = 0; c < 128; c++) s += wrow[c] * arow[c];
            } else {
                const float* wrow = h2_w + (size_t)k * 128;
                const float* arow = h2_att + which * 128;
                for (int c = 0; c < 128; c++) s += wrow[c] * arow[c];
            }
            (which ? weA : wnA)[h3 * 128 + k] = s;
        }
        return;
    }
    int g = blockIdx.x * 256 + t;
    if (g < Ee) {
        int m = g / KPB;
        int k = g - m * KPB;
        int n = he_n[m + (size_t)k * Mm];
        he_nT[g] = n;
        atomicAdd(&counts[n], 1);
    }
}

// ---------------- BN dots (+in-kernel finalize; block 0 publishes AB; +fill_csr fold) ------
// Also emits bufh = fp16(BN(X)) -- the half-width gather source for s_build.
template <int H, bool FILL>
__global__ __launch_bounds__(256) void bn_dots(const float* __restrict__ X,
                                               const float* __restrict__ stIn,
                                               const float* __restrict__ fing,
                                               const float* __restrict__ finb,
                                               float* __restrict__ ABout,
                                               const float* __restrict__ wn,
                                               const float* __restrict__ we,
                                               float* __restrict__ an,
                                               float* __restrict__ pe,
                                               unsigned short* __restrict__ bufh,
                                               const int* __restrict__ he_n,
                                               const int* __restrict__ offs,
                                               int* __restrict__ cursor,
                                               int* __restrict__ eid, int mainBlocks) {
    int t = threadIdx.x;
    if (FILL && (int)blockIdx.x >= mainBlocks) {
        int e = (blockIdx.x - mainBlocks) * 256 + t;
        if (e < Ee) {
            int n = he_n[e];
            int p = atomicAdd(&cursor[n], 1);
            eid[offs[n] + p] = e;
        }
        return;
    }
    __shared__ float ABsh[256];
    finalize_to_lds(stIn, fing, finb, ABsh, t);
    if (blockIdx.x == 0) ABout[t] = ABsh[t];
    int w = t >> 6, lane = t & 63;
    float a0 = ABsh[lane], a1 = ABsh[lane + 64];
    float b0 = ABsh[128 + lane], b1 = ABsh[192 + lane];
    float wn0[H], wn1[H], we0[H], we1[H];
#pragma unroll
    for (int h = 0; h < H; h++) {
        wn0[h] = wn[h * 128 + lane]; wn1[h] = wn[h * 128 + 64 + lane];
        we0[h] = we[h * 128 + lane]; we1[h] = we[h * 128 + 64 + lane];
    }
#pragma unroll
    for (int nn = 0; nn < 4; nn++) {
        int row = blockIdx.x * 16 + w * 4 + nn;
        const float* xr = X + (size_t)row * 128;
        float v0 = xr[lane] * a0 + b0;
        float v1 = xr[lane + 64] * a1 + b1;
        bufh[(size_t)row * 128 + lane] = f2h(v0);
        bufh[(size_t)row * 128 + 64 + lane] = f2h(v1);
        float pv[H], qv[H];
#pragma unroll
        for (int h = 0; h < H; h++) {
            pv[h] = wave_sum(v0 * wn0[h] + v1 * wn1[h]);
            qv[h] = wave_sum(v0 * we0[h] + v1 * we1[h]);
        }
        if (lane == 0) {
            if (H == 2) {
                *(float2*)&an[row * 2] = make_float2(pv[0], pv[1]);
                *(float2*)&pe[row * 2] = make_float2(qv[0], qv[1]);
            } else {
                an[row] = pv[0];
                pe[row] = qv[0];
            }
        }
    }
}

// final elementwise BN apply with in-kernel finalize (16 rows/block)
__global__ __launch_bounds__(256) void bn_out(const float* __restrict__ X,
                                              const float* __restrict__ stIn,
                                              const float* __restrict__ fing,
                                              const float* __restrict__ finb,
                                              float* __restrict__ Y) {
    __shared__ float ABsh[256];
    int t = threadIdx.x;
    finalize_to_lds(stIn, fing, finb, ABsh, t);
    int w = t >> 6, lane = t & 63;
    float a0 = ABsh[lane], a1 = ABsh[lane + 64];
    float b0 = ABsh[128 + lane], b1 = ABsh[192 + lane];
#pragma unroll
    for (int nn = 0; nn < 4; nn++) {
        int row = blockIdx.x * 16 + w * 4 + nn;
        const float* xr = X + (size_t)row * 128;
        float* yr = Y + (size_t)row * 128;
        yr[lane] = xr[lane] * a0 + b0;
        yr[lane + 64] = xr[lane + 64] * a1 + b1;
    }
}

// ae[m,h] = sum over the 80 member nodes of pe[node,h]  (coalesced via he_nT)
template <int H>
__global__ __launch_bounds__(256) void ea_from_pe(const int* __restrict__ he_nT,
                                                  const float* __restrict__ pe,
                                                  float* __restrict__ ae) {
    int w = threadIdx.x >> 6, lane = threadIdx.x & 63;
    int m = blockIdx.x * 4 + w;
    if (m >= Mm) return;
    float s[H];
#pragma unroll
    for (int h = 0; h < H; h++) s[h] = 0.f;
    for (int k = lane; k < KPB; k += 64) {
        int idx = he_nT[m * KPB + k];
        if (H == 2) {
            float2 p2 = *(const float2*)(pe + (size_t)idx * 2);
            s[0] += p2.x;
            s[H - 1] += p2.y;
        } else {
            s[0] += pe[idx];
        }
    }
#pragma unroll
    for (int h = 0; h < H; h++) s[h] = wave_sum(s[h]);
    if (lane == 0)
#pragma unroll
        for (int h = 0; h < H; h++) ae[m * H + h] = s[h];
}

// per-node softmax STATS ONLY; consumers recompute p from nsp:
//   H=2: nsp[n*8..] = {an0,an1,mx0,mx1} {1/sm0,1/sm1,Dinv*0.5,0}
//   H=1: nsp[n*4..] = {an, mx, 1/sm, Dinv}
template <int H>
__global__ __launch_bounds__(256) void seg_softmax(const int* __restrict__ offs,
                                                   const int* __restrict__ eid,
                                                   const float* __restrict__ an,
                                                   const float* __restrict__ ae,
                                                   const float* __restrict__ he_w,
                                                   float* __restrict__ nsp) {
    int t = threadIdx.x;
    int wv = t >> 6, lane = t & 63;
    int q = lane >> 3, li = lane & 7;
    int n = blockIdx.x * 32 + wv * 8 + q;
    bool valid = n < Nn;
    int base = valid ? offs[n] : 0;
    int deg = valid ? offs[n + 1] - base : 0;
    float anv[H];
#pragma unroll
    for (int h = 0; h < H; h++) anv[h] = valid ? an[n * H + h] : 0.f;

    bool h0 = li < deg, h1 = li + 8 < deg;
    int m0 = 0, m1 = 0;
    float l0[H], l1[H];
    float mx[H];
#pragma unroll
    for (int h = 0; h < H; h++) { mx[h] = -INFINITY; l0[h] = 0.f; l1[h] = 0.f; }
    if (h0) {
        m0 = eid[base + li] % Mm;
#pragma unroll
        for (int h = 0; h < H; h++) {
            l0[h] = lrelu_f(anv[h] + ae[m0 * H + h]);
            mx[h] = fmaxf(mx[h], l0[h]);
        }
    }
    if (h1) {
        m1 = eid[base + li + 8] % Mm;
#pragma unroll
        for (int h = 0; h < H; h++) {
            l1[h] = lrelu_f(anv[h] + ae[m1 * H + h]);
            mx[h] = fmaxf(mx[h], l1[h]);
        }
    }
    for (int c = li + 16; c < deg; c += 8) {
        int m = eid[base + c] % Mm;
#pragma unroll
        for (int h = 0; h < H; h++) mx[h] = fmaxf(mx[h], lrelu_f(anv[h] + ae[m * H + h]));
    }
#pragma unroll
    for (int h = 0; h < H; h++) {
#pragma unroll
        for (int o = 1; o <= 4; o <<= 1) mx[h] = fmaxf(mx[h], __shfl_xor(mx[h], o, 64));
    }
    float sm[H];
#pragma unroll
    for (int h = 0; h < H; h++) sm[h] = 0.f;
    float dn = 0.f;
    if (h0) {
        dn += he_w[m0];
#pragma unroll
        for (int h = 0; h < H; h++) sm[h] += expf(l0[h] - mx[h]);
    }
    if (h1) {
        dn += he_w[m1];
#pragma unroll
        for (int h = 0; h < H; h++) sm[h] += expf(l1[h] - mx[h]);
    }
    for (int c = li + 16; c < deg; c += 8) {
        int m = eid[base + c] % Mm;
        dn += he_w[m];
#pragma unroll
        for (int h = 0; h < H; h++) sm[h] += expf(lrelu_f(anv[h] + ae[m * H + h]) - mx[h]);
    }
#pragma unroll
    for (int o = 1; o <= 4; o <<= 1) dn += __shfl_xor(dn, o, 64);
#pragma unroll
    for (int h = 0; h < H; h++) {
#pragma unroll
        for (int o = 1; o <= 4; o <<= 1) sm[h] += __shfl_xor(sm[h], o, 64);
    }
    if (valid && li == 0) {
        float Dv = dn > 0.f ? 1.0f / dn : 0.0f;
        if (H == 2) {
            *(float4*)(nsp + (size_t)n * 8) = make_float4(anv[0], anv[H - 1], mx[0], mx[H - 1]);
            *(float4*)(nsp + (size_t)n * 8 + 4) =
                make_float4(1.f / sm[0], 1.f / sm[H - 1], 0.5f * Dv, 0.f);
        } else {
            *(float4*)(nsp + (size_t)n * 4) = make_float4(anv[0], mx[0], 1.f / sm[0], Dv);
        }
    }
}

// S[h][m][:] = sum_k p[e,h] * BNX_h[he_n[e], :]   (8 groups x 32 lanes)
// gathers the fp16 BN-applied copy (bufh) -- 256B/row, no A/B fma.
template <int H>
__global__ __launch_bounds__(256) void s_build(const unsigned short* __restrict__ Xh,
                                               const int* __restrict__ he_nT,
                                               const float* __restrict__ nsp,
                                               const float* __restrict__ ae,
                                               float* __restrict__ S) {
    __shared__ int idx[KPB];
    __shared__ float av[KPB][H];
    __shared__ float red[8][H][128];
    int m = blockIdx.x, t = threadIdx.x;
    int g = t >> 5, l = t & 31;
    if (t < KPB) {
        int nd = he_nT[m * KPB + t];
        idx[t] = nd;
        if (H == 2) {
            float4 pa = *(const float4*)(nsp + (size_t)nd * 8);
            float4 pb = *(const float4*)(nsp + (size_t)nd * 8 + 4);
            float2 a2 = *(const float2*)(ae + (size_t)m * 2);
            av[t][0] = expf(lrelu_f(pa.x + a2.x) - pa.z) * pb.x;
            av[t][H - 1] = expf(lrelu_f(pa.y + a2.y) - pa.w) * pb.y;
        } else {
            float4 pa = *(const float4*)(nsp + (size_t)nd * 4);
            float aem = ae[m];
            av[t][0] = expf(lrelu_f(pa.x + aem) - pa.y) * pa.z;
        }
    }
    __syncthreads();
    float4 acc[H];
#pragma unroll
    for (int h = 0; h < H; h++) acc[h] = make_float4(0.f, 0.f, 0.f, 0.f);
#pragma unroll
    for (int kk = 0; kk < KPB / 8; kk++) {
        int k = g + kk * 8;
        ushort4 u = *(const ushort4*)(Xh + (size_t)idx[k] * 128 + l * 4);
        float vx = h2f(u.x), vy = h2f(u.y), vz = h2f(u.z), vw = h2f(u.w);
#pragma unroll
        for (int h = 0; h < H; h++) {
            float a = av[k][h];
            acc[h].x = fmaf(a, vx, acc[h].x);
            acc[h].y = fmaf(a, vy, acc[h].y);
            acc[h].z = fmaf(a, vz, acc[h].z);
            acc[h].w = fmaf(a, vw, acc[h].w);
        }
    }
#pragma unroll
    for (int h = 0; h < H; h++) *(float4*)&red[g][h][l * 4] = acc[h];
    __syncthreads();
    if (t < 32 * H) {
        int h = t >> 5, l2 = t & 31;
        float4 s = make_float4(0.f, 0.f, 0.f, 0.f);
#pragma unroll
        for (int gg = 0; gg < 8; gg++) {
            float4 r = *(const float4*)&red[gg][h][l2 * 4];
            s.x += r.x; s.y += r.y; s.z += r.z; s.w += r.w;
        }
        ((float4*)(S + ((size_t)h * Mm + m) * 128))[l2] = s;
    }
}

// node_agg v6: eo now fp16 (eoh) -- halves the per-edge gather bytes (R7).
// wave = 4 consecutive nodes; staging recomputes per-slot {m, c0[,c1]} from eid+nsp+ae;
// main loop j-segmented with named accumulators. Fence-free stats. In-place T.
template <int H>
__global__ __launch_bounds__(256) void node_agg(const int* __restrict__ offs,
                                                const int* __restrict__ eid,
                                                const float* __restrict__ nsp,
                                                const float* __restrict__ ae,
                                                const unsigned short* __restrict__ eoh,
                                                const float* __restrict__ bias,
                                                const float* __restrict__ AB,
                                                float* __restrict__ stF,
                                                float* __restrict__ T) {
    __shared__ float smem[4][256];
    __shared__ float redS[4][128], redQ[4][128];
    int t = threadIdx.x;
    int w = t >> 6, lane = t & 63;
    int n0 = blockIdx.x * 16 + w * 4;
    int o = offs[n0 + (lane < 4 ? lane : 4)];
    int b0 = __shfl(o, 0, 64);
    int b1 = __shfl(o, 1, 64);
    int b2 = __shfl(o, 2, 64);
    int b3 = __shfl(o, 3, 64);
    int b4 = __shfl(o, 4, 64);
    int cnt = b4 - b0;
    int cnt64 = cnt < 64 ? cnt : 64;

    if (lane < cnt64) {
        int slot = b0 + lane;
        int j = (slot >= b1) + (slot >= b2) + (slot >= b3);
        int e = eid[slot];
        int m = e % Mm;
        if (H == 2) {
            float4 pa = *(const float4*)(nsp + (size_t)(n0 + j) * 8);
            float4 pb = *(const float4*)(nsp + (size_t)(n0 + j) * 8 + 4);
            float2 a2 = *(const float2*)(ae + (size_t)m * 2);
            float c0 = expf(lrelu_f(pa.x + a2.x) - pa.z) * pb.x * pb.z;
            float c1 = expf(lrelu_f(pa.y + a2.y) - pa.w) * pb.y * pb.z;
            *(float4*)&smem[w][4 * lane] = make_float4(__int_as_float(m), c0, c1, 0.f);
        } else {
            float4 pa = *(const float4*)(nsp + (size_t)(n0 + j) * 4);
            float c = expf(lrelu_f(pa.x + ae[m]) - pa.y) * pa.z * pa.w;
            *(float2*)&smem[w][2 * lane] = make_float2(__int_as_float(m), c);
        }
    }
    __syncthreads();

    int s1 = min(b1 - b0, cnt64), s2 = min(b2 - b0, cnt64), s3 = min(b3 - b0, cnt64);
    float2 acc0 = make_float2(0.f, 0.f), acc1 = acc0, acc2 = acc0, acc3 = acc0;

#define NA_BODY(ACC, CBEG, CEND)                                                \
    {                                                                           \
        int c = (CBEG);                                                         \
        for (; c + 1 < (CEND); c += 2) {                                        \
            if (H == 2) {                                                       \
                float4 sa = *(const float4*)&smem[w][4 * c];                    \
                float4 sb = *(const float4*)&smem[w][4 * (c + 1)];              \
                float4 ea = ldh4(eoh + (size_t)__float_as_int(sa.x) * 256 + 4 * lane); \
                float4 eb = ldh4(eoh + (size_t)__float_as_int(sb.x) * 256 + 4 * lane); \
                ACC.x += sa.y * ea.x + sa.z * ea.z + sb.y * eb.x + sb.z * eb.z; \
                ACC.y += sa.y * ea.y + sa.z * ea.w + sb.y * eb.y + sb.z * eb.w; \
            } else {                                                            \
                float2 sa = *(const float2*)&smem[w][2 * c];                    \
                float2 sb = *(const float2*)&smem[w][2 * (c + 1)];              \
                float2 ea = ldh2(eoh + (size_t)__float_as_int(sa.x) * 128 + 2 * lane); \
                float2 eb = ldh2(eoh + (size_t)__float_as_int(sb.x) * 128 + 2 * lane); \
                ACC.x += sa.y * ea.x + sb.y * eb.x;                             \
                ACC.y += sa.y * ea.y + sb.y * eb.y;                             \
            }                                                                   \
        }                                                                       \
        if (c < (CEND)) {                                                       \
            if (H == 2) {                                                       \
                float4 sa = *(const float4*)&smem[w][4 * c];                    \
                float4 ea = ldh4(eoh + (size_t)__float_as_int(sa.x) * 256 + 4 * lane); \
                ACC.x += sa.y * ea.x + sa.z * ea.z;                             \
                ACC.y += sa.y * ea.y + sa.z * ea.w;                             \
            } else {                                                            \
                float2 sa = *(const float2*)&smem[w][2 * c];                    \
                float2 ea = ldh2(eoh + (size_t)__float_as_int(sa.x) * 128 + 2 * lane); \
                ACC.x += sa.y * ea.x;                                           \
                ACC.y += sa.y * ea.y;                                           \
            }                                                                   \
        }                                                                       \
    }
    NA_BODY(acc0, 0, s1)
    NA_BODY(acc1, s1, s2)
    NA_BODY(acc2, s2, s3)
    NA_BODY(acc3, s3, cnt64)
#undef NA_BODY

    for (int ss = 64; ss < cnt; ss++) {  // rare tail (cnt > 64): recompute coef inline
        int slot = b0 + ss;
        int j = (slot >= b1) + (slot >= b2) + (slot >= b3);
        int e = eid[slot];
        int m = e % Mm;
        float cx, cy;
        if (H == 2) {
            float4 pa = *(const float4*)(nsp + (size_t)(n0 + j) * 8);
            float4 pb = *(const float4*)(nsp + (size_t)(n0 + j) * 8 + 4);
            float2 a2 = *(const float2*)(ae + (size_t)m * 2);
            float c0 = expf(lrelu_f(pa.x + a2.x) - pa.z) * pb.x * pb.z;
            float c1 = expf(lrelu_f(pa.y + a2.y) - pa.w) * pb.y * pb.z;
            float4 ev = ldh4(eoh + (size_t)m * 256 + 4 * lane);
            cx = c0 * ev.x + c1 * ev.z;
            cy = c0 * ev.y + c1 * ev.w;
        } else {
            float4 pa = *(const float4*)(nsp + (size_t)(n0 + j) * 4);
            float c = expf(lrelu_f(pa.x + ae[m]) - pa.y) * pa.z * pa.w;
            float2 ev = ldh2(eoh + (size_t)m * 128 + 2 * lane);
            cx = c * ev.x;
            cy = c * ev.y;
        }
        if (j == 0) { acc0.x += cx; acc0.y += cy; }
        else if (j == 1) { acc1.x += cx; acc1.y += cy; }
        else if (j == 2) { acc2.x += cx; acc2.y += cy; }
        else { acc3.x += cx; acc3.y += cy; }
    }

    int col = 2 * lane;
    float2 A2 = *(const float2*)(AB + col);
    float2 B2 = *(const float2*)(AB + 128 + col);
    float2 bi = *(const float2*)(bias + col);
    float cs0 = 0.f, cs1 = 0.f, cq0 = 0.f, cq1 = 0.f;
    float2 accs[4] = {acc0, acc1, acc2, acc3};
#pragma unroll
    for (int j = 0; j < 4; j++) {
        int n = n0 + j;
        float2 xr = *(const float2*)(T + (size_t)n * 128 + col);
        float r0 = xr.x * A2.x + B2.x + bi.x + accs[j].x;
        float r1 = xr.y * A2.y + B2.y + bi.y + accs[j].y;
        *(float2*)(T + (size_t)n * 128 + col) = make_float2(r0, r1);
        cs0 += r0; cs1 += r1;
        cq0 += r0 * r0; cq1 += r1 * r1;
    }
    redS[w][col] = cs0; redS[w][col + 1] = cs1;
    redQ[w][col] = cq0; redQ[w][col + 1] = cq1;
    __syncthreads();
    if (t < 128) {
        float s = 0.f, qq = 0.f;
#pragma unroll
        for (int ww = 0; ww < 4; ww++) { s += redS[ww][t]; qq += redQ[ww][t]; }
        int bkt = blockIdx.x & (NBKT - 1);
        atomicAdd(&stF[bkt * 256 + t], s);
        atomicAdd(&stF[bkt * 256 + 128 + t], qq);
    }
}

extern "C" void kernel_launch(void* const* d_in, const int* in_sizes, int n_in,
                              void* d_out, int out_size, void* d_ws, size_t ws_size,
                              hipStream_t stream) {
    const float* x = (const float*)d_in[0];
    const int* he_n = (const int*)d_in[1];
    const float* he_w = (const float*)d_in[3];
    const float* lin1_w = (const float*)d_in[4];
    const float* lin1_b = (const float*)d_in[5];
    const float* bn1_g = (const float*)d_in[6];
    const float* bn1_b = (const float*)d_in[7];
    const float* h1_w = (const float*)d_in[8];
    const float* h1_att = (const float*)d_in[9];
    const float* h1_b = (const float*)d_in[10];
    const float* bn2_g = (const float*)d_in[11];
    const float* bn2_b = (const float*)d_in[12];
    const float* h2_w = (const float*)d_in[13];
    const float* h2_att = (const float*)d_in[14];
    const float* h2_b = (const float*)d_in[15];
    const float* bn3_g = (const float*)d_in[16];
    const float* bn3_b = (const float*)d_in[17];
    const float* lin2_w = (const float*)d_in[18];
    const float* lin2_b = (const float*)d_in[19];
    const float* bn4_g = (const float*)d_in[20];
    const float* bn4_b = (const float*)d_in[21];
    float* out = (float*)d_out;

    char* ws = (char*)d_ws;
    size_t off = 0;
    auto alloc = [&](size_t bytes) -> char* {
        char* p = ws + off;
        off = (off + bytes + 255) & ~(size_t)255;
        return p;
    };
    // --- zeroed region (one memset) ---
    int* counts = (int*)alloc((size_t)Nn * 4);
    int* cursor = (int*)alloc((size_t)Nn * 4);
    float* stats = (float*)alloc((size_t)4 * NBKT * 256 * 4);
    size_t zbytes = off;
    // --- rest ---
    int* offs = (int*)alloc((size_t)(Nn + 1) * 4);
    int* eid = (int*)alloc((size_t)Ee * 4);
    int* he_nT = (int*)alloc((size_t)Ee * 4);
    float* an = (float*)alloc((size_t)Nn * 2 * 4);
    float* pe = (float*)alloc((size_t)Nn * 2 * 4);
    float* ae = (float*)alloc((size_t)Mm * 2 * 4);
    float* nsp = (float*)alloc((size_t)Nn * 8 * 4);
    float* S = (float*)alloc((size_t)2 * Mm * 128 * 4);
    unsigned short* eoh = (unsigned short*)alloc((size_t)2 * Mm * 128 * 2);
    float* wnA = (float*)alloc(384 * 4);
    float* weA = (float*)alloc(384 * 4);
    float* AB = (float*)alloc(2 * 256 * 4);
    unsigned short* bufh = (unsigned short*)alloc((size_t)Nn * 128 * 2);
    float* buf = (float*)alloc((size_t)Nn * 128 * 4);

    float* st0 = stats;
    float* st1 = stats + NBKT * 256;
    float* st2 = stats + 2 * NBKT * 256;
    float* st3 = stats + 3 * NBKT * 256;
    float *AB1 = AB, *AB2 = AB + 256;

    hipMemsetAsync(d_ws, 0, zbytes, stream);

    constexpr int GB32 = (Nn + 31) / 32;    // 1563
    // CSR count + he_n transpose (+watt in extra block)
    count_edges_watt<<<1251, 256, 0, stream>>>(he_n, counts, h1_w, h1_att, h2_w, h2_att,
                                               wnA, weA, he_nT);

    // stage 1: buf = lrelu(x@lin1_w + b); fused bn1 stats; +49 blocks run the CSR scan
    gemmT<32, true, false, false, true, false, true, false>
        <<<dim3(GB32 + NBSCAN, 1), 256, 0, stream>>>(
        x, 0, lin1_w, 128, lin1_b, 1.f, nullptr, nullptr, nullptr, nullptr, st0, buf, 128, Nn,
        GB32, counts, offs);
    // bn1 dots (finalizes st0 in-kernel; publishes AB1 + fp16 bufh); +1250 blocks fill_csr
    bn_dots<2, true><<<3125 + 1250, 256, 0, stream>>>(buf, st0, bn1_g, bn1_b, AB1, wnA, weA,
                                                      an, pe, bufh, he_n, offs, cursor, eid,
                                                      3125);

    // hgconv1 (H=2); BN1 pre-applied in bufh (fp16); eo in fp16 (eoh)
    ea_from_pe<2><<<Mm / 4, 256, 0, stream>>>(he_nT, pe, ae);
    seg_softmax<2><<<(Nn + 31) / 32, 256, 0, stream>>>(offs, eid, an, ae, he_w, nsp);
    s_build<2><<<Mm, 256, 0, stream>>>(bufh, he_nT, nsp, ae, S);
    gemmT<32, false, false, false, false, true, false, true><<<dim3(125, 2), 256, 0, stream>>>(
        S, (size_t)Mm * 128, h1_w, 256, nullptr, BINV, nullptr, nullptr, nullptr, nullptr,
        nullptr, (float*)eoh, 256, Mm, 125, nullptr, nullptr);
    node_agg<2><<<3125, 256, 0, stream>>>(offs, eid, nsp, ae, eoh, h1_b, AB1, st1, buf);

    // stage 2 dots (finalizes st1 -> AB2; emits BN2-applied fp16 bufh)
    bn_dots<1, false><<<3125, 256, 0, stream>>>(buf, st1, bn2_g, bn2_b, AB2, wnA + 256,
                                                weA + 256, an, pe, bufh, nullptr, nullptr,
                                                nullptr, nullptr, 3125);

    // hgconv2 (H=1); BN2 pre-applied in bufh; eo in fp16
    ea_from_pe<1><<<Mm / 4, 256, 0, stream>>>(he_nT, pe, ae);
    seg_softmax<1><<<(Nn + 31) / 32, 256, 0, stream>>>(offs, eid, an, ae, he_w, nsp);
    s_build<1><<<Mm, 256, 0, stream>>>(bufh, he_nT, nsp, ae, S);
    gemmT<32, false, false, false, false, false, false, true><<<dim3(125, 1), 256, 0, stream>>>(
        S, 0, h2_w, 128, nullptr, BINV, nullptr, nullptr, nullptr, nullptr, nullptr,
        (float*)eoh, 128, Mm, 125, nullptr, nullptr);
    node_agg<1><<<3125, 256, 0, stream>>>(offs, eid, nsp, ae, eoh, h2_b, AB2, st2, buf);

    // lin2: in-kernel BN3 finalize (st2) + prologue, lrelu + residual + bn4 stats epilogue
    gemmT<32, true, true, true, true, false, false, false><<<dim3(GB32, 1), 256, 0, stream>>>(
        buf, 0, lin2_w, 128, lin2_b, 1.f, st2, bn3_g, bn3_b, x, st3, buf, 128, Nn,
        GB32, nullptr, nullptr);
    // final BN4: in-kernel finalize (st3) + apply
    bn_out<<<3125, 256, 0, stream>>>(buf, st3, bn4_g, bn4_b, out);
}

// Round 8
// 353.664 us; speedup vs baseline: 1.1515x; 1.0140x over previous
//
#include <hip/hip_runtime.h>
#include <hip/hip_fp16.h>
#include <math.h>

constexpr int Nn = 50000;
constexpr int Mm = 4000;
constexpr int Ee = 320000;
constexpr int KPB = Ee / Mm;           // 80 entries per hyperedge (he_e = i % M)
constexpr float BINV = 1.0f / (float)KPB;
constexpr float EPSf = 1e-5f;
constexpr int NBKT = 16;               // stat buckets (fp32 atomics, no fence!)
constexpr int NBSCAN = 49;             // scan blocks (1024 nodes each)

__device__ __forceinline__ float lrelu_f(float x) { return x >= 0.f ? x : 0.2f * x; }

__device__ __forceinline__ unsigned short f2h(float f) {
    __half h = __float2half_rn(f);
    return *reinterpret_cast<unsigned short*>(&h);
}
__device__ __forceinline__ float h2f(unsigned short s) {
    __half_raw r; r.x = s;
    return __half2float(__half(r));
}
__device__ __forceinline__ unsigned int packh2(float a, float b) {
    return (unsigned int)f2h(a) | ((unsigned int)f2h(b) << 16);
}
__device__ __forceinline__ float4 ldh4(const unsigned short* p) {
    ushort4 u = *(const ushort4*)p;
    return make_float4(h2f(u.x), h2f(u.y), h2f(u.z), h2f(u.w));
}
__device__ __forceinline__ float2 ldh2(const unsigned short* p) {
    ushort2 u = *(const ushort2*)p;
    return make_float2(h2f(u.x), h2f(u.y));
}

__device__ __forceinline__ float wave_sum(float v) {
#pragma unroll
    for (int o = 32; o >= 1; o >>= 1) v += __shfl_xor(v, o, 64);
    return v;
}

// Consumer-side BN finalize: stats buckets (prev kernel's fp32 atomics) -> AB in LDS.
__device__ __forceinline__ void finalize_to_lds(const float* __restrict__ st,
                                                const float* __restrict__ g,
                                                const float* __restrict__ b,
                                                float* ABsh, int t) {
    if (t < 128) {
        double ds = 0, dq = 0;
#pragma unroll
        for (int i = 0; i < NBKT; i++) {
            ds += (double)st[i * 256 + t];
            dq += (double)st[i * 256 + 128 + t];
        }
        double mean = ds / (double)Nn;
        double var = dq / (double)Nn - mean * mean;
        float rstd = (float)(1.0 / sqrt(var + (double)EPSf));
        float A = g[t] * rstd;
        ABsh[t] = A;
        ABsh[128 + t] = b[t] - (float)mean * A;
    }
    __syncthreads();
}

// exclusive scan of counts -> offs; block b handles nodes [b*1024, b*1024+1024)
__device__ void scan_body(const int* __restrict__ counts, int* __restrict__ offs,
                          int b, int t) {
    __shared__ int sdi[256];
    int pre = 0;
    for (int i = t; i < b * 1024; i += 256) pre += counts[i];
    sdi[t] = pre;
    __syncthreads();
    for (int st = 128; st >= 1; st >>= 1) {
        if (t < st) sdi[t] += sdi[t + st];
        __syncthreads();
    }
    int run0 = sdi[0];
    __syncthreads();
    int c4[4];
    int s = 0;
#pragma unroll
    for (int i = 0; i < 4; i++) {
        int n = b * 1024 + t * 4 + i;
        c4[i] = (n < Nn) ? counts[n] : 0;
        s += c4[i];
    }
    sdi[t] = s;
    __syncthreads();
    for (int off = 1; off < 256; off <<= 1) {
        int v = (t >= off) ? sdi[t - off] : 0;
        __syncthreads();
        sdi[t] += v;
        __syncthreads();
    }
    int run = sdi[t] - s + run0;
#pragma unroll
    for (int i = 0; i < 4; i++) {
        int n = b * 1024 + t * 4 + i;
        if (n < Nn) offs[n] = run;
        run += c4[i];
    }
    if (b == NBSCAN - 1 && t == 255) offs[Nn] = run0 + sdi[255];
}

// ---------------- GEMM: C[R, bcol:+128] = op(op_bn(A[R,128]) @ B[:, bcol:+128]) -------------
// BK=16, A-tile transposed in LDS. ROWS=32 for the Nn gemms (R1 best config).
// PROBN: in-kernel BN finalize + apply on A load. PACKH2: eo col-pair interleave (h=blockIdx.y).
// STATS: bucketed fp32 atomics (fence-free). SCANX: extra x-blocks run the CSR offset scan.
// HALFOUT: C is fp16 (same element indices). HALFIN (R8): A is fp16 (same indices).
template <int ROWS, bool LRELU, bool PROBN, bool RESID, bool STATS, bool PACKH2, bool SCANX,
          bool HALFOUT, bool HALFIN>
__global__ __launch_bounds__(256) void gemmT(const float* __restrict__ A, size_t aystride,
                                             const float* __restrict__ B, int ldb,
                                             const float* __restrict__ bias, float scale,
                                             const float* __restrict__ stIn,
                                             const float* __restrict__ fing,
                                             const float* __restrict__ finb,
                                             const float* __restrict__ resid,
                                             float* __restrict__ stF,
                                             float* __restrict__ C, int ldc, int R,
                                             int gemmBlocksX,
                                             const int* __restrict__ counts,
                                             int* __restrict__ offs) {
    constexpr int RPT = ROWS / 16;
    const int t = threadIdx.x;
    if (SCANX && (int)blockIdx.x >= gemmBlocksX) {
        if (blockIdx.y == 0) scan_body(counts, offs, blockIdx.x - gemmBlocksX, t);
        return;
    }
    __shared__ float As[16][ROWS + 4];
    __shared__ float Bs[16][128];
    __shared__ float Sred[STATS ? 16 : 1][STATS ? 128 : 1];
    __shared__ float ABsh[PROBN ? 256 : 1];
    const int ty = t >> 4, tx = t & 15;
    const int row0 = blockIdx.x * ROWS;
    const int bcol = blockIdx.y * 128;
    A += (size_t)blockIdx.y * aystride;

    if (PROBN) finalize_to_lds(stIn, fing, finb, ABsh, t);

    float4 acc[RPT][2];
#pragma unroll
    for (int i = 0; i < RPT; i++)
#pragma unroll
        for (int q = 0; q < 2; q++) acc[i][q] = make_float4(0.f, 0.f, 0.f, 0.f);

    for (int k0 = 0; k0 < 128; k0 += 16) {
        if (ROWS == 64) {
            int r = t >> 2, kc = (t & 3) * 4;
            int rr = row0 + r;
            rr = rr < R ? rr : R - 1;
            float4 av = *(const float4*)(A + (size_t)rr * 128 + k0 + kc);
            if (PROBN) {
                float4 sA = *(const float4*)&ABsh[k0 + kc];
                float4 sB = *(const float4*)&ABsh[128 + k0 + kc];
                av.x = av.x * sA.x + sB.x; av.y = av.y * sA.y + sB.y;
                av.z = av.z * sA.z + sB.z; av.w = av.w * sA.w + sB.w;
            }
            As[kc + 0][r] = av.x; As[kc + 1][r] = av.y;
            As[kc + 2][r] = av.z; As[kc + 3][r] = av.w;
        } else {  // ROWS == 32
            int r = t >> 3, kc = (t & 7) * 2;
            int rr = row0 + r;
            rr = rr < R ? rr : R - 1;
            float2 av;
            if (HALFIN) {
                av = ldh2((const unsigned short*)A + (size_t)rr * 128 + k0 + kc);
            } else {
                av = *(const float2*)(A + (size_t)rr * 128 + k0 + kc);
            }
            if (PROBN) {
                av.x = av.x * ABsh[k0 + kc] + ABsh[128 + k0 + kc];
                av.y = av.y * ABsh[k0 + kc + 1] + ABsh[128 + k0 + kc + 1];
            }
            As[kc + 0][r] = av.x;
            As[kc + 1][r] = av.y;
        }
        {
            int kk = t >> 5, c4 = (t & 31) * 4;
            float4 bv0 = *(const float4*)(B + (size_t)(k0 + kk) * ldb + bcol + c4);
            float4 bv1 = *(const float4*)(B + (size_t)(k0 + kk + 8) * ldb + bcol + c4);
            *(float4*)&Bs[kk][c4] = bv0;
            *(float4*)&Bs[kk + 8][c4] = bv1;
        }
        __syncthreads();
#pragma unroll
        for (int kk = 0; kk < 16; kk++) {
            float ar[RPT];
            if (RPT == 4) {
                float4 a4 = *(const float4*)&As[kk][ty * 4];
                ar[0] = a4.x; ar[1] = a4.y; ar[2] = a4.z; ar[3] = a4.w;
            } else {
                float2 a2 = *(const float2*)&As[kk][ty * 2];
                ar[0] = a2.x; ar[RPT - 1] = a2.y;
            }
            float4 b0 = *(const float4*)&Bs[kk][4 * tx];
            float4 b1 = *(const float4*)&Bs[kk][64 + 4 * tx];
#pragma unroll
            for (int i = 0; i < RPT; i++) {
                acc[i][0].x = fmaf(ar[i], b0.x, acc[i][0].x);
                acc[i][0].y = fmaf(ar[i], b0.y, acc[i][0].y);
                acc[i][0].z = fmaf(ar[i], b0.z, acc[i][0].z);
                acc[i][0].w = fmaf(ar[i], b0.w, acc[i][0].w);
                acc[i][1].x = fmaf(ar[i], b1.x, acc[i][1].x);
                acc[i][1].y = fmaf(ar[i], b1.y, acc[i][1].y);
                acc[i][1].z = fmaf(ar[i], b1.z, acc[i][1].z);
                acc[i][1].w = fmaf(ar[i], b1.w, acc[i][1].w);
            }
        }
        __syncthreads();
    }

    float4 bv0 = make_float4(0.f, 0.f, 0.f, 0.f), bv1 = bv0;
    if (bias) {
        bv0 = *(const float4*)(bias + bcol + 4 * tx);
        bv1 = *(const float4*)(bias + bcol + 64 + 4 * tx);
    }
    float4 cs0 = make_float4(0.f, 0.f, 0.f, 0.f), cs1 = cs0, cq0 = cs0, cq1 = cs0;
#pragma unroll
    for (int i = 0; i < RPT; i++) {
        int row = row0 + ty * RPT + i;
        if (row >= R) continue;
        float4 v0, v1;
        v0.x = acc[i][0].x * scale + bv0.x; v0.y = acc[i][0].y * scale + bv0.y;
        v0.z = acc[i][0].z * scale + bv0.z; v0.w = acc[i][0].w * scale + bv0.w;
        v1.x = acc[i][1].x * scale + bv1.x; v1.y = acc[i][1].y * scale + bv1.y;
        v1.z = acc[i][1].z * scale + bv1.z; v1.w = acc[i][1].w * scale + bv1.w;
        if (LRELU) {
            v0.x = lrelu_f(v0.x); v0.y = lrelu_f(v0.y); v0.z = lrelu_f(v0.z); v0.w = lrelu_f(v0.w);
            v1.x = lrelu_f(v1.x); v1.y = lrelu_f(v1.y); v1.z = lrelu_f(v1.z); v1.w = lrelu_f(v1.w);
        }
        if (RESID) {
            float4 r0 = *(const float4*)(resid + (size_t)row * 128 + bcol + 4 * tx);
            float4 r1 = *(const float4*)(resid + (size_t)row * 128 + bcol + 64 + 4 * tx);
            v0.x += r0.x; v0.y += r0.y; v0.z += r0.z; v0.w += r0.w;
            v1.x += r1.x; v1.y += r1.y; v1.z += r1.z; v1.w += r1.w;
        }
        if (HALFOUT) {
            unsigned short* Ch = (unsigned short*)C;
            if (PACKH2) {
                int h = blockIdx.y;
                unsigned short* c0 = Ch + (size_t)row * ldc + 8 * tx + 2 * h;
                *(unsigned int*)(c0) = packh2(v0.x, v0.y);
                *(unsigned int*)(c0 + 4) = packh2(v0.z, v0.w);
                unsigned short* c1 = Ch + (size_t)row * ldc + 128 + 8 * tx + 2 * h;
                *(unsigned int*)(c1) = packh2(v1.x, v1.y);
                *(unsigned int*)(c1 + 4) = packh2(v1.z, v1.w);
            } else {
                unsigned short* c0 = Ch + (size_t)row * ldc + bcol + 4 * tx;
                *(unsigned int*)(c0) = packh2(v0.x, v0.y);
                *(unsigned int*)(c0 + 2) = packh2(v0.z, v0.w);
                unsigned short* c1 = Ch + (size_t)row * ldc + bcol + 64 + 4 * tx;
                *(unsigned int*)(c1) = packh2(v1.x, v1.y);
                *(unsigned int*)(c1 + 2) = packh2(v1.z, v1.w);
            }
        } else if (PACKH2) {
            int h = blockIdx.y;
            float* c0 = C + (size_t)row * ldc + 8 * tx + 2 * h;
            *(float2*)(c0) = make_float2(v0.x, v0.y);
            *(float2*)(c0 + 4) = make_float2(v0.z, v0.w);
            float* c1 = C + (size_t)row * ldc + 128 + 8 * tx + 2 * h;
            *(float2*)(c1) = make_float2(v1.x, v1.y);
            *(float2*)(c1 + 4) = make_float2(v1.z, v1.w);
        } else {
            *(float4*)(C + (size_t)row * ldc + bcol + 4 * tx) = v0;
            *(float4*)(C + (size_t)row * ldc + bcol + 64 + 4 * tx) = v1;
        }
        if (STATS) {
            cs0.x += v0.x; cs0.y += v0.y; cs0.z += v0.z; cs0.w += v0.w;
            cs1.x += v1.x; cs1.y += v1.y; cs1.z += v1.z; cs1.w += v1.w;
            cq0.x += v0.x * v0.x; cq0.y += v0.y * v0.y; cq0.z += v0.z * v0.z; cq0.w += v0.w * v0.w;
            cq1.x += v1.x * v1.x; cq1.y += v1.y * v1.y; cq1.z += v1.z * v1.z; cq1.w += v1.w * v1.w;
        }
    }
    if (STATS) {
        int bkt = blockIdx.x & (NBKT - 1);
#pragma unroll
        for (int pass = 0; pass < 2; pass++) {
            *(float4*)&Sred[ty][4 * tx] = pass ? cq0 : cs0;
            *(float4*)&Sred[ty][64 + 4 * tx] = pass ? cq1 : cs1;
            __syncthreads();
            if (t < 128) {
                float tot = 0.f;
#pragma unroll
                for (int r = 0; r < 16; r++) tot += Sred[r][t];
                atomicAdd(&stF[bkt * 256 + pass * 128 + t], tot);
            }
            __syncthreads();
        }
    }
}

// ---------------- CSR count + he_n transpose (+watt folded into extra block) ----------------
__global__ void count_edges_watt(const int* __restrict__ he_n, int* __restrict__ counts,
                                 const float* __restrict__ h1_w, const float* __restrict__ h1_att,
                                 const float* __restrict__ h2_w, const float* __restrict__ h2_att,
                                 float* __restrict__ wnA, float* __restrict__ weA,
                                 int* __restrict__ he_nT) {
    int t = threadIdx.x;
    if (blockIdx.x == 1250) {
        for (int j = 0; j < 3; j++) {
            int id = t + 256 * j;
            if (id >= 768) break;
            int which = id / 384;
            int rem = id % 384;
            int h3 = rem >> 7, k = rem & 127;
            float s = 0.f;
            if (h3 < 2) {
                const float* wrow = h1_w + (size_t)k * 256 + h3 * 128;
                const float* arow = h1_att + h3 * 256 + which * 128;
                for (int c = 0; c < 128; c++) s += wrow[c] * arow[c];
            } else {
                const float* wrow = h2_w + (size_t)k * 128;
                const float* arow = h2_att + which * 128;
                for (int c = 0; c < 128; c++) s += wrow[c] * arow[c];
            }
            (which ? weA : wnA)[h3 * 128 + k] = s;
        }
        return;
    }
    int g = blockIdx.x * 256 + t;
    if (g < Ee) {
        int m = g / KPB;
        int k = g - m * KPB;
        int n = he_n[m + (size_t)k * Mm];
        he_nT[g] = n;
        atomicAdd(&counts[n], 1);
    }
}

// ---------------- BN dots (+in-kernel finalize; block 0 publishes AB; +fill_csr fold) ------
// R8: X is fp16 (pre-BN). Dots computed on BN(fp16 X) in fp32.
template <int H, bool FILL>
__global__ __launch_bounds__(256) void bn_dots(const unsigned short* __restrict__ X,
                                               const float* __restrict__ stIn,
                                               const float* __restrict__ fing,
                                               const float* __restrict__ finb,
                                               float* __restrict__ ABout,
                                               const float* __restrict__ wn,
                                               const float* __restrict__ we,
                                               float* __restrict__ an,
                                               float* __restrict__ pe,
                                               const int* __restrict__ he_n,
                                               const int* __restrict__ offs,
                                               int* __restrict__ cursor,
                                               int* __restrict__ eid, int mainBlocks) {
    int t = threadIdx.x;
    if (FILL && (int)blockIdx.x >= mainBlocks) {
        int e = (blockIdx.x - mainBlocks) * 256 + t;
        if (e < Ee) {
            int n = he_n[e];
            int p = atomicAdd(&cursor[n], 1);
            eid[offs[n] + p] = e;
        }
        return;
    }
    __shared__ float ABsh[256];
    finalize_to_lds(stIn, fing, finb, ABsh, t);
    if (blockIdx.x == 0) ABout[t] = ABsh[t];
    int w = t >> 6, lane = t & 63;
    float a0 = ABsh[lane], a1 = ABsh[lane + 64];
    float b0 = ABsh[128 + lane], b1 = ABsh[192 + lane];
    float wn0[H], wn1[H], we0[H], we1[H];
#pragma unroll
    for (int h = 0; h < H; h++) {
        wn0[h] = wn[h * 128 + lane]; wn1[h] = wn[h * 128 + 64 + lane];
        we0[h] = we[h * 128 + lane]; we1[h] = we[h * 128 + 64 + lane];
    }
#pragma unroll
    for (int nn = 0; nn < 4; nn++) {
        int row = blockIdx.x * 16 + w * 4 + nn;
        const unsigned short* xr = X + (size_t)row * 128;
        float v0 = h2f(xr[lane]) * a0 + b0;
        float v1 = h2f(xr[lane + 64]) * a1 + b1;
        float pv[H], qv[H];
#pragma unroll
        for (int h = 0; h < H; h++) {
            pv[h] = wave_sum(v0 * wn0[h] + v1 * wn1[h]);
            qv[h] = wave_sum(v0 * we0[h] + v1 * we1[h]);
        }
        if (lane == 0) {
            if (H == 2) {
                *(float2*)&an[row * 2] = make_float2(pv[0], pv[1]);
                *(float2*)&pe[row * 2] = make_float2(qv[0], qv[1]);
            } else {
                an[row] = pv[0];
                pe[row] = qv[0];
            }
        }
    }
}

// final elementwise BN apply with in-kernel finalize (16 rows/block); fp16 input, fp32 out
__global__ __launch_bounds__(256) void bn_out(const unsigned short* __restrict__ X,
                                              const float* __restrict__ stIn,
                                              const float* __restrict__ fing,
                                              const float* __restrict__ finb,
                                              float* __restrict__ Y) {
    __shared__ float ABsh[256];
    int t = threadIdx.x;
    finalize_to_lds(stIn, fing, finb, ABsh, t);
    int w = t >> 6, lane = t & 63;
    float a0 = ABsh[lane], a1 = ABsh[lane + 64];
    float b0 = ABsh[128 + lane], b1 = ABsh[192 + lane];
#pragma unroll
    for (int nn = 0; nn < 4; nn++) {
        int row = blockIdx.x * 16 + w * 4 + nn;
        const unsigned short* xr = X + (size_t)row * 128;
        float* yr = Y + (size_t)row * 128;
        yr[lane] = h2f(xr[lane]) * a0 + b0;
        yr[lane + 64] = h2f(xr[lane + 64]) * a1 + b1;
    }
}

// ae[m,h] = sum over the 80 member nodes of pe[node,h]  (coalesced via he_nT)
template <int H>
__global__ __launch_bounds__(256) void ea_from_pe(const int* __restrict__ he_nT,
                                                  const float* __restrict__ pe,
                                                  float* __restrict__ ae) {
    int w = threadIdx.x >> 6, lane = threadIdx.x & 63;
    int m = blockIdx.x * 4 + w;
    if (m >= Mm) return;
    float s[H];
#pragma unroll
    for (int h = 0; h < H; h++) s[h] = 0.f;
    for (int k = lane; k < KPB; k += 64) {
        int idx = he_nT[m * KPB + k];
        if (H == 2) {
            float2 p2 = *(const float2*)(pe + (size_t)idx * 2);
            s[0] += p2.x;
            s[H - 1] += p2.y;
        } else {
            s[0] += pe[idx];
        }
    }
#pragma unroll
    for (int h = 0; h < H; h++) s[h] = wave_sum(s[h]);
    if (lane == 0)
#pragma unroll
        for (int h = 0; h < H; h++) ae[m * H + h] = s[h];
}

// per-node softmax STATS ONLY; consumers recompute p from nsp:
//   H=2: nsp[n*8..] = {an0,an1,mx0,mx1} {1/sm0,1/sm1,Dinv*0.5,0}
//   H=1: nsp[n*4..] = {an, mx, 1/sm, Dinv}
template <int H>
__global__ __launch_bounds__(256) void seg_softmax(const int* __restrict__ offs,
                                                   const int* __restrict__ eid,
                                                   const float* __restrict__ an,
                                                   const float* __restrict__ ae,
                                                   const float* __restrict__ he_w,
                                                   float* __restrict__ nsp) {
    int t = threadIdx.x;
    int wv = t >> 6, lane = t & 63;
    int q = lane >> 3, li = lane & 7;
    int n = blockIdx.x * 32 + wv * 8 + q;
    bool valid = n < Nn;
    int base = valid ? offs[n] : 0;
    int deg = valid ? offs[n + 1] - base : 0;
    float anv[H];
#pragma unroll
    for (int h = 0; h < H; h++) anv[h] = valid ? an[n * H + h] : 0.f;

    bool h0 = li < deg, h1 = li + 8 < deg;
    int m0 = 0, m1 = 0;
    float l0[H], l1[H];
    float mx[H];
#pragma unroll
    for (int h = 0; h < H; h++) { mx[h] = -INFINITY; l0[h] = 0.f; l1[h] = 0.f; }
    if (h0) {
        m0 = eid[base + li] % Mm;
#pragma unroll
        for (int h = 0; h < H; h++) {
            l0[h] = lrelu_f(anv[h] + ae[m0 * H + h]);
            mx[h] = fmaxf(mx[h], l0[h]);
        }
    }
    if (h1) {
        m1 = eid[base + li + 8] % Mm;
#pragma unroll
        for (int h = 0; h < H; h++) {
            l1[h] = lrelu_f(anv[h] + ae[m1 * H + h]);
            mx[h] = fmaxf(mx[h], l1[h]);
        }
    }
    for (int c = li + 16; c < deg; c += 8) {
        int m = eid[base + c] % Mm;
#pragma unroll
        for (int h = 0; h < H; h++) mx[h] = fmaxf(mx[h], lrelu_f(anv[h] + ae[m * H + h]));
    }
#pragma unroll
    for (int h = 0; h < H; h++) {
#pragma unroll
        for (int o = 1; o <= 4; o <<= 1) mx[h] = fmaxf(mx[h], __shfl_xor(mx[h], o, 64));
    }
    float sm[H];
#pragma unroll
    for (int h = 0; h < H; h++) sm[h] = 0.f;
    float dn = 0.f;
    if (h0) {
        dn += he_w[m0];
#pragma unroll
        for (int h = 0; h < H; h++) sm[h] += expf(l0[h] - mx[h]);
    }
    if (h1) {
        dn += he_w[m1];
#pragma unroll
        for (int h = 0; h < H; h++) sm[h] += expf(l1[h] - mx[h]);
    }
    for (int c = li + 16; c < deg; c += 8) {
        int m = eid[base + c] % Mm;
        dn += he_w[m];
#pragma unroll
        for (int h = 0; h < H; h++) sm[h] += expf(lrelu_f(anv[h] + ae[m * H + h]) - mx[h]);
    }
#pragma unroll
    for (int o = 1; o <= 4; o <<= 1) dn += __shfl_xor(dn, o, 64);
#pragma unroll
    for (int h = 0; h < H; h++) {
#pragma unroll
        for (int o = 1; o <= 4; o <<= 1) sm[h] += __shfl_xor(sm[h], o, 64);
    }
    if (valid && li == 0) {
        float Dv = dn > 0.f ? 1.0f / dn : 0.0f;
        if (H == 2) {
            *(float4*)(nsp + (size_t)n * 8) = make_float4(anv[0], anv[H - 1], mx[0], mx[H - 1]);
            *(float4*)(nsp + (size_t)n * 8 + 4) =
                make_float4(1.f / sm[0], 1.f / sm[H - 1], 0.5f * Dv, 0.f);
        } else {
            *(float4*)(nsp + (size_t)n * 4) = make_float4(anv[0], mx[0], 1.f / sm[0], Dv);
        }
    }
}

// S[h][m][:] = sum_k p[e,h] * BN(Xh[he_n[e], :])   (8 groups x 32 lanes)
// R8: Xh is fp16 PRE-BN; BN applied inline from AB (published by bn_dots).
template <int H>
__global__ __launch_bounds__(256) void s_build(const unsigned short* __restrict__ Xh,
                                               const float* __restrict__ AB,
                                               const int* __restrict__ he_nT,
                                               const float* __restrict__ nsp,
                                               const float* __restrict__ ae,
                                               float* __restrict__ S) {
    __shared__ int idx[KPB];
    __shared__ float av[KPB][H];
    __shared__ float red[8][H][128];
    int m = blockIdx.x, t = threadIdx.x;
    int g = t >> 5, l = t & 31;
    if (t < KPB) {
        int nd = he_nT[m * KPB + t];
        idx[t] = nd;
        if (H == 2) {
            float4 pa = *(const float4*)(nsp + (size_t)nd * 8);
            float4 pb = *(const float4*)(nsp + (size_t)nd * 8 + 4);
            float2 a2 = *(const float2*)(ae + (size_t)m * 2);
            av[t][0] = expf(lrelu_f(pa.x + a2.x) - pa.z) * pb.x;
            av[t][H - 1] = expf(lrelu_f(pa.y + a2.y) - pa.w) * pb.y;
        } else {
            float4 pa = *(const float4*)(nsp + (size_t)nd * 4);
            float aem = ae[m];
            av[t][0] = expf(lrelu_f(pa.x + aem) - pa.y) * pa.z;
        }
    }
    __syncthreads();
    float4 A4 = ((const float4*)AB)[l];
    float4 B4 = ((const float4*)(AB + 128))[l];
    float4 acc[H];
#pragma unroll
    for (int h = 0; h < H; h++) acc[h] = make_float4(0.f, 0.f, 0.f, 0.f);
#pragma unroll
    for (int kk = 0; kk < KPB / 8; kk++) {
        int k = g + kk * 8;
        float4 v = ldh4(Xh + (size_t)idx[k] * 128 + l * 4);
        v.x = v.x * A4.x + B4.x;
        v.y = v.y * A4.y + B4.y;
        v.z = v.z * A4.z + B4.z;
        v.w = v.w * A4.w + B4.w;
#pragma unroll
        for (int h = 0; h < H; h++) {
            float a = av[k][h];
            acc[h].x = fmaf(a, v.x, acc[h].x);
            acc[h].y = fmaf(a, v.y, acc[h].y);
            acc[h].z = fmaf(a, v.z, acc[h].z);
            acc[h].w = fmaf(a, v.w, acc[h].w);
        }
    }
#pragma unroll
    for (int h = 0; h < H; h++) *(float4*)&red[g][h][l * 4] = acc[h];
    __syncthreads();
    if (t < 32 * H) {
        int h = t >> 5, l2 = t & 31;
        float4 s = make_float4(0.f, 0.f, 0.f, 0.f);
#pragma unroll
        for (int gg = 0; gg < 8; gg++) {
            float4 r = *(const float4*)&red[gg][h][l2 * 4];
            s.x += r.x; s.y += r.y; s.z += r.z; s.w += r.w;
        }
        ((float4*)(S + ((size_t)h * Mm + m) * 128))[l2] = s;
    }
}

// node_agg v7: eo fp16 (eoh), T fp16 in-place (R8). wave = 4 consecutive nodes; staging
// recomputes per-slot {m, c0[,c1]} from eid+nsp+ae; j-segmented main loop. Fence-free stats.
template <int H>
__global__ __launch_bounds__(256) void node_agg(const int* __restrict__ offs,
                                                const int* __restrict__ eid,
                                                const float* __restrict__ nsp,
                                                const float* __restrict__ ae,
                                                const unsigned short* __restrict__ eoh,
                                                const float* __restrict__ bias,
                                                const float* __restrict__ AB,
                                                float* __restrict__ stF,
                                                unsigned short* __restrict__ T) {
    __shared__ float smem[4][256];
    __shared__ float redS[4][128], redQ[4][128];
    int t = threadIdx.x;
    int w = t >> 6, lane = t & 63;
    int n0 = blockIdx.x * 16 + w * 4;
    int o = offs[n0 + (lane < 4 ? lane : 4)];
    int b0 = __shfl(o, 0, 64);
    int b1 = __shfl(o, 1, 64);
    int b2 = __shfl(o, 2, 64);
    int b3 = __shfl(o, 3, 64);
    int b4 = __shfl(o, 4, 64);
    int cnt = b4 - b0;
    int cnt64 = cnt < 64 ? cnt : 64;

    if (lane < cnt64) {
        int slot = b0 + lane;
        int j = (slot >= b1) + (slot >= b2) + (slot >= b3);
        int e = eid[slot];
        int m = e % Mm;
        if (H == 2) {
            float4 pa = *(const float4*)(nsp + (size_t)(n0 + j) * 8);
            float4 pb = *(const float4*)(nsp + (size_t)(n0 + j) * 8 + 4);
            float2 a2 = *(const float2*)(ae + (size_t)m * 2);
            float c0 = expf(lrelu_f(pa.x + a2.x) - pa.z) * pb.x * pb.z;
            float c1 = expf(lrelu_f(pa.y + a2.y) - pa.w) * pb.y * pb.z;
            *(float4*)&smem[w][4 * lane] = make_float4(__int_as_float(m), c0, c1, 0.f);
        } else {
            float4 pa = *(const float4*)(nsp + (size_t)(n0 + j) * 4);
            float c = expf(lrelu_f(pa.x + ae[m]) - pa.y) * pa.z * pa.w;
            *(float2*)&smem[w][2 * lane] = make_float2(__int_as_float(m), c);
        }
    }
    __syncthreads();

    int s1 = min(b1 - b0, cnt64), s2 = min(b2 - b0, cnt64), s3 = min(b3 - b0, cnt64);
    float2 acc0 = make_float2(0.f, 0.f), acc1 = acc0, acc2 = acc0, acc3 = acc0;

#define NA_BODY(ACC, CBEG, CEND)                                                \
    {                                                                           \
        int c = (CBEG);                                                         \
        for (; c + 1 < (CEND); c += 2) {                                        \
            if (H == 2) {                                                       \
                float4 sa = *(const float4*)&smem[w][4 * c];                    \
                float4 sb = *(const float4*)&smem[w][4 * (c + 1)];              \
                float4 ea = ldh4(eoh + (size_t)__float_as_int(sa.x) * 256 + 4 * lane); \
                float4 eb = ldh4(eoh + (size_t)__float_as_int(sb.x) * 256 + 4 * lane); \
                ACC.x += sa.y * ea.x + sa.z * ea.z + sb.y * eb.x + sb.z * eb.z; \
                ACC.y += sa.y * ea.y + sa.z * ea.w + sb.y * eb.y + sb.z * eb.w; \
            } else {                                                            \
                float2 sa = *(const float2*)&smem[w][2 * c];                    \
                float2 sb = *(const float2*)&smem[w][2 * (c + 1)];              \
                float2 ea = ldh2(eoh + (size_t)__float_as_int(sa.x) * 128 + 2 * lane); \
                float2 eb = ldh2(eoh + (size_t)__float_as_int(sb.x) * 128 + 2 * lane); \
                ACC.x += sa.y * ea.x + sb.y * eb.x;                             \
                ACC.y += sa.y * ea.y + sb.y * eb.y;                             \
            }                                                                   \
        }                                                                       \
        if (c < (CEND)) {                                                       \
            if (H == 2) {                                                       \
                float4 sa = *(const float4*)&smem[w][4 * c];                    \
                float4 ea = ldh4(eoh + (size_t)__float_as_int(sa.x) * 256 + 4 * lane); \
                ACC.x += sa.y * ea.x + sa.z * ea.z;                             \
                ACC.y += sa.y * ea.y + sa.z * ea.w;                             \
            } else {                                                            \
                float2 sa = *(const float2*)&smem[w][2 * c];                    \
                float2 ea = ldh2(eoh + (size_t)__float_as_int(sa.x) * 128 + 2 * lane); \
                ACC.x += sa.y * ea.x;                                           \
                ACC.y += sa.y * ea.y;                                           \
            }                                                                   \
        }                                                                       \
    }
    NA_BODY(acc0, 0, s1)
    NA_BODY(acc1, s1, s2)
    NA_BODY(acc2, s2, s3)
    NA_BODY(acc3, s3, cnt64)
#undef NA_BODY

    for (int ss = 64; ss < cnt; ss++) {  // rare tail (cnt > 64): recompute coef inline
        int slot = b0 + ss;
        int j = (slot >= b1) + (slot >= b2) + (slot >= b3);
        int e = eid[slot];
        int m = e % Mm;
        float cx, cy;
        if (H == 2) {
            float4 pa = *(const float4*)(nsp + (size_t)(n0 + j) * 8);
            float4 pb = *(const float4*)(nsp + (size_t)(n0 + j) * 8 + 4);
            float2 a2 = *(const float2*)(ae + (size_t)m * 2);
            float c0 = expf(lrelu_f(pa.x + a2.x) - pa.z) * pb.x * pb.z;
            float c1 = expf(lrelu_f(pa.y + a2.y) - pa.w) * pb.y * pb.z;
            float4 ev = ldh4(eoh + (size_t)m * 256 + 4 * lane);
            cx = c0 * ev.x + c1 * ev.z;
            cy = c0 * ev.y + c1 * ev.w;
        } else {
            float4 pa = *(const float4*)(nsp + (size_t)(n0 + j) * 4);
            float c = expf(lrelu_f(pa.x + ae[m]) - pa.y) * pa.z * pa.w;
            float2 ev = ldh2(eoh + (size_t)m * 128 + 2 * lane);
            cx = c * ev.x;
            cy = c * ev.y;
        }
        if (j == 0) { acc0.x += cx; acc0.y += cy; }
        else if (j == 1) { acc1.x += cx; acc1.y += cy; }
        else if (j == 2) { acc2.x += cx; acc2.y += cy; }
        else { acc3.x += cx; acc3.y += cy; }
    }

    int col = 2 * lane;
    float2 A2 = *(const float2*)(AB + col);
    float2 B2 = *(const float2*)(AB + 128 + col);
    float2 bi = *(const float2*)(bias + col);
    float cs0 = 0.f, cs1 = 0.f, cq0 = 0.f, cq1 = 0.f;
    float2 accs[4] = {acc0, acc1, acc2, acc3};
#pragma unroll
    for (int j = 0; j < 4; j++) {
        int n = n0 + j;
        float2 xr = ldh2(T + (size_t)n * 128 + col);
        float r0 = xr.x * A2.x + B2.x + bi.x + accs[j].x;
        float r1 = xr.y * A2.y + B2.y + bi.y + accs[j].y;
        *(unsigned int*)(T + (size_t)n * 128 + col) = packh2(r0, r1);
        cs0 += r0; cs1 += r1;
        cq0 += r0 * r0; cq1 += r1 * r1;
    }
    redS[w][col] = cs0; redS[w][col + 1] = cs1;
    redQ[w][col] = cq0; redQ[w][col + 1] = cq1;
    __syncthreads();
    if (t < 128) {
        float s = 0.f, qq = 0.f;
#pragma unroll
        for (int ww = 0; ww < 4; ww++) { s += redS[ww][t]; qq += redQ[ww][t]; }
        int bkt = blockIdx.x & (NBKT - 1);
        atomicAdd(&stF[bkt * 256 + t], s);
        atomicAdd(&stF[bkt * 256 + 128 + t], qq);
    }
}

extern "C" void kernel_launch(void* const* d_in, const int* in_sizes, int n_in,
                              void* d_out, int out_size, void* d_ws, size_t ws_size,
                              hipStream_t stream) {
    const float* x = (const float*)d_in[0];
    const int* he_n = (const int*)d_in[1];
    const float* he_w = (const float*)d_in[3];
    const float* lin1_w = (const float*)d_in[4];
    const float* lin1_b = (const float*)d_in[5];
    const float* bn1_g = (const float*)d_in[6];
    const float* bn1_b = (const float*)d_in[7];
    const float* h1_w = (const float*)d_in[8];
    const float* h1_att = (const float*)d_in[9];
    const float* h1_b = (const float*)d_in[10];
    const float* bn2_g = (const float*)d_in[11];
    const float* bn2_b = (const float*)d_in[12];
    const float* h2_w = (const float*)d_in[13];
    const float* h2_att = (const float*)d_in[14];
    const float* h2_b = (const float*)d_in[15];
    const float* bn3_g = (const float*)d_in[16];
    const float* bn3_b = (const float*)d_in[17];
    const float* lin2_w = (const float*)d_in[18];
    const float* lin2_b = (const float*)d_in[19];
    const float* bn4_g = (const float*)d_in[20];
    const float* bn4_b = (const float*)d_in[21];
    float* out = (float*)d_out;

    char* ws = (char*)d_ws;
    size_t off = 0;
    auto alloc = [&](size_t bytes) -> char* {
        char* p = ws + off;
        off = (off + bytes + 255) & ~(size_t)255;
        return p;
    };
    // --- zeroed region (one memset) ---
    int* counts = (int*)alloc((size_t)Nn * 4);
    int* cursor = (int*)alloc((size_t)Nn * 4);
    float* stats = (float*)alloc((size_t)4 * NBKT * 256 * 4);
    size_t zbytes = off;
    // --- rest ---
    int* offs = (int*)alloc((size_t)(Nn + 1) * 4);
    int* eid = (int*)alloc((size_t)Ee * 4);
    int* he_nT = (int*)alloc((size_t)Ee * 4);
    float* an = (float*)alloc((size_t)Nn * 2 * 4);
    float* pe = (float*)alloc((size_t)Nn * 2 * 4);
    float* ae = (float*)alloc((size_t)Mm * 2 * 4);
    float* nsp = (float*)alloc((size_t)Nn * 8 * 4);
    float* S = (float*)alloc((size_t)2 * Mm * 128 * 4);
    unsigned short* eoh = (unsigned short*)alloc((size_t)2 * Mm * 128 * 2);
    float* wnA = (float*)alloc(384 * 4);
    float* weA = (float*)alloc(384 * 4);
    float* AB = (float*)alloc(2 * 256 * 4);
    unsigned short* bufq = (unsigned short*)alloc((size_t)Nn * 128 * 2);

    float* st0 = stats;
    float* st1 = stats + NBKT * 256;
    float* st2 = stats + 2 * NBKT * 256;
    float* st3 = stats + 3 * NBKT * 256;
    float *AB1 = AB, *AB2 = AB + 256;

    hipMemsetAsync(d_ws, 0, zbytes, stream);

    constexpr int GB32 = (Nn + 31) / 32;    // 1563
    // CSR count + he_n transpose (+watt in extra block)
    count_edges_watt<<<1251, 256, 0, stream>>>(he_n, counts, h1_w, h1_att, h2_w, h2_att,
                                               wnA, weA, he_nT);

    // stage 1: bufq = fp16(lrelu(x@lin1_w + b)); fused bn1 stats (fp32); +49 scan blocks
    gemmT<32, true, false, false, true, false, true, true, false>
        <<<dim3(GB32 + NBSCAN, 1), 256, 0, stream>>>(
        x, 0, lin1_w, 128, lin1_b, 1.f, nullptr, nullptr, nullptr, nullptr, st0,
        (float*)bufq, 128, Nn, GB32, counts, offs);
    // bn1 dots (finalizes st0 in-kernel; block 0 publishes AB1); +1250 blocks fill_csr
    bn_dots<2, true><<<3125 + 1250, 256, 0, stream>>>(bufq, st0, bn1_g, bn1_b, AB1, wnA, weA,
                                                      an, pe, he_n, offs, cursor, eid, 3125);

    // hgconv1 (H=2); BN1 applied inline from AB1 against fp16 bufq; eo fp16
    ea_from_pe<2><<<Mm / 4, 256, 0, stream>>>(he_nT, pe, ae);
    seg_softmax<2><<<(Nn + 31) / 32, 256, 0, stream>>>(offs, eid, an, ae, he_w, nsp);
    s_build<2><<<Mm, 256, 0, stream>>>(bufq, AB1, he_nT, nsp, ae, S);
    gemmT<32, false, false, false, false, true, false, true, false>
        <<<dim3(125, 2), 256, 0, stream>>>(
        S, (size_t)Mm * 128, h1_w, 256, nullptr, BINV, nullptr, nullptr, nullptr, nullptr,
        nullptr, (float*)eoh, 256, Mm, 125, nullptr, nullptr);
    node_agg<2><<<3125, 256, 0, stream>>>(offs, eid, nsp, ae, eoh, h1_b, AB1, st1, bufq);

    // stage 2 dots (finalizes st1 -> AB2)
    bn_dots<1, false><<<3125, 256, 0, stream>>>(bufq, st1, bn2_g, bn2_b, AB2, wnA + 256,
                                                weA + 256, an, pe, nullptr, nullptr, nullptr,
                                                nullptr, 3125);

    // hgconv2 (H=1); BN2 applied inline from AB2; eo fp16
    ea_from_pe<1><<<Mm / 4, 256, 0, stream>>>(he_nT, pe, ae);
    seg_softmax<1><<<(Nn + 31) / 32, 256, 0, stream>>>(offs, eid, an, ae, he_w, nsp);
    s_build<1><<<Mm, 256, 0, stream>>>(bufq, AB2, he_nT, nsp, ae, S);
    gemmT<32, false, false, false, false, false, false, true, false>
        <<<dim3(125, 1), 256, 0, stream>>>(
        S, 0, h2_w, 128, nullptr, BINV, nullptr, nullptr, nullptr, nullptr, nullptr,
        (float*)eoh, 128, Mm, 125, nullptr, nullptr);
    node_agg<1><<<3125, 256, 0, stream>>>(offs, eid, nsp, ae, eoh, h2_b, AB2, st2, bufq);

    // lin2: fp16 A (bufq) + in-kernel BN3 finalize/apply, lrelu + fp32 residual + bn4 stats;
    // writes fp16 in-place
    gemmT<32, true, true, true, true, false, false, true, true>
        <<<dim3(GB32, 1), 256, 0, stream>>>(
        (const float*)bufq, 0, lin2_w, 128, lin2_b, 1.f, st2, bn3_g, bn3_b, x, st3,
        (float*)bufq, 128, Nn, GB32, nullptr, nullptr);
    // final BN4: in-kernel finalize (st3) + apply; fp16 -> fp32 out
    bn_out<<<3125, 256, 0, stream>>>(bufq, st3, bn4_g, bn4_b, out);
}

// Round 9
// 348.116 us; speedup vs baseline: 1.1698x; 1.0159x over previous
//
#include <hip/hip_runtime.h>
#include <hip/hip_fp16.h>
#include <math.h>

constexpr int Nn = 50000;
constexpr int Mm = 4000;
constexpr int Ee = 320000;
constexpr int KPB = Ee / Mm;           // 80 entries per hyperedge (he_e = i % M)
constexpr float BINV = 1.0f / (float)KPB;
constexpr float EPSf = 1e-5f;
constexpr int NBKT = 16;               // stat buckets (fp32 atomics, no fence!)
constexpr int NBSCAN = 49;             // scan blocks (1024 nodes each)

typedef _Float16 half2v __attribute__((ext_vector_type(2)));

__device__ __forceinline__ float lrelu_f(float x) { return x >= 0.f ? x : 0.2f * x; }

__device__ __forceinline__ unsigned short f2h(float f) {
    __half h = __float2half_rn(f);
    return *reinterpret_cast<unsigned short*>(&h);
}
__device__ __forceinline__ float h2f(unsigned short s) {
    __half_raw r; r.x = s;
    return __half2float(__half(r));
}
__device__ __forceinline__ unsigned int packh2(float a, float b) {
    return (unsigned int)f2h(a) | ((unsigned int)f2h(b) << 16);
}
__device__ __forceinline__ float4 ldh4(const unsigned short* p) {
    ushort4 u = *(const ushort4*)p;
    return make_float4(h2f(u.x), h2f(u.y), h2f(u.z), h2f(u.w));
}
__device__ __forceinline__ float2 ldh2(const unsigned short* p) {
    ushort2 u = *(const ushort2*)p;
    return make_float2(h2f(u.x), h2f(u.y));
}
__device__ __forceinline__ unsigned int packf2h2(float a, float b) {
    union { half2v h; unsigned int u; } cv;
    cv.h[0] = (_Float16)a; cv.h[1] = (_Float16)b;
    return cv.u;
}
__device__ __forceinline__ float fdot2f(unsigned int a, unsigned int b, float c) {
    union { unsigned int u; half2v h; } ua, ub;
    ua.u = a; ub.u = b;
    return __builtin_amdgcn_fdot2(ua.h, ub.h, c, false);
}

__device__ __forceinline__ float wave_sum(float v) {
#pragma unroll
    for (int o = 32; o >= 1; o >>= 1) v += __shfl_xor(v, o, 64);
    return v;
}

// Consumer-side BN finalize: stats buckets (prev kernel's fp32 atomics) -> AB in LDS.
__device__ __forceinline__ void finalize_to_lds(const float* __restrict__ st,
                                                const float* __restrict__ g,
                                                const float* __restrict__ b,
                                                float* ABsh, int t) {
    if (t < 128) {
        double ds = 0, dq = 0;
#pragma unroll
        for (int i = 0; i < NBKT; i++) {
            ds += (double)st[i * 256 + t];
            dq += (double)st[i * 256 + 128 + t];
        }
        double mean = ds / (double)Nn;
        double var = dq / (double)Nn - mean * mean;
        float rstd = (float)(1.0 / sqrt(var + (double)EPSf));
        float A = g[t] * rstd;
        ABsh[t] = A;
        ABsh[128 + t] = b[t] - (float)mean * A;
    }
    __syncthreads();
}

// exclusive scan of counts -> offs; block b handles nodes [b*1024, b*1024+1024)
__device__ void scan_body(const int* __restrict__ counts, int* __restrict__ offs,
                          int b, int t) {
    __shared__ int sdi[256];
    int pre = 0;
    for (int i = t; i < b * 1024; i += 256) pre += counts[i];
    sdi[t] = pre;
    __syncthreads();
    for (int st = 128; st >= 1; st >>= 1) {
        if (t < st) sdi[t] += sdi[t + st];
        __syncthreads();
    }
    int run0 = sdi[0];
    __syncthreads();
    int c4[4];
    int s = 0;
#pragma unroll
    for (int i = 0; i < 4; i++) {
        int n = b * 1024 + t * 4 + i;
        c4[i] = (n < Nn) ? counts[n] : 0;
        s += c4[i];
    }
    sdi[t] = s;
    __syncthreads();
    for (int off = 1; off < 256; off <<= 1) {
        int v = (t >= off) ? sdi[t - off] : 0;
        __syncthreads();
        sdi[t] += v;
        __syncthreads();
    }
    int run = sdi[t] - s + run0;
#pragma unroll
    for (int i = 0; i < 4; i++) {
        int n = b * 1024 + t * 4 + i;
        if (n < Nn) offs[n] = run;
        run += c4[i];
    }
    if (b == NBSCAN - 1 && t == 255) offs[Nn] = run0 + sdi[255];
}

// ---------------- GEMM: C[R, bcol:+128] = op(op_bn(A[R,128]) @ B[:, bcol:+128]) -------------
// BK=16, A-tile transposed in LDS. ROWS=32 for the Nn gemms.
// PROBN: in-kernel BN finalize + apply on A load. PACKH2: eo col-pair interleave (h=blockIdx.y).
// STATS: bucketed fp32 atomics (fence-free). SCANX: extra x-blocks run the CSR offset scan.
// HALFOUT: C is fp16. HALFIN: A is fp16. DOT16 (R9): stage A/B as packed fp16 k-pairs and
// use v_dot2_f32_f16 (fp32 accumulate) -- halves FMA instruction count and LDS-read ops.
template <int ROWS, bool LRELU, bool PROBN, bool RESID, bool STATS, bool PACKH2, bool SCANX,
          bool HALFOUT, bool HALFIN, bool DOT16>
__global__ __launch_bounds__(256) void gemmT(const float* __restrict__ A, size_t aystride,
                                             const float* __restrict__ B, int ldb,
                                             const float* __restrict__ bias, float scale,
                                             const float* __restrict__ stIn,
                                             const float* __restrict__ fing,
                                             const float* __restrict__ finb,
                                             const float* __restrict__ resid,
                                             float* __restrict__ stF,
                                             float* __restrict__ C, int ldc, int R,
                                             int gemmBlocksX,
                                             const int* __restrict__ counts,
                                             int* __restrict__ offs) {
    constexpr int RPT = ROWS / 16;
    const int t = threadIdx.x;
    if (SCANX && (int)blockIdx.x >= gemmBlocksX) {
        if (blockIdx.y == 0) scan_body(counts, offs, blockIdx.x - gemmBlocksX, t);
        return;
    }
    __shared__ float As[DOT16 ? 1 : 16][ROWS + 4];
    __shared__ float Bs[DOT16 ? 1 : 16][128];
    __shared__ unsigned int As2[DOT16 ? 8 : 1][ROWS + 4];
    __shared__ unsigned int Bs2[DOT16 ? 8 : 1][128];
    __shared__ float Sred[STATS ? 16 : 1][STATS ? 128 : 1];
    __shared__ float ABsh[PROBN ? 256 : 1];
    const int ty = t >> 4, tx = t & 15;
    const int row0 = blockIdx.x * ROWS;
    const int bcol = blockIdx.y * 128;
    A += (size_t)blockIdx.y * aystride;

    if (PROBN) finalize_to_lds(stIn, fing, finb, ABsh, t);

    float4 acc[RPT][2];
#pragma unroll
    for (int i = 0; i < RPT; i++)
#pragma unroll
        for (int q = 0; q < 2; q++) acc[i][q] = make_float4(0.f, 0.f, 0.f, 0.f);

    for (int k0 = 0; k0 < 128; k0 += 16) {
        if (DOT16) {  // ROWS==32 only
            {
                int r = t >> 3, kc = (t & 7) * 2;
                int rr = row0 + r;
                rr = rr < R ? rr : R - 1;
                float2 av;
                if (HALFIN) {
                    av = ldh2((const unsigned short*)A + (size_t)rr * 128 + k0 + kc);
                } else {
                    av = *(const float2*)(A + (size_t)rr * 128 + k0 + kc);
                }
                if (PROBN) {
                    av.x = av.x * ABsh[k0 + kc] + ABsh[128 + k0 + kc];
                    av.y = av.y * ABsh[k0 + kc + 1] + ABsh[128 + k0 + kc + 1];
                }
                As2[kc >> 1][r] = packf2h2(av.x, av.y);
            }
            {
                int kk = t >> 5, c4 = (t & 31) * 4;
                float4 bv0 = *(const float4*)(B + (size_t)(k0 + 2 * kk) * ldb + bcol + c4);
                float4 bv1 = *(const float4*)(B + (size_t)(k0 + 2 * kk + 1) * ldb + bcol + c4);
                Bs2[kk][c4 + 0] = packf2h2(bv0.x, bv1.x);
                Bs2[kk][c4 + 1] = packf2h2(bv0.y, bv1.y);
                Bs2[kk][c4 + 2] = packf2h2(bv0.z, bv1.z);
                Bs2[kk][c4 + 3] = packf2h2(bv0.w, bv1.w);
            }
            __syncthreads();
#pragma unroll
            for (int j = 0; j < 8; j++) {
                uint4 b0 = *(const uint4*)&Bs2[j][4 * tx];
                uint4 b1 = *(const uint4*)&Bs2[j][64 + 4 * tx];
#pragma unroll
                for (int i = 0; i < RPT; i++) {
                    unsigned int au = As2[j][ty * RPT + i];
                    acc[i][0].x = fdot2f(au, b0.x, acc[i][0].x);
                    acc[i][0].y = fdot2f(au, b0.y, acc[i][0].y);
                    acc[i][0].z = fdot2f(au, b0.z, acc[i][0].z);
                    acc[i][0].w = fdot2f(au, b0.w, acc[i][0].w);
                    acc[i][1].x = fdot2f(au, b1.x, acc[i][1].x);
                    acc[i][1].y = fdot2f(au, b1.y, acc[i][1].y);
                    acc[i][1].z = fdot2f(au, b1.z, acc[i][1].z);
                    acc[i][1].w = fdot2f(au, b1.w, acc[i][1].w);
                }
            }
            __syncthreads();
            continue;
        }
        if (ROWS == 64) {
            int r = t >> 2, kc = (t & 3) * 4;
            int rr = row0 + r;
            rr = rr < R ? rr : R - 1;
            float4 av = *(const float4*)(A + (size_t)rr * 128 + k0 + kc);
            if (PROBN) {
                float4 sA = *(const float4*)&ABsh[k0 + kc];
                float4 sB = *(const float4*)&ABsh[128 + k0 + kc];
                av.x = av.x * sA.x + sB.x; av.y = av.y * sA.y + sB.y;
                av.z = av.z * sA.z + sB.z; av.w = av.w * sA.w + sB.w;
            }
            As[kc + 0][r] = av.x; As[kc + 1][r] = av.y;
            As[kc + 2][r] = av.z; As[kc + 3][r] = av.w;
        } else {  // ROWS == 32
            int r = t >> 3, kc = (t & 7) * 2;
            int rr = row0 + r;
            rr = rr < R ? rr : R - 1;
            float2 av;
            if (HALFIN) {
                av = ldh2((const unsigned short*)A + (size_t)rr * 128 + k0 + kc);
            } else {
                av = *(const float2*)(A + (size_t)rr * 128 + k0 + kc);
            }
            if (PROBN) {
                av.x = av.x * ABsh[k0 + kc] + ABsh[128 + k0 + kc];
                av.y = av.y * ABsh[k0 + kc + 1] + ABsh[128 + k0 + kc + 1];
            }
            As[kc + 0][r] = av.x;
            As[kc + 1][r] = av.y;
        }
        {
            int kk = t >> 5, c4 = (t & 31) * 4;
            float4 bv0 = *(const float4*)(B + (size_t)(k0 + kk) * ldb + bcol + c4);
            float4 bv1 = *(const float4*)(B + (size_t)(k0 + kk + 8) * ldb + bcol + c4);
            *(float4*)&Bs[kk][c4] = bv0;
            *(float4*)&Bs[kk + 8][c4] = bv1;
        }
        __syncthreads();
#pragma unroll
        for (int kk = 0; kk < 16; kk++) {
            float ar[RPT];
            if (RPT == 4) {
                float4 a4 = *(const float4*)&As[kk][ty * 4];
                ar[0] = a4.x; ar[1] = a4.y; ar[2] = a4.z; ar[3] = a4.w;
            } else {
                float2 a2 = *(const float2*)&As[kk][ty * 2];
                ar[0] = a2.x; ar[RPT - 1] = a2.y;
            }
            float4 b0 = *(const float4*)&Bs[kk][4 * tx];
            float4 b1 = *(const float4*)&Bs[kk][64 + 4 * tx];
#pragma unroll
            for (int i = 0; i < RPT; i++) {
                acc[i][0].x = fmaf(ar[i], b0.x, acc[i][0].x);
                acc[i][0].y = fmaf(ar[i], b0.y, acc[i][0].y);
                acc[i][0].z = fmaf(ar[i], b0.z, acc[i][0].z);
                acc[i][0].w = fmaf(ar[i], b0.w, acc[i][0].w);
                acc[i][1].x = fmaf(ar[i], b1.x, acc[i][1].x);
                acc[i][1].y = fmaf(ar[i], b1.y, acc[i][1].y);
                acc[i][1].z = fmaf(ar[i], b1.z, acc[i][1].z);
                acc[i][1].w = fmaf(ar[i], b1.w, acc[i][1].w);
            }
        }
        __syncthreads();
    }

    float4 bv0 = make_float4(0.f, 0.f, 0.f, 0.f), bv1 = bv0;
    if (bias) {
        bv0 = *(const float4*)(bias + bcol + 4 * tx);
        bv1 = *(const float4*)(bias + bcol + 64 + 4 * tx);
    }
    float4 cs0 = make_float4(0.f, 0.f, 0.f, 0.f), cs1 = cs0, cq0 = cs0, cq1 = cs0;
#pragma unroll
    for (int i = 0; i < RPT; i++) {
        int row = row0 + ty * RPT + i;
        if (row >= R) continue;
        float4 v0, v1;
        v0.x = acc[i][0].x * scale + bv0.x; v0.y = acc[i][0].y * scale + bv0.y;
        v0.z = acc[i][0].z * scale + bv0.z; v0.w = acc[i][0].w * scale + bv0.w;
        v1.x = acc[i][1].x * scale + bv1.x; v1.y = acc[i][1].y * scale + bv1.y;
        v1.z = acc[i][1].z * scale + bv1.z; v1.w = acc[i][1].w * scale + bv1.w;
        if (LRELU) {
            v0.x = lrelu_f(v0.x); v0.y = lrelu_f(v0.y); v0.z = lrelu_f(v0.z); v0.w = lrelu_f(v0.w);
            v1.x = lrelu_f(v1.x); v1.y = lrelu_f(v1.y); v1.z = lrelu_f(v1.z); v1.w = lrelu_f(v1.w);
        }
        if (RESID) {
            float4 r0 = *(const float4*)(resid + (size_t)row * 128 + bcol + 4 * tx);
            float4 r1 = *(const float4*)(resid + (size_t)row * 128 + bcol + 64 + 4 * tx);
            v0.x += r0.x; v0.y += r0.y; v0.z += r0.z; v0.w += r0.w;
            v1.x += r1.x; v1.y += r1.y; v1.z += r1.z; v1.w += r1.w;
        }
        if (HALFOUT) {
            unsigned short* Ch = (unsigned short*)C;
            if (PACKH2) {
                int h = blockIdx.y;
                unsigned short* c0 = Ch + (size_t)row * ldc + 8 * tx + 2 * h;
                *(unsigned int*)(c0) = packh2(v0.x, v0.y);
                *(unsigned int*)(c0 + 4) = packh2(v0.z, v0.w);
                unsigned short* c1 = Ch + (size_t)row * ldc + 128 + 8 * tx + 2 * h;
                *(unsigned int*)(c1) = packh2(v1.x, v1.y);
                *(unsigned int*)(c1 + 4) = packh2(v1.z, v1.w);
            } else {
                unsigned short* c0 = Ch + (size_t)row * ldc + bcol + 4 * tx;
                *(unsigned int*)(c0) = packh2(v0.x, v0.y);
                *(unsigned int*)(c0 + 2) = packh2(v0.z, v0.w);
                unsigned short* c1 = Ch + (size_t)row * ldc + bcol + 64 + 4 * tx;
                *(unsigned int*)(c1) = packh2(v1.x, v1.y);
                *(unsigned int*)(c1 + 2) = packh2(v1.z, v1.w);
            }
        } else if (PACKH2) {
            int h = blockIdx.y;
            float* c0 = C + (size_t)row * ldc + 8 * tx + 2 * h;
            *(float2*)(c0) = make_float2(v0.x, v0.y);
            *(float2*)(c0 + 4) = make_float2(v0.z, v0.w);
            float* c1 = C + (size_t)row * ldc + 128 + 8 * tx + 2 * h;
            *(float2*)(c1) = make_float2(v1.x, v1.y);
            *(float2*)(c1 + 4) = make_float2(v1.z, v1.w);
        } else {
            *(float4*)(C + (size_t)row * ldc + bcol + 4 * tx) = v0;
            *(float4*)(C + (size_t)row * ldc + bcol + 64 + 4 * tx) = v1;
        }
        if (STATS) {
            cs0.x += v0.x; cs0.y += v0.y; cs0.z += v0.z; cs0.w += v0.w;
            cs1.x += v1.x; cs1.y += v1.y; cs1.z += v1.z; cs1.w += v1.w;
            cq0.x += v0.x * v0.x; cq0.y += v0.y * v0.y; cq0.z += v0.z * v0.z; cq0.w += v0.w * v0.w;
            cq1.x += v1.x * v1.x; cq1.y += v1.y * v1.y; cq1.z += v1.z * v1.z; cq1.w += v1.w * v1.w;
        }
    }
    if (STATS) {
        int bkt = blockIdx.x & (NBKT - 1);
#pragma unroll
        for (int pass = 0; pass < 2; pass++) {
            *(float4*)&Sred[ty][4 * tx] = pass ? cq0 : cs0;
            *(float4*)&Sred[ty][64 + 4 * tx] = pass ? cq1 : cs1;
            __syncthreads();
            if (t < 128) {
                float tot = 0.f;
#pragma unroll
                for (int r = 0; r < 16; r++) tot += Sred[r][t];
                atomicAdd(&stF[bkt * 256 + pass * 128 + t], tot);
            }
            __syncthreads();
        }
    }
}

// ---------------- CSR count + he_n transpose (+watt folded into extra block) ----------------
__global__ void count_edges_watt(const int* __restrict__ he_n, int* __restrict__ counts,
                                 const float* __restrict__ h1_w, const float* __restrict__ h1_att,
                                 const float* __restrict__ h2_w, const float* __restrict__ h2_att,
                                 float* __restrict__ wnA, float* __restrict__ weA,
                                 int* __restrict__ he_nT) {
    int t = threadIdx.x;
    if (blockIdx.x == 1250) {
        for (int j = 0; j < 3; j++) {
            int id = t + 256 * j;
            if (id >= 768) break;
            int which = id / 384;
            int rem = id % 384;
            int h3 = rem >> 7, k = rem & 127;
            float s = 0.f;
            if (h3 < 2) {
                const float* wrow = h1_w + (size_t)k * 256 + h3 * 128;
                const float* arow = h1_att + h3 * 256 + which * 128;
                for (int c = 0; c < 128; c++) s += wrow[c] * arow[c];
            } else {
                const float* wrow = h2_w + (size_t)k * 128;
                const float* arow = h2_att + which * 128;
                for (int c = 0; c < 128; c++) s += wrow[c] * arow[c];
            }
            (which ? weA : wnA)[h3 * 128 + k] = s;
        }
        return;
    }
    int g = blockIdx.x * 256 + t;
    if (g < Ee) {
        int m = g / KPB;
        int k = g - m * KPB;
        int n = he_n[m + (size_t)k * Mm];
        he_nT[g] = n;
        atomicAdd(&counts[n], 1);
    }
}

// ---------------- BN dots (+in-kernel finalize; block 0 publishes AB; +fill_csr fold) ------
// X is fp16 (pre-BN). Dots computed on BN(fp16 X) in fp32.
template <int H, bool FILL>
__global__ __launch_bounds__(256) void bn_dots(const unsigned short* __restrict__ X,
                                               const float* __restrict__ stIn,
                                               const float* __restrict__ fing,
                                               const float* __restrict__ finb,
                                               float* __restrict__ ABout,
                                               const float* __restrict__ wn,
                                               const float* __restrict__ we,
                                               float* __restrict__ an,
                                               float* __restrict__ pe,
                                               const int* __restrict__ he_n,
                                               const int* __restrict__ offs,
                                               int* __restrict__ cursor,
                                               int* __restrict__ eid, int mainBlocks) {
    int t = threadIdx.x;
    if (FILL && (int)blockIdx.x >= mainBlocks) {
        int e = (blockIdx.x - mainBlocks) * 256 + t;
        if (e < Ee) {
            int n = he_n[e];
            int p = atomicAdd(&cursor[n], 1);
            eid[offs[n] + p] = e;
        }
        return;
    }
    __shared__ float ABsh[256];
    finalize_to_lds(stIn, fing, finb, ABsh, t);
    if (blockIdx.x == 0) ABout[t] = ABsh[t];
    int w = t >> 6, lane = t & 63;
    float a0 = ABsh[lane], a1 = ABsh[lane + 64];
    float b0 = ABsh[128 + lane], b1 = ABsh[192 + lane];
    float wn0[H], wn1[H], we0[H], we1[H];
#pragma unroll
    for (int h = 0; h < H; h++) {
        wn0[h] = wn[h * 128 + lane]; wn1[h] = wn[h * 128 + 64 + lane];
        we0[h] = we[h * 128 + lane]; we1[h] = we[h * 128 + 64 + lane];
    }
#pragma unroll
    for (int nn = 0; nn < 4; nn++) {
        int row = blockIdx.x * 16 + w * 4 + nn;
        const unsigned short* xr = X + (size_t)row * 128;
        float v0 = h2f(xr[lane]) * a0 + b0;
        float v1 = h2f(xr[lane + 64]) * a1 + b1;
        float pv[H], qv[H];
#pragma unroll
        for (int h = 0; h < H; h++) {
            pv[h] = wave_sum(v0 * wn0[h] + v1 * wn1[h]);
            qv[h] = wave_sum(v0 * we0[h] + v1 * we1[h]);
        }
        if (lane == 0) {
            if (H == 2) {
                *(float2*)&an[row * 2] = make_float2(pv[0], pv[1]);
                *(float2*)&pe[row * 2] = make_float2(qv[0], qv[1]);
            } else {
                an[row] = pv[0];
                pe[row] = qv[0];
            }
        }
    }
}

// final elementwise BN apply with in-kernel finalize (16 rows/block); fp16 input, fp32 out
__global__ __launch_bounds__(256) void bn_out(const unsigned short* __restrict__ X,
                                              const float* __restrict__ stIn,
                                              const float* __restrict__ fing,
                                              const float* __restrict__ finb,
                                              float* __restrict__ Y) {
    __shared__ float ABsh[256];
    int t = threadIdx.x;
    finalize_to_lds(stIn, fing, finb, ABsh, t);
    int w = t >> 6, lane = t & 63;
    float a0 = ABsh[lane], a1 = ABsh[lane + 64];
    float b0 = ABsh[128 + lane], b1 = ABsh[192 + lane];
#pragma unroll
    for (int nn = 0; nn < 4; nn++) {
        int row = blockIdx.x * 16 + w * 4 + nn;
        const unsigned short* xr = X + (size_t)row * 128;
        float* yr = Y + (size_t)row * 128;
        yr[lane] = h2f(xr[lane]) * a0 + b0;
        yr[lane + 64] = h2f(xr[lane + 64]) * a1 + b1;
    }
}

// ae[m,h] = sum over the 80 member nodes of pe[node,h]  (coalesced via he_nT)
template <int H>
__global__ __launch_bounds__(256) void ea_from_pe(const int* __restrict__ he_nT,
                                                  const float* __restrict__ pe,
                                                  float* __restrict__ ae) {
    int w = threadIdx.x >> 6, lane = threadIdx.x & 63;
    int m = blockIdx.x * 4 + w;
    if (m >= Mm) return;
    float s[H];
#pragma unroll
    for (int h = 0; h < H; h++) s[h] = 0.f;
    for (int k = lane; k < KPB; k += 64) {
        int idx = he_nT[m * KPB + k];
        if (H == 2) {
            float2 p2 = *(const float2*)(pe + (size_t)idx * 2);
            s[0] += p2.x;
            s[H - 1] += p2.y;
        } else {
            s[0] += pe[idx];
        }
    }
#pragma unroll
    for (int h = 0; h < H; h++) s[h] = wave_sum(s[h]);
    if (lane == 0)
#pragma unroll
        for (int h = 0; h < H; h++) ae[m * H + h] = s[h];
}

// per-node softmax STATS ONLY; consumers recompute p from nsp:
//   H=2: nsp[n*8..] = {an0,an1,mx0,mx1} {1/sm0,1/sm1,Dinv*0.5,0}
//   H=1: nsp[n*4..] = {an, mx, 1/sm, Dinv}
template <int H>
__global__ __launch_bounds__(256) void seg_softmax(const int* __restrict__ offs,
                                                   const int* __restrict__ eid,
                                                   const float* __restrict__ an,
                                                   const float* __restrict__ ae,
                                                   const float* __restrict__ he_w,
                                                   float* __restrict__ nsp) {
    int t = threadIdx.x;
    int wv = t >> 6, lane = t & 63;
    int q = lane >> 3, li = lane & 7;
    int n = blockIdx.x * 32 + wv * 8 + q;
    bool valid = n < Nn;
    int base = valid ? offs[n] : 0;
    int deg = valid ? offs[n + 1] - base : 0;
    float anv[H];
#pragma unroll
    for (int h = 0; h < H; h++) anv[h] = valid ? an[n * H + h] : 0.f;

    bool h0 = li < deg, h1 = li + 8 < deg;
    int m0 = 0, m1 = 0;
    float l0[H], l1[H];
    float mx[H];
#pragma unroll
    for (int h = 0; h < H; h++) { mx[h] = -INFINITY; l0[h] = 0.f; l1[h] = 0.f; }
    if (h0) {
        m0 = eid[base + li] % Mm;
#pragma unroll
        for (int h = 0; h < H; h++) {
            l0[h] = lrelu_f(anv[h] + ae[m0 * H + h]);
            mx[h] = fmaxf(mx[h], l0[h]);
        }
    }
    if (h1) {
        m1 = eid[base + li + 8] % Mm;
#pragma unroll
        for (int h = 0; h < H; h++) {
            l1[h] = lrelu_f(anv[h] + ae[m1 * H + h]);
            mx[h] = fmaxf(mx[h], l1[h]);
        }
    }
    for (int c = li + 16; c < deg; c += 8) {
        int m = eid[base + c] % Mm;
#pragma unroll
        for (int h = 0; h < H; h++) mx[h] = fmaxf(mx[h], lrelu_f(anv[h] + ae[m * H + h]));
    }
#pragma unroll
    for (int h = 0; h < H; h++) {
#pragma unroll
        for (int o = 1; o <= 4; o <<= 1) mx[h] = fmaxf(mx[h], __shfl_xor(mx[h], o, 64));
    }
    float sm[H];
#pragma unroll
    for (int h = 0; h < H; h++) sm[h] = 0.f;
    float dn = 0.f;
    if (h0) {
        dn += he_w[m0];
#pragma unroll
        for (int h = 0; h < H; h++) sm[h] += expf(l0[h] - mx[h]);
    }
    if (h1) {
        dn += he_w[m1];
#pragma unroll
        for (int h = 0; h < H; h++) sm[h] += expf(l1[h] - mx[h]);
    }
    for (int c = li + 16; c < deg; c += 8) {
        int m = eid[base + c] % Mm;
        dn += he_w[m];
#pragma unroll
        for (int h = 0; h < H; h++) sm[h] += expf(lrelu_f(anv[h] + ae[m * H + h]) - mx[h]);
    }
#pragma unroll
    for (int o = 1; o <= 4; o <<= 1) dn += __shfl_xor(dn, o, 64);
#pragma unroll
    for (int h = 0; h < H; h++) {
#pragma unroll
        for (int o = 1; o <= 4; o <<= 1) sm[h] += __shfl_xor(sm[h], o, 64);
    }
    if (valid && li == 0) {
        float Dv = dn > 0.f ? 1.0f / dn : 0.0f;
        if (H == 2) {
            *(float4*)(nsp + (size_t)n * 8) = make_float4(anv[0], anv[H - 1], mx[0], mx[H - 1]);
            *(float4*)(nsp + (size_t)n * 8 + 4) =
                make_float4(1.f / sm[0], 1.f / sm[H - 1], 0.5f * Dv, 0.f);
        } else {
            *(float4*)(nsp + (size_t)n * 4) = make_float4(anv[0], mx[0], 1.f / sm[0], Dv);
        }
    }
}

// S[h][m][:] = sum_k p[e,h] * BN(Xh[he_n[e], :])   (8 groups x 32 lanes)
// Xh is fp16 PRE-BN; BN applied inline from AB (published by bn_dots).
template <int H>
__global__ __launch_bounds__(256) void s_build(const unsigned short* __restrict__ Xh,
                                               const float* __restrict__ AB,
                                               const int* __restrict__ he_nT,
                                               const float* __restrict__ nsp,
                                               const float* __restrict__ ae,
                                               float* __restrict__ S) {
    __shared__ int idx[KPB];
    __shared__ float av[KPB][H];
    __shared__ float red[8][H][128];
    int m = blockIdx.x, t = threadIdx.x;
    int g = t >> 5, l = t & 31;
    if (t < KPB) {
        int nd = he_nT[m * KPB + t];
        idx[t] = nd;
        if (H == 2) {
            float4 pa = *(const float4*)(nsp + (size_t)nd * 8);
            float4 pb = *(const float4*)(nsp + (size_t)nd * 8 + 4);
            float2 a2 = *(const float2*)(ae + (size_t)m * 2);
            av[t][0] = expf(lrelu_f(pa.x + a2.x) - pa.z) * pb.x;
            av[t][H - 1] = expf(lrelu_f(pa.y + a2.y) - pa.w) * pb.y;
        } else {
            float4 pa = *(const float4*)(nsp + (size_t)nd * 4);
            float aem = ae[m];
            av[t][0] = expf(lrelu_f(pa.x + aem) - pa.y) * pa.z;
        }
    }
    __syncthreads();
    float4 A4 = ((const float4*)AB)[l];
    float4 B4 = ((const float4*)(AB + 128))[l];
    float4 acc[H];
#pragma unroll
    for (int h = 0; h < H; h++) acc[h] = make_float4(0.f, 0.f, 0.f, 0.f);
#pragma unroll
    for (int kk = 0; kk < KPB / 8; kk++) {
        int k = g + kk * 8;
        float4 v = ldh4(Xh + (size_t)idx[k] * 128 + l * 4);
        v.x = v.x * A4.x + B4.x;
        v.y = v.y * A4.y + B4.y;
        v.z = v.z * A4.z + B4.z;
        v.w = v.w * A4.w + B4.w;
#pragma unroll
        for (int h = 0; h < H; h++) {
            float a = av[k][h];
            acc[h].x = fmaf(a, v.x, acc[h].x);
            acc[h].y = fmaf(a, v.y, acc[h].y);
            acc[h].z = fmaf(a, v.z, acc[h].z);
            acc[h].w = fmaf(a, v.w, acc[h].w);
        }
    }
#pragma unroll
    for (int h = 0; h < H; h++) *(float4*)&red[g][h][l * 4] = acc[h];
    __syncthreads();
    if (t < 32 * H) {
        int h = t >> 5, l2 = t & 31;
        float4 s = make_float4(0.f, 0.f, 0.f, 0.f);
#pragma unroll
        for (int gg = 0; gg < 8; gg++) {
            float4 r = *(const float4*)&red[gg][h][l2 * 4];
            s.x += r.x; s.y += r.y; s.z += r.z; s.w += r.w;
        }
        ((float4*)(S + ((size_t)h * Mm + m) * 128))[l2] = s;
    }
}

// node_agg v7: eo fp16 (eoh), T fp16 in-place. wave = 4 consecutive nodes; staging
// recomputes per-slot {m, c0[,c1]} from eid+nsp+ae; j-segmented main loop. Fence-free stats.
template <int H>
__global__ __launch_bounds__(256) void node_agg(const int* __restrict__ offs,
                                                const int* __restrict__ eid,
                                                const float* __restrict__ nsp,
                                                const float* __restrict__ ae,
                                                const unsigned short* __restrict__ eoh,
                                                const float* __restrict__ bias,
                                                const float* __restrict__ AB,
                                                float* __restrict__ stF,
                                                unsigned short* __restrict__ T) {
    __shared__ float smem[4][256];
    __shared__ float redS[4][128], redQ[4][128];
    int t = threadIdx.x;
    int w = t >> 6, lane = t & 63;
    int n0 = blockIdx.x * 16 + w * 4;
    int o = offs[n0 + (lane < 4 ? lane : 4)];
    int b0 = __shfl(o, 0, 64);
    int b1 = __shfl(o, 1, 64);
    int b2 = __shfl(o, 2, 64);
    int b3 = __shfl(o, 3, 64);
    int b4 = __shfl(o, 4, 64);
    int cnt = b4 - b0;
    int cnt64 = cnt < 64 ? cnt : 64;

    if (lane < cnt64) {
        int slot = b0 + lane;
        int j = (slot >= b1) + (slot >= b2) + (slot >= b3);
        int e = eid[slot];
        int m = e % Mm;
        if (H == 2) {
            float4 pa = *(const float4*)(nsp + (size_t)(n0 + j) * 8);
            float4 pb = *(const float4*)(nsp + (size_t)(n0 + j) * 8 + 4);
            float2 a2 = *(const float2*)(ae + (size_t)m * 2);
            float c0 = expf(lrelu_f(pa.x + a2.x) - pa.z) * pb.x * pb.z;
            float c1 = expf(lrelu_f(pa.y + a2.y) - pa.w) * pb.y * pb.z;
            *(float4*)&smem[w][4 * lane] = make_float4(__int_as_float(m), c0, c1, 0.f);
        } else {
            float4 pa = *(const float4*)(nsp + (size_t)(n0 + j) * 4);
            float c = expf(lrelu_f(pa.x + ae[m]) - pa.y) * pa.z * pa.w;
            *(float2*)&smem[w][2 * lane] = make_float2(__int_as_float(m), c);
        }
    }
    __syncthreads();

    int s1 = min(b1 - b0, cnt64), s2 = min(b2 - b0, cnt64), s3 = min(b3 - b0, cnt64);
    float2 acc0 = make_float2(0.f, 0.f), acc1 = acc0, acc2 = acc0, acc3 = acc0;

#define NA_BODY(ACC, CBEG, CEND)                                                \
    {                                                                           \
        int c = (CBEG);                                                         \
        for (; c + 1 < (CEND); c += 2) {                                        \
            if (H == 2) {                                                       \
                float4 sa = *(const float4*)&smem[w][4 * c];                    \
                float4 sb = *(const float4*)&smem[w][4 * (c + 1)];              \
                float4 ea = ldh4(eoh + (size_t)__float_as_int(sa.x) * 256 + 4 * lane); \
                float4 eb = ldh4(eoh + (size_t)__float_as_int(sb.x) * 256 + 4 * lane); \
                ACC.x += sa.y * ea.x + sa.z * ea.z + sb.y * eb.x + sb.z * eb.z; \
                ACC.y += sa.y * ea.y + sa.z * ea.w + sb.y * eb.y + sb.z * eb.w; \
            } else {                                                            \
                float2 sa = *(const float2*)&smem[w][2 * c];                    \
                float2 sb = *(const float2*)&smem[w][2 * (c + 1)];              \
                float2 ea = ldh2(eoh + (size_t)__float_as_int(sa.x) * 128 + 2 * lane); \
                float2 eb = ldh2(eoh + (size_t)__float_as_int(sb.x) * 128 + 2 * lane); \
                ACC.x += sa.y * ea.x + sb.y * eb.x;                             \
                ACC.y += sa.y * ea.y + sb.y * eb.y;                             \
            }                                                                   \
        }                                                                       \
        if (c < (CEND)) {                                                       \
            if (H == 2) {                                                       \
                float4 sa = *(const float4*)&smem[w][4 * c];                    \
                float4 ea = ldh4(eoh + (size_t)__float_as_int(sa.x) * 256 + 4 * lane); \
                ACC.x += sa.y * ea.x + sa.z * ea.z;                             \
                ACC.y += sa.y * ea.y + sa.z * ea.w;                             \
            } else {                                                            \
                float2 sa = *(const float2*)&smem[w][2 * c];                    \
                float2 ea = ldh2(eoh + (size_t)__float_as_int(sa.x) * 128 + 2 * lane); \
                ACC.x += sa.y * ea.x;                                           \
                ACC.y += sa.y * ea.y;                                           \
            }                                                                   \
        }                                                                       \
    }
    NA_BODY(acc0, 0, s1)
    NA_BODY(acc1, s1, s2)
    NA_BODY(acc2, s2, s3)
    NA_BODY(acc3, s3, cnt64)
#undef NA_BODY

    for (int ss = 64; ss < cnt; ss++) {  // rare tail (cnt > 64): recompute coef inline
        int slot = b0 + ss;
        int j = (slot >= b1) + (slot >= b2) + (slot >= b3);
        int e = eid[slot];
        int m = e % Mm;
        float cx, cy;
        if (H == 2) {
            float4 pa = *(const float4*)(nsp + (size_t)(n0 + j) * 8);
            float4 pb = *(const float4*)(nsp + (size_t)(n0 + j) * 8 + 4);
            float2 a2 = *(const float2*)(ae + (size_t)m * 2);
            float c0 = expf(lrelu_f(pa.x + a2.x) - pa.z) * pb.x * pb.z;
            float c1 = expf(lrelu_f(pa.y + a2.y) - pa.w) * pb.y * pb.z;
            float4 ev = ldh4(eoh + (size_t)m * 256 + 4 * lane);
            cx = c0 * ev.x + c1 * ev.z;
            cy = c0 * ev.y + c1 * ev.w;
        } else {
            float4 pa = *(const float4*)(nsp + (size_t)(n0 + j) * 4);
            float c = expf(lrelu_f(pa.x + ae[m]) - pa.y) * pa.z * pa.w;
            float2 ev = ldh2(eoh + (size_t)m * 128 + 2 * lane);
            cx = c * ev.x;
            cy = c * ev.y;
        }
        if (j == 0) { acc0.x += cx; acc0.y += cy; }
        else if (j == 1) { acc1.x += cx; acc1.y += cy; }
        else if (j == 2) { acc2.x += cx; acc2.y += cy; }
        else { acc3.x += cx; acc3.y += cy; }
    }

    int col = 2 * lane;
    float2 A2 = *(const float2*)(AB + col);
    float2 B2 = *(const float2*)(AB + 128 + col);
    float2 bi = *(const float2*)(bias + col);
    float cs0 = 0.f, cs1 = 0.f, cq0 = 0.f, cq1 = 0.f;
    float2 accs[4] = {acc0, acc1, acc2, acc3};
#pragma unroll
    for (int j = 0; j < 4; j++) {
        int n = n0 + j;
        float2 xr = ldh2(T + (size_t)n * 128 + col);
        float r0 = xr.x * A2.x + B2.x + bi.x + accs[j].x;
        float r1 = xr.y * A2.y + B2.y + bi.y + accs[j].y;
        *(unsigned int*)(T + (size_t)n * 128 + col) = packh2(r0, r1);
        cs0 += r0; cs1 += r1;
        cq0 += r0 * r0; cq1 += r1 * r1;
    }
    redS[w][col] = cs0; redS[w][col + 1] = cs1;
    redQ[w][col] = cq0; redQ[w][col + 1] = cq1;
    __syncthreads();
    if (t < 128) {
        float s = 0.f, qq = 0.f;
#pragma unroll
        for (int ww = 0; ww < 4; ww++) { s += redS[ww][t]; qq += redQ[ww][t]; }
        int bkt = blockIdx.x & (NBKT - 1);
        atomicAdd(&stF[bkt * 256 + t], s);
        atomicAdd(&stF[bkt * 256 + 128 + t], qq);
    }
}

extern "C" void kernel_launch(void* const* d_in, const int* in_sizes, int n_in,
                              void* d_out, int out_size, void* d_ws, size_t ws_size,
                              hipStream_t stream) {
    const float* x = (const float*)d_in[0];
    const int* he_n = (const int*)d_in[1];
    const float* he_w = (const float*)d_in[3];
    const float* lin1_w = (const float*)d_in[4];
    const float* lin1_b = (const float*)d_in[5];
    const float* bn1_g = (const float*)d_in[6];
    const float* bn1_b = (const float*)d_in[7];
    const float* h1_w = (const float*)d_in[8];
    const float* h1_att = (const float*)d_in[9];
    const float* h1_b = (const float*)d_in[10];
    const float* bn2_g = (const float*)d_in[11];
    const float* bn2_b = (const float*)d_in[12];
    const float* h2_w = (const float*)d_in[13];
    const float* h2_att = (const float*)d_in[14];
    const float* h2_b = (const float*)d_in[15];
    const float* bn3_g = (const float*)d_in[16];
    const float* bn3_b = (const float*)d_in[17];
    const float* lin2_w = (const float*)d_in[18];
    const float* lin2_b = (const float*)d_in[19];
    const float* bn4_g = (const float*)d_in[20];
    const float* bn4_b = (const float*)d_in[21];
    float* out = (float*)d_out;

    char* ws = (char*)d_ws;
    size_t off = 0;
    auto alloc = [&](size_t bytes) -> char* {
        char* p = ws + off;
        off = (off + bytes + 255) & ~(size_t)255;
        return p;
    };
    // --- zeroed region (one memset) ---
    int* counts = (int*)alloc((size_t)Nn * 4);
    int* cursor = (int*)alloc((size_t)Nn * 4);
    float* stats = (float*)alloc((size_t)4 * NBKT * 256 * 4);
    size_t zbytes = off;
    // --- rest ---
    int* offs = (int*)alloc((size_t)(Nn + 1) * 4);
    int* eid = (int*)alloc((size_t)Ee * 4);
    int* he_nT = (int*)alloc((size_t)Ee * 4);
    float* an = (float*)alloc((size_t)Nn * 2 * 4);
    float* pe = (float*)alloc((size_t)Nn * 2 * 4);
    float* ae = (float*)alloc((size_t)Mm * 2 * 4);
    float* nsp = (float*)alloc((size_t)Nn * 8 * 4);
    float* S = (float*)alloc((size_t)2 * Mm * 128 * 4);
    unsigned short* eoh = (unsigned short*)alloc((size_t)2 * Mm * 128 * 2);
    float* wnA = (float*)alloc(384 * 4);
    float* weA = (float*)alloc(384 * 4);
    float* AB = (float*)alloc(2 * 256 * 4);
    unsigned short* bufq = (unsigned short*)alloc((size_t)Nn * 128 * 2);

    float* st0 = stats;
    float* st1 = stats + NBKT * 256;
    float* st2 = stats + 2 * NBKT * 256;
    float* st3 = stats + 3 * NBKT * 256;
    float *AB1 = AB, *AB2 = AB + 256;

    hipMemsetAsync(d_ws, 0, zbytes, stream);

    constexpr int GB32 = (Nn + 31) / 32;    // 1563
    // CSR count + he_n transpose (+watt in extra block)
    count_edges_watt<<<1251, 256, 0, stream>>>(he_n, counts, h1_w, h1_att, h2_w, h2_att,
                                               wnA, weA, he_nT);

    // stage 1: bufq = fp16(lrelu(x@lin1_w + b)) via fdot2; bn1 stats (fp32); +49 scan blocks
    gemmT<32, true, false, false, true, false, true, true, false, true>
        <<<dim3(GB32 + NBSCAN, 1), 256, 0, stream>>>(
        x, 0, lin1_w, 128, lin1_b, 1.f, nullptr, nullptr, nullptr, nullptr, st0,
        (float*)bufq, 128, Nn, GB32, counts, offs);
    // bn1 dots (finalizes st0 in-kernel; block 0 publishes AB1); +1250 blocks fill_csr
    bn_dots<2, true><<<3125 + 1250, 256, 0, stream>>>(bufq, st0, bn1_g, bn1_b, AB1, wnA, weA,
                                                      an, pe, he_n, offs, cursor, eid, 3125);

    // hgconv1 (H=2); BN1 applied inline from AB1 against fp16 bufq; eo fp16
    ea_from_pe<2><<<Mm / 4, 256, 0, stream>>>(he_nT, pe, ae);
    seg_softmax<2><<<(Nn + 31) / 32, 256, 0, stream>>>(offs, eid, an, ae, he_w, nsp);
    s_build<2><<<Mm, 256, 0, stream>>>(bufq, AB1, he_nT, nsp, ae, S);
    gemmT<32, false, false, false, false, true, false, true, false, false>
        <<<dim3(125, 2), 256, 0, stream>>>(
        S, (size_t)Mm * 128, h1_w, 256, nullptr, BINV, nullptr, nullptr, nullptr, nullptr,
        nullptr, (float*)eoh, 256, Mm, 125, nullptr, nullptr);
    node_agg<2><<<3125, 256, 0, stream>>>(offs, eid, nsp, ae, eoh, h1_b, AB1, st1, bufq);

    // stage 2 dots (finalizes st1 -> AB2)
    bn_dots<1, false><<<3125, 256, 0, stream>>>(bufq, st1, bn2_g, bn2_b, AB2, wnA + 256,
                                                weA + 256, an, pe, nullptr, nullptr, nullptr,
                                                nullptr, 3125);

    // hgconv2 (H=1); BN2 applied inline from AB2; eo fp16
    ea_from_pe<1><<<Mm / 4, 256, 0, stream>>>(he_nT, pe, ae);
    seg_softmax<1><<<(Nn + 31) / 32, 256, 0, stream>>>(offs, eid, an, ae, he_w, nsp);
    s_build<1><<<Mm, 256, 0, stream>>>(bufq, AB2, he_nT, nsp, ae, S);
    gemmT<32, false, false, false, false, false, false, true, false, false>
        <<<dim3(125, 1), 256, 0, stream>>>(
        S, 0, h2_w, 128, nullptr, BINV, nullptr, nullptr, nullptr, nullptr, nullptr,
        (float*)eoh, 128, Mm, 125, nullptr, nullptr);
    node_agg<1><<<3125, 256, 0, stream>>>(offs, eid, nsp, ae, eoh, h2_b, AB2, st2, bufq);

    // lin2: fp16 A (bufq) via fdot2 + in-kernel BN3 finalize/apply, lrelu + fp32 residual
    // + bn4 stats; writes fp16 in-place
    gemmT<32, true, true, true, true, false, false, true, true, true>
        <<<dim3(GB32, 1), 256, 0, stream>>>(
        (const float*)bufq, 0, lin2_w, 128, lin2_b, 1.f, st2, bn3_g, bn3_b, x, st3,
        (float*)bufq, 128, Nn, GB32, nullptr, nullptr);
    // final BN4: in-kernel finalize (st3) + apply; fp16 -> fp32 out
    bn_out<<<3125, 256, 0, stream>>>(bufq, st3, bn4_g, bn4_b, out);
}